// Round 5
// baseline (814.887 us; speedup 1.0000x reference)
//
#include <hip/hip_runtime.h>
#include <stdint.h>
#include <stddef.h>

#define DEVINL static __device__ __forceinline__

typedef __attribute__((ext_vector_type(8))) short  bfrag;   // 8x bf16 (bits)
typedef __attribute__((ext_vector_type(4))) float  facc;    // MFMA accumulator

DEVINL uint16_t f2b(float f){
  uint32_t u = __float_as_uint(f);
  return (uint16_t)((u + 0x7fffu + ((u >> 16) & 1u)) >> 16);   // RNE
}
DEVINL float b2f(uint16_t b){ return __uint_as_float(((uint32_t)b) << 16); }

DEVINL facc MFMA(bfrag a, bfrag b, facc c){
  return __builtin_amdgcn_mfma_f32_16x16x32_bf16(a, b, c, 0, 0, 0);
}

// async global->LDS, 16B per lane; LDS dest = wave-uniform base + lane*16
DEVINL void gload16(const void* g, void* l){
  __builtin_amdgcn_global_load_lds(
      (const __attribute__((address_space(1))) uint32_t*)g,
      (__attribute__((address_space(3))) uint32_t*)l, 16, 0, 0);
}

DEVINL float fast_tanh(float x){           // tanh = 2*sigmoid(2x)-1
  return 2.f/(1.f+__expf(-2.f*x)) - 1.f;
}

// ---------------- multi-buffer f32 -> bf16 convert (one launch) ----------------
struct F2BJobs {
  const float* s[7];
  uint16_t*    d[7];
  int          n[7];
};
__global__ void k_f2b_multi(F2BJobs jobs){
  int j = blockIdx.y;
  const float* s = jobs.s[j];
  uint16_t* d = jobs.d[j];
  int n = jobs.n[j];
  int i = blockIdx.x*256 + threadIdx.x;
  int st = gridDim.x*256;
  for(; i<n; i+=st) d[i] = f2b(s[i]);
}

// ---------------- zero border pixels of padded [128][16][16][C] ----------------
__global__ void k_zborder(uint16_t* __restrict__ X, int C){
  int b = blockIdx.x, t = threadIdx.x;
  for(int p=0;p<60;p++){
    int y, x;
    if(p<16){ y=0; x=p; }
    else if(p<32){ y=15; x=p-16; }
    else { int q=p-32; y=1+(q>>1); x=(q&1)?15:0; }
    uint32_t* dst = (uint32_t*)(X + ((size_t)(b*16+y)*16 + x)*C);
    for(int i=t;i<C/2;i+=256) dst[i] = 0;
  }
}

// ---------------- LSTM weight prep + Legendre tmat ----------------
__global__ void k_lstm_prep(const float* __restrict__ Wih, const float* __restrict__ Whh,
                            const float* __restrict__ bih, const float* __restrict__ bhh,
                            const float* __restrict__ sW, const float* __restrict__ sb,
                            const float* __restrict__ encW,
                            uint16_t* __restrict__ Wc, float* __restrict__ be,
                            uint16_t* __restrict__ encWb, float* __restrict__ tm){
  int n = threadIdx.x;
  if(n < 19){
    float tv = (float)(n - 6) / 12.0f;
    float Pm = 1.0f, Pc = tv;
    tm[0*19+n] = Pm * sqrtf(0.5f);
    tm[1*19+n] = Pc * sqrtf(1.5f);
    for(int q=1; q<7; q++){
      float Pn = ((float)(2*q+1)*tv*Pc - (float)q*Pm) / (float)(q+1);
      Pm = Pc; Pc = Pn;
      tm[(q+1)*19+n] = Pc * sqrtf((float)(2*(q+1)+1) * 0.5f);
    }
  }
  for(int k=0;k<64;k++) Wc[n*96+k] = f2b(Whh[n*64+k]);
  for(int k5=0;k5<5;k5++){
    float s = 0.f;
    for(int j=0;j<64;j++) s += Wih[n*64+j]*sW[j*5+k5];
    Wc[n*96+64+k5] = f2b(s);
  }
  for(int k=69;k<96;k++) Wc[n*96+k] = 0;
  float s = 0.f;
  for(int j=0;j<64;j++) s += Wih[n*64+j]*sb[j];
  be[n] = s + bih[n] + bhh[n];
  if(n < 64){
    for(int k=0;k<64;k++) encWb[n*64+k] = f2b(encW[n*64+k]);
  }
}

// ---------------- LSTM: 32 sequences / block, MFMA gates ----------------
__global__ __launch_bounds__(256) void k_lstm(
    const float* __restrict__ ego_seq, const float* __restrict__ ag_seq,
    const int* __restrict__ ego_len, const int* __restrict__ ag_len,
    const int* __restrict__ grid_pos,
    const uint16_t* __restrict__ Wc, const float* __restrict__ be,
    const uint16_t* __restrict__ encWb, const float* __restrict__ encB,
    float* __restrict__ agrid, uint16_t* __restrict__ egoT, uint16_t* __restrict__ feat)
{
  __shared__ __align__(16) uint16_t A[32*96];   // [seq][k] : k<64 h, 64..68 x_t, 69..95 zero
  __shared__ float Xf[32*160];                  // raw seq f32 [32][32][5]
  __shared__ int   idxs[32];

  int t = threadIdx.x, w = t>>6, l = t&63;
  int blk = blockIdx.x;
  bool isEgo = blk < 4;
  int seq0 = isEgo ? blk*32 : (blk-4)*32;
  const float* seqp = (isEgo ? ego_seq : ag_seq) + (size_t)seq0*160;

  for(int i=t;i<32*160;i+=256) Xf[i] = seqp[i];
  if(t < 32){
    int L = isEgo ? ego_len[seq0+t] : ag_len[seq0+t];
    if(L < 1) L = 1;
    idxs[t] = L-1;
  }
  for(int i=t;i<32*96;i+=256) A[i] = 0;

  bfrag bf[4][3];
  float be4[4];
  for(int ct=0;ct<4;ct++){
    int n = (ct*4+w)*16 + (l&15);
    for(int ks=0;ks<3;ks++)
      bf[ct][ks] = *(const bfrag*)(Wc + n*96 + ks*32 + (l>>4)*8);
    be4[ct] = be[n];
  }
  float cst[8], hl[8];
  for(int i=0;i<8;i++){ cst[i]=0.f; hl[i]=0.f; }
  __syncthreads();
  int myidx[8];
  for(int rt=0;rt<2;rt++) for(int r=0;r<4;r++){
    int s = rt*16 + (l>>4)*4 + r;
    myidx[rt*4+r] = idxs[s];
  }

  for(int st=0; st<32; st++){
    if(t < 160){ int s=t/5, kk=t%5; A[s*96+64+kk] = f2b(Xf[s*160 + st*5 + kk]); }
    __syncthreads();
    facc acc[2][4];
    for(int rt=0;rt<2;rt++) for(int ct=0;ct<4;ct++) acc[rt][ct] = facc{0.f,0.f,0.f,0.f};
    #pragma unroll
    for(int ks=0;ks<3;ks++){
      bfrag aA[2];
      #pragma unroll
      for(int rt=0;rt<2;rt++)
        aA[rt] = *(const bfrag*)(A + (rt*16+(l&15))*96 + ks*32 + (l>>4)*8);
      #pragma unroll
      for(int rt=0;rt<2;rt++)
        #pragma unroll
        for(int ct=0;ct<4;ct++)
          acc[rt][ct] = MFMA(aA[rt], bf[ct][ks], acc[rt][ct]);
    }
    __syncthreads();   // all A reads done before h overwrite
    #pragma unroll
    for(int rt=0;rt<2;rt++) for(int r=0;r<4;r++){
      int cell = rt*4+r;
      int s = rt*16 + (l>>4)*4 + r;
      float gi = acc[rt][0][r] + be4[0];
      float gf = acc[rt][1][r] + be4[1];
      float gg = acc[rt][2][r] + be4[2];
      float go = acc[rt][3][r] + be4[3];
      float si = 1.f/(1.f+__expf(-gi));
      float sf = 1.f/(1.f+__expf(-gf));
      float so = 1.f/(1.f+__expf(-go));
      float tg = fast_tanh(gg);
      float c2 = sf*cst[cell] + si*tg;
      cst[cell] = c2;
      float hn = so*fast_tanh(c2);
      A[s*96 + w*16 + (l&15)] = f2b(hn);
      if(st == myidx[cell]) hl[cell] = hn;
    }
  }
  __syncthreads();
  for(int rt=0;rt<2;rt++) for(int r=0;r<4;r++){
    int s = rt*16 + (l>>4)*4 + r;
    A[s*96 + w*16 + (l&15)] = f2b(hl[rt*4+r]);
  }
  __syncthreads();
  bfrag eb[2];
  for(int ks=0;ks<2;ks++)
    eb[ks] = *(const bfrag*)(encWb + (w*16+(l&15))*64 + ks*32 + (l>>4)*8);
  facc ea[2]; ea[0] = facc{0.f,0.f,0.f,0.f}; ea[1] = facc{0.f,0.f,0.f,0.f};
  for(int ks=0;ks<2;ks++){
    for(int rt=0;rt<2;rt++){
      bfrag aA = *(const bfrag*)(A + (rt*16+(l&15))*96 + ks*32 + (l>>4)*8);
      ea[rt] = MFMA(aA, eb[ks], ea[rt]);
    }
  }
  int n = w*16 + (l&15);
  float bn_ = encB[n];
  for(int rt=0;rt<2;rt++) for(int r=0;r<4;r++){
    int s = rt*16 + (l>>4)*4 + r;
    float v = ea[rt][r] + bn_;
    int gs = seq0 + s;
    if(isEgo){
      egoT[(size_t)gs*576 + 512 + n] = f2b(v);
      feat[(size_t)gs*1088 + 1024 + n] = f2b(v);
    } else {
      int py = grid_pos[gs*2+0], px = grid_pos[gs*2+1];
      atomicAdd(&agrid[((size_t)(gs>>5)*196 + py*14 + px)*64 + n], v);
    }
  }
}

// ---------------- pack conv1 input: NCHW f32 (+grid NHWC f32) -> padded NHWC bf16 ----------------
__global__ void k_packx(const float* __restrict__ cnn, const float* __restrict__ agrid,
                        uint16_t* __restrict__ Xp)
{
  __shared__ float tile[32*200];
  int b = blockIdx.x, ch = blockIdx.y, t = threadIdx.x;
  if(ch < 32){
    int c0 = ch*32;
    for(int i=t;i<32*196;i+=256){
      int ci = i/196, s = i%196;
      tile[ci*200+s] = cnn[((size_t)b*1024 + c0+ci)*196 + s];
    }
    __syncthreads();
    for(int i=t;i<32*196;i+=256){
      int s = i>>5, ci = i&31;
      int y = s/14, x = s%14;
      Xp[(((size_t)b*16 + y+1)*16 + x+1)*1088 + c0 + ci] = f2b(tile[ci*200+s]);
    }
  } else {
    int j0 = (ch-32)*32;
    for(int i=t;i<32*196;i+=256){
      int s = i>>5, ji = i&31;
      int y = s/14, x = s%14;
      Xp[(((size_t)b*16 + y+1)*16 + x+1)*1088 + 1024 + j0 + ji] =
          f2b(agrid[((size_t)b*196 + s)*64 + j0 + ji]);
    }
  }
}

// ---------------- pack conv weights OIHW f32 -> [dydx][O][C] bf16 (B^T layout) ----------------
__global__ void k_packw(const float* __restrict__ W, uint16_t* __restrict__ Wp, int O, int C)
{
  int o = blockIdx.x;
  int c = blockIdx.y*64 + threadIdx.x;
  const float* src = W + ((size_t)o*C + c)*9;
  float v[9];
  #pragma unroll
  for(int d=0;d<9;d++) v[d] = src[d];
  #pragma unroll
  for(int d=0;d<9;d++)
    Wp[((size_t)d*O + o)*C + c] = f2b(v[d]);
}

// ---------------- implicit-GEMM conv, double-buffered prefetch (T3-min) ----------------
// MODE 0: conv1  (A=Xp padded NHWC, C=1088, out padded Y1p)       grid 784
// MODE 1: conv2  (A=Y1p padded, C=512, stride 2, out [6272][512])  grid 196
// MODE 2: kv 1x1 (A=Y2 [6272][512], out [6272][2048])              grid 784
// cc-outer / tap-inner (L2 reuse). LDS double-buffer: stage step s+1 before
// computing step s; raw s_barrier + counted vmcnt(8) so prefetch loads stay in
// flight across the barrier (T3+T4). sched_barrier(0) pins ordering (rule #18).
// BN partial stats folded into the epilogue.
template<int MODE>
__global__ __launch_bounds__(256) void k_conv(
    const uint16_t* __restrict__ Ain, const uint16_t* __restrict__ Wb,
    uint16_t* __restrict__ Out, float* __restrict__ stats)
{
  constexpr int CB   = (MODE==0) ? 1088 : 512;
  constexpr int NB   = (MODE==2) ? 2048 : 512;
  constexpr int NDY  = (MODE==2) ? 1 : 9;
  constexpr int NCC  = (MODE==0) ? 17 : 8;
  constexpr int NSTEP= NDY*NCC;
  constexpr int MT   = (MODE==0) ? 196 : 49;              // m-tiles
  constexpr int NT   = NB/128;                            // n-tiles
  constexpr int NWG  = MT*NT;
  constexpr int Q8   = NWG/8, R8 = NWG%8;
  static_assert(NCC*64 == CB, "cc loop must advance exactly one dx step");

  __shared__ __align__(16) uint16_t As[2*128*64];
  __shared__ __align__(16) uint16_t Bs[2*128*64];
  __shared__ int outOff[128];

  int t = threadIdx.x, w = t>>6, l = t&63;

  // bijective XCD-chunk swizzle (m204)
  int xcd = blockIdx.x & 7, pos = blockIdx.x >> 3;
  int wgid = (xcd < R8 ? xcd*(Q8+1) : R8*(Q8+1) + (xcd-R8)*Q8) + pos;
  int n0 = (wgid / MT) * 128;
  int m0 = (wgid % MT) * 128;

  if(t < 128){
    int m = m0 + t, oo;
    if(MODE==0){
      int b = m/196, s = m%196, y = s/14, x = s%14;
      oo = ((b*16 + y+1)*16 + (x+1))*512;
    } else if(MODE==1){
      oo = m*512;
    } else {
      oo = m*2048;
    }
    outOff[t] = oo;
  }

  // per-lane staging pointers: 4 A rows + 4 B rows, constant-stride advanced
  const uint16_t* aP[4];
  const uint16_t* bP[4];
  #pragma unroll
  for(int p=0;p<4;p++){
    int r = w*32 + p*8 + (l>>3);
    int m = m0 + r, ro;
    if(MODE==0){
      int b = m/196, s = m%196, y = s/14, x = s%14;
      ro = ((b*16 + y)*16 + x)*1088;
    } else if(MODE==1){
      int b = m/49, s = m%49, y = s/7, x = s%7;
      ro = ((b*16 + 2*y)*16 + 2*x)*512;
    } else {
      ro = m*512;
    }
    aP[p] = Ain + ro + (l&7)*8;
    bP[p] = Wb + (size_t)(n0 + r)*CB + (l&7)*8;
  }
  __syncthreads();

  facc acc[4][4];
  #pragma unroll
  for(int i=0;i<4;i++)
    #pragma unroll
    for(int j=0;j<4;j++) acc[i][j] = facc{0.f,0.f,0.f,0.f};
  int wm = w>>1, wn = w&1;
  int dd = 0;   // tap index of the NEXT stage position

  // stage one step into LDS buffer `buf`
  #define STAGE(buf) do{                                              \
    char* ad_ = (char*)As + (buf)*16384 + w*4096;                     \
    char* bd_ = (char*)Bs + (buf)*16384 + w*4096;                     \
    _Pragma("unroll")                                                 \
    for(int p=0;p<4;p++) gload16(aP[p], ad_ + p*1024);                \
    _Pragma("unroll")                                                 \
    for(int p=0;p<4;p++) gload16(bP[p], bd_ + p*1024);                \
  }while(0)

  // advance pointers to the next stage position
  #define ADV() do{                                                   \
    if(MODE==2){                                                      \
      _Pragma("unroll")                                               \
      for(int p=0;p<4;p++){ aP[p]+=64; bP[p]+=64; }                   \
    } else if(dd==8){                                                 \
      _Pragma("unroll")                                               \
      for(int p=0;p<4;p++){ aP[p]+=64-34*CB; bP[p]+=64-8*NB*CB; }     \
      dd=0;                                                           \
    } else {                                                          \
      int sA_ = (dd==2||dd==5) ? 14*CB : CB;                          \
      _Pragma("unroll")                                               \
      for(int p=0;p<4;p++){ aP[p]+=sA_; bP[p]+=NB*CB; }               \
      dd++;                                                           \
    }                                                                 \
  }while(0)

  #define COMPUTE(buf) do{                                            \
    const uint16_t* ab_ = As + (buf)*8192;                            \
    const uint16_t* bb_ = Bs + (buf)*8192;                            \
    _Pragma("unroll")                                                 \
    for(int ks=0;ks<2;ks++){                                          \
      bfrag a_[4], b_[4];                                             \
      _Pragma("unroll")                                               \
      for(int i=0;i<4;i++)                                            \
        a_[i] = *(const bfrag*)(ab_ + (wm*64 + i*16 + (l&15))*64 + ks*32 + (l>>4)*8); \
      _Pragma("unroll")                                               \
      for(int j=0;j<4;j++)                                            \
        b_[j] = *(const bfrag*)(bb_ + (wn*64 + j*16 + (l&15))*64 + ks*32 + (l>>4)*8); \
      _Pragma("unroll")                                               \
      for(int i=0;i<4;i++)                                            \
        _Pragma("unroll")                                             \
        for(int j=0;j<4;j++)                                          \
          acc[i][j] = MFMA(a_[i], b_[j], acc[i][j]);                  \
    }                                                                 \
  }while(0)

  STAGE(0); ADV();
  for(int s=1; s<NSTEP; s++){
    STAGE(s&1); ADV();
    asm volatile("s_waitcnt vmcnt(8)" ::: "memory");
    __builtin_amdgcn_s_barrier();
    __builtin_amdgcn_sched_barrier(0);
    COMPUTE((s-1)&1);
    __builtin_amdgcn_sched_barrier(0);
    __builtin_amdgcn_s_barrier();
  }
  asm volatile("s_waitcnt vmcnt(0)" ::: "memory");
  __builtin_amdgcn_s_barrier();
  __builtin_amdgcn_sched_barrier(0);
  COMPUTE((NSTEP-1)&1);

  #undef STAGE
  #undef ADV
  #undef COMPUTE

  #pragma unroll
  for(int i=0;i<4;i++)
    #pragma unroll
    for(int j=0;j<4;j++){
      int n = n0 + wn*64 + j*16 + (l&15);
      #pragma unroll
      for(int r=0;r<4;r++){
        int mr = wm*64 + i*16 + (l>>4)*4 + r;
        Out[(size_t)outOff[mr] + n] = f2b(acc[i][j][r]);
      }
    }

  if(MODE != 2){
    __syncthreads();                          // all LDS reads done before reuse
    float* sred = (float*)As;                 // [128 n][8 rowgrp][2] = 8 KB
    int rg = wm*4 + (l>>4);
    #pragma unroll
    for(int j=0;j<4;j++){
      float s=0.f, q=0.f;
      #pragma unroll
      for(int i=0;i<4;i++)
        #pragma unroll
        for(int r=0;r<4;r++){ float v = acc[i][j][r]; s += v; q += v*v; }
      int nl = wn*64 + j*16 + (l&15);
      sred[(nl*8 + rg)*2+0] = s;
      sred[(nl*8 + rg)*2+1] = q;
    }
    __syncthreads();
    if(t < 128){
      float s=0.f, q=0.f;
      #pragma unroll
      for(int rgi=0;rgi<8;rgi++){ s += sred[(t*8+rgi)*2]; q += sred[(t*8+rgi)*2+1]; }
      atomicAdd(&stats[n0+t], s);
      atomicAdd(&stats[512+n0+t], q);
    }
  }
}

// ---------------- BN apply + ReLU in-place; conv2 variant extracts center into egoT/feat ----------------
// stats layout: [0..511]=sum, [512..1023]=sumsq
template<int PAD>
__global__ void k_bnapply(uint16_t* __restrict__ Y, const float* __restrict__ stats,
                          const float* __restrict__ gg, const float* __restrict__ bb,
                          int M, float invM,
                          uint16_t* __restrict__ egoT, uint16_t* __restrict__ feat)
{
  int t = threadIdx.x;
  int m0 = blockIdx.x*8;
  float mu0 = stats[2*t]*invM,       mu1 = stats[2*t+1]*invM;
  float v0 = stats[512+2*t]*invM - mu0*mu0, v1 = stats[512+2*t+1]*invM - mu1*mu1;
  float sc0 = gg[2*t]  *rsqrtf(v0+1e-5f), sc1 = gg[2*t+1]*rsqrtf(v1+1e-5f);
  float sh0 = bb[2*t]   - mu0*sc0,        sh1 = bb[2*t+1] - mu1*sc1;
  for(int i=0;i<8;i++){
    int m = m0+i; if(m>=M) break;
    size_t off;
    if(PAD){ int b=m/196, s=m%196, y=s/14, x=s%14; off = (((size_t)b*16+y+1)*16 + x+1)*512; }
    else off = (size_t)m*512;
    uint32_t u = *(const uint32_t*)(Y + off + 2*t);
    float a = fmaxf(b2f((uint16_t)u)*sc0 + sh0, 0.f);
    float c = fmaxf(b2f((uint16_t)(u>>16))*sc1 + sh1, 0.f);
    uint32_t pu = (uint32_t)f2b(a) | ((uint32_t)f2b(c)<<16);
    *(uint32_t*)(Y + off + 2*t) = pu;
    if(!PAD && (m%49)==24){
      int b = m/49;
      *(uint32_t*)(egoT + (size_t)b*576 + 2*t) = pu;
      *(uint32_t*)(feat + (size_t)b*1088 + 512 + 2*t) = pu;
    }
  }
}

// ---------------- small-M GEMM (M=128), no LDS ----------------
// flags: 1 = relu, 2 = f32 output (else bf16)
__global__ __launch_bounds__(256) void k_sgemm(
    const uint16_t* __restrict__ A, int lda,
    const uint16_t* __restrict__ B, int ldb,
    const float* __restrict__ bias,
    void* __restrict__ C, int ldc,
    int N, int K, int flags)
{
  int t = threadIdx.x, w = t>>6, l = t&63;
  int nt = blockIdx.x*4 + w;
  int n  = nt*16 + (l&15);
  int m0 = blockIdx.y*16;
  bool nv = n < N;
  facc acc = facc{0.f,0.f,0.f,0.f};
  for(int k=0;k<K;k+=32){
    bfrag af = *(const bfrag*)(A + (size_t)(m0+(l&15))*lda + k + (l>>4)*8);
    bfrag bf_ = {0,0,0,0,0,0,0,0};
    if(nv) bf_ = *(const bfrag*)(B + (size_t)n*ldb + k + (l>>4)*8);
    acc = MFMA(af, bf_, acc);
  }
  if(nv){
    float bv = bias ? bias[n] : 0.f;
    #pragma unroll
    for(int r=0;r<4;r++){
      int m = m0 + (l>>4)*4 + r;
      float v = acc[r] + bv;
      if(flags & 1) v = fmaxf(v, 0.f);
      if(flags & 2) ((float*)C)[(size_t)m*ldc + n] = v;
      else ((uint16_t*)C)[(size_t)m*ldc + n] = f2b(v);
    }
  }
}

// ---------------- attention: one wave per (b,h); ring handled analytically ----------------
__global__ __launch_bounds__(256) void k_attn(
    const float* __restrict__ q, const uint16_t* __restrict__ kv,
    uint16_t* __restrict__ o)
{
  int t = threadIdx.x, w = t>>6, l = t&63;
  int idx = blockIdx.x*4 + w;          // b*16+h
  int b = idx>>4, h = idx&15;
  float qf = q[(size_t)b*1024 + h*64 + l];
  const uint16_t* kp = kv + (size_t)b*49*2048 + h*64 + l;
  float eo = 0.f;
  for(int g=0; g<49; g++){
    float p = qf * b2f(kp[(size_t)g*2048]);
    for(int s=32;s>0;s>>=1) p += __shfl_xor(p, s);
    if(l == g) eo = p;
  }
  float e = (l<49) ? eo*(1.f/32.f) : -1e30f;
  float mx = e;
  for(int s=32;s>0;s>>=1) mx = fmaxf(mx, __shfl_xor(mx, s));
  mx = fmaxf(mx, 0.f);                          // 32 ring slots have energy 0
  float p = (l<49) ? __expf(e-mx) : 0.f;
  float den = p;
  for(int s=32;s>0;s>>=1) den += __shfl_xor(den, s);
  den += 32.f*__expf(-mx);
  const uint16_t* vp = kv + (size_t)b*49*2048 + 1024 + h*64 + l;
  float accv = 0.f;
  for(int g=0; g<49; g++){
    float pg = __shfl(p, g);
    accv += pg * b2f(vp[(size_t)g*2048]);
  }
  o[(size_t)b*1024 + h*64 + l] = f2b(accv/den);
}

// ---------------- trajectory: d2[b][25][16] @ tmat -> out [b][25][19][2] ----------------
__global__ void k_traj(const float* __restrict__ d2, const float* __restrict__ tm,
                       float* __restrict__ out)
{
  int i = blockIdx.x*256 + threadIdx.x;
  if(i >= 3200) return;
  const float* dp = d2 + (size_t)i*16;
  float cx[8], cy[8];
  #pragma unroll
  for(int j=0;j<8;j++){ cx[j]=dp[j]; cy[j]=dp[8+j]; }
  float* op = out + (size_t)i*38;
  for(int tt=0;tt<19;tt++){
    float x=0.f, y=0.f;
    #pragma unroll
    for(int j=0;j<8;j++){ float tv = tm[j*19+tt]; x += cx[j]*tv; y += cy[j]*tv; }
    op[tt*2+0]=x; op[tt*2+1]=y;
  }
}

// ======================= host =======================
extern "C" void kernel_launch(void* const* d_in, const int* in_sizes, int n_in,
                              void* d_out, int out_size, void* d_ws, size_t ws_size,
                              hipStream_t stream)
{
  const float* cnn      = (const float*)d_in[0];
  const float* ego_seq  = (const float*)d_in[1];
  const float* ag_seq   = (const float*)d_in[2];
  const int*   ego_len  = (const int*)d_in[3];
  const int*   ag_len   = (const int*)d_in[4];
  const int*   grid_pos = (const int*)d_in[5];
  const float* sW  = (const float*)d_in[6];
  const float* sb  = (const float*)d_in[7];
  const float* Wih = (const float*)d_in[8];
  const float* Whh = (const float*)d_in[9];
  const float* bih = (const float*)d_in[10];
  const float* bhh = (const float*)d_in[11];
  const float* encW = (const float*)d_in[12];
  const float* encB = (const float*)d_in[13];
  const float* conv1W = (const float*)d_in[14];
  const float* bn1g = (const float*)d_in[15];
  const float* bn1b = (const float*)d_in[16];
  const float* conv2W = (const float*)d_in[17];
  const float* bn2g = (const float*)d_in[18];
  const float* bn2b = (const float*)d_in[19];
  const float* qWf  = (const float*)d_in[20];
  const float* kWf  = (const float*)d_in[21];
  const float* vWf  = (const float*)d_in[22];
  const float* aoW  = (const float*)d_in[23];
  const float* aoB  = (const float*)d_in[24];
  const float* clsWf = (const float*)d_in[25];
  const float* clsB  = (const float*)d_in[26];
  const float* d1Wf  = (const float*)d_in[27];
  const float* d1B   = (const float*)d_in[28];
  const float* d2Wf  = (const float*)d_in[29];
  const float* d2B   = (const float*)d_in[30];

  char* ws = (char*)d_ws;
  const size_t XP_OFF   = 0;                 // 71,303,168
  const size_t KV_OFF   = 0;                 // alias: after Xp dead
  const size_t Y2_OFF   = 29360128;          // alias inside Xp region
  const size_t Y1P_OFF  = 71303168;          // 33,554,432
  const size_t WP1_OFF  = 104857600;
  const size_t WP2_OFF  = 114884608;
  const size_t WKV_OFF  = 119603200;
  const size_t QW_OFF   = 121700352;
  const size_t AOW_OFF  = 122880000;
  const size_t CLSW_OFF = 123928576;
  const size_t D1W_OFF  = 123982976;
  const size_t D2W_OFF  = 124540032;
  const size_t GRID_OFF = 124744832;
  const size_t EGOT_OFF = 131167360;
  const size_t FEAT_OFF = 131314816;
  const size_t QBUF_OFF = 131593344;
  const size_t OBUF_OFF = 132117632;
  const size_t D1_OFF   = 132379776;
  const size_t D2_OFF   = 132445312;
  const size_t WC_OFF   = 132650112;
  const size_t BE_OFF   = 132699264;
  const size_t ENCW_OFF = 132700288;
  const size_t TMAT_OFF = 132708480;
  const size_t ST1_OFF  = 132709120;         // 4,096 (sum 512 + sumsq 512)
  const size_t ST2_OFF  = 132713216;         // 4,096

  uint16_t* XP   = (uint16_t*)(ws + XP_OFF);
  uint16_t* KV   = (uint16_t*)(ws + KV_OFF);
  uint16_t* Y2   = (uint16_t*)(ws + Y2_OFF);
  uint16_t* Y1P  = (uint16_t*)(ws + Y1P_OFF);
  uint16_t* WP1  = (uint16_t*)(ws + WP1_OFF);
  uint16_t* WP2  = (uint16_t*)(ws + WP2_OFF);
  uint16_t* WKV  = (uint16_t*)(ws + WKV_OFF);
  uint16_t* QW   = (uint16_t*)(ws + QW_OFF);
  uint16_t* AOW  = (uint16_t*)(ws + AOW_OFF);
  uint16_t* CLSW = (uint16_t*)(ws + CLSW_OFF);
  uint16_t* D1W  = (uint16_t*)(ws + D1W_OFF);
  uint16_t* D2W  = (uint16_t*)(ws + D2W_OFF);
  float*    GRIDB= (float*)(ws + GRID_OFF);
  uint16_t* EGOT = (uint16_t*)(ws + EGOT_OFF);
  uint16_t* FEAT = (uint16_t*)(ws + FEAT_OFF);
  float*    QBUF = (float*)(ws + QBUF_OFF);
  uint16_t* OBUF = (uint16_t*)(ws + OBUF_OFF);
  uint16_t* D1B  = (uint16_t*)(ws + D1_OFF);
  float*    D2B  = (float*)(ws + D2_OFF);
  uint16_t* WC   = (uint16_t*)(ws + WC_OFF);
  float*    BE   = (float*)(ws + BE_OFF);
  uint16_t* ENCWB= (uint16_t*)(ws + ENCW_OFF);
  float*    TMAT = (float*)(ws + TMAT_OFF);
  float*    ST1  = (float*)(ws + ST1_OFF);
  float*    ST2  = (float*)(ws + ST2_OFF);
  float*    outF = (float*)d_out;

  (void)hipMemsetAsync(ws + GRID_OFF, 0, 6422528, stream);
  (void)hipMemsetAsync(ws + ST1_OFF,  0, 8192, stream);

  // border zeros (replaces 71MB + 33MB memsets)
  k_zborder<<<128,256,0,stream>>>(XP, 1088);
  k_zborder<<<128,256,0,stream>>>(Y1P, 512);

  // constants / weight packs
  k_lstm_prep<<<1,256,0,stream>>>(Wih,Whh,bih,bhh,sW,sb,encW, WC,BE,ENCWB, TMAT);
  k_packw<<<dim3(512,17),64,0,stream>>>(conv1W, WP1, 512, 1088);
  k_packw<<<dim3(512,8), 64,0,stream>>>(conv2W, WP2, 512, 512);
  {
    F2BJobs jb;
    jb.s[0]=kWf;  jb.d[0]=WKV;              jb.n[0]=1024*512;
    jb.s[1]=vWf;  jb.d[1]=WKV + 1024*512;   jb.n[1]=1024*512;
    jb.s[2]=qWf;  jb.d[2]=QW;               jb.n[2]=1024*576;
    jb.s[3]=aoW;  jb.d[3]=AOW;              jb.n[3]=512*1024;
    jb.s[4]=clsWf;jb.d[4]=CLSW;             jb.n[4]=25*1088;
    jb.s[5]=d1Wf; jb.d[5]=D1W;              jb.n[5]=256*1088;
    jb.s[6]=d2Wf; jb.d[6]=D2W;              jb.n[6]=400*256;
    k_f2b_multi<<<dim3(48,7),256,0,stream>>>(jb);
  }

  // encoders + scatter
  k_lstm<<<132,256,0,stream>>>(ego_seq, ag_seq, ego_len, ag_len, grid_pos,
                               WC, BE, ENCWB, encB, GRIDB, EGOT, FEAT);
  // conv input pack
  k_packx<<<dim3(128,34),256,0,stream>>>(cnn, GRIDB, XP);
  // conv1 (+stats) -> BN1 -> relu (in place, padded)
  k_conv<0><<<784,256,0,stream>>>(XP, WP1, Y1P, ST1);
  k_bnapply<1><<<3136,256,0,stream>>>(Y1P, ST1, bn1g, bn1b, 25088, 1.f/25088.f, nullptr, nullptr);
  // conv2 (+stats) -> BN2 -> relu (+ center pixel -> egoT/feat)
  k_conv<1><<<196,256,0,stream>>>(Y1P, WP2, Y2, ST2);
  k_bnapply<0><<<784,256,0,stream>>>(Y2, ST2, bn2g, bn2b, 6272, 1.f/6272.f, EGOT, FEAT);
  // k,v 1x1 convs
  k_conv<2><<<784,256,0,stream>>>(Y2, WKV, KV, nullptr);
  // q = egoT @ qW^T  (f32 out)
  k_sgemm<<<dim3(16,8),256,0,stream>>>(EGOT, 576, QW, 576, nullptr, QBUF, 1024, 1024, 576, 2);
  // attention
  k_attn<<<512,256,0,stream>>>(QBUF, KV, OBUF);
  // attn_out -> feat[:,0:512]
  k_sgemm<<<dim3(8,8),256,0,stream>>>(OBUF, 1024, AOW, 1024, aoB, FEAT, 1088, 512, 1024, 0);
  // conf -> d_out[121600:]
  k_sgemm<<<dim3(1,8),256,0,stream>>>(FEAT, 1088, CLSW, 1088, clsB, outF + 121600, 25, 25, 1088, 2);
  // dec1 (relu) -> dec2 -> traj
  k_sgemm<<<dim3(4,8),256,0,stream>>>(FEAT, 1088, D1W, 1088, d1B, D1B, 256, 256, 1088, 1);
  k_sgemm<<<dim3(7,8),256,0,stream>>>(D1B, 256, D2W, 256, d2B, D2B, 400, 400, 256, 2);
  k_traj<<<13,256,0,stream>>>(D2B, TMAT, outF);

  (void)in_sizes; (void)n_in; (void)out_size; (void)ws_size;
}

// Round 6
// 677.027 us; speedup vs baseline: 1.2036x; 1.2036x over previous
//
#include <hip/hip_runtime.h>
#include <stdint.h>
#include <stddef.h>

#define DEVINL static __device__ __forceinline__

typedef __attribute__((ext_vector_type(8))) short  bfrag;   // 8x bf16 (bits)
typedef __attribute__((ext_vector_type(4))) float  facc;    // MFMA accumulator

DEVINL uint16_t f2b(float f){
  uint32_t u = __float_as_uint(f);
  return (uint16_t)((u + 0x7fffu + ((u >> 16) & 1u)) >> 16);   // RNE
}
DEVINL float b2f(uint16_t b){ return __uint_as_float(((uint32_t)b) << 16); }

DEVINL facc MFMA(bfrag a, bfrag b, facc c){
  return __builtin_amdgcn_mfma_f32_16x16x32_bf16(a, b, c, 0, 0, 0);
}

// async global->LDS, 16B per lane; LDS dest = wave-uniform base + lane*16
DEVINL void gload16(const void* g, void* l){
  __builtin_amdgcn_global_load_lds(
      (const __attribute__((address_space(1))) uint32_t*)g,
      (__attribute__((address_space(3))) uint32_t*)l, 16, 0, 0);
}

DEVINL float fast_tanh(float x){           // tanh = 2*sigmoid(2x)-1
  return 2.f/(1.f+__expf(-2.f*x)) - 1.f;
}

// ---------------- multi-buffer f32 -> bf16 convert (one launch) ----------------
struct F2BJobs {
  const float* s[7];
  uint16_t*    d[7];
  int          n[7];
};
__global__ void k_f2b_multi(F2BJobs jobs){
  int j = blockIdx.y;
  const float* s = jobs.s[j];
  uint16_t* d = jobs.d[j];
  int n = jobs.n[j];
  int i = blockIdx.x*256 + threadIdx.x;
  int st = gridDim.x*256;
  for(; i<n; i+=st) d[i] = f2b(s[i]);
}

// ---------------- zero border pixels of padded [128][16][16][C] ----------------
__global__ void k_zborder(uint16_t* __restrict__ X, int C){
  int b = blockIdx.x, t = threadIdx.x;
  for(int p=0;p<60;p++){
    int y, x;
    if(p<16){ y=0; x=p; }
    else if(p<32){ y=15; x=p-16; }
    else { int q=p-32; y=1+(q>>1); x=(q&1)?15:0; }
    uint32_t* dst = (uint32_t*)(X + ((size_t)(b*16+y)*16 + x)*C);
    for(int i=t;i<C/2;i+=256) dst[i] = 0;
  }
}

// ---------------- LSTM weight prep + Legendre tmat ----------------
__global__ void k_lstm_prep(const float* __restrict__ Wih, const float* __restrict__ Whh,
                            const float* __restrict__ bih, const float* __restrict__ bhh,
                            const float* __restrict__ sW, const float* __restrict__ sb,
                            const float* __restrict__ encW,
                            uint16_t* __restrict__ Wc, float* __restrict__ be,
                            uint16_t* __restrict__ encWb, float* __restrict__ tm){
  int n = threadIdx.x;
  if(n < 19){
    float tv = (float)(n - 6) / 12.0f;
    float Pm = 1.0f, Pc = tv;
    tm[0*19+n] = Pm * sqrtf(0.5f);
    tm[1*19+n] = Pc * sqrtf(1.5f);
    for(int q=1; q<7; q++){
      float Pn = ((float)(2*q+1)*tv*Pc - (float)q*Pm) / (float)(q+1);
      Pm = Pc; Pc = Pn;
      tm[(q+1)*19+n] = Pc * sqrtf((float)(2*(q+1)+1) * 0.5f);
    }
  }
  for(int k=0;k<64;k++) Wc[n*96+k] = f2b(Whh[n*64+k]);
  for(int k5=0;k5<5;k5++){
    float s = 0.f;
    for(int j=0;j<64;j++) s += Wih[n*64+j]*sW[j*5+k5];
    Wc[n*96+64+k5] = f2b(s);
  }
  for(int k=69;k<96;k++) Wc[n*96+k] = 0;
  float s = 0.f;
  for(int j=0;j<64;j++) s += Wih[n*64+j]*sb[j];
  be[n] = s + bih[n] + bhh[n];
  if(n < 64){
    for(int k=0;k<64;k++) encWb[n*64+k] = f2b(encW[n*64+k]);
  }
}

// ---------------- LSTM: 32 sequences / block, MFMA gates ----------------
__global__ __launch_bounds__(256) void k_lstm(
    const float* __restrict__ ego_seq, const float* __restrict__ ag_seq,
    const int* __restrict__ ego_len, const int* __restrict__ ag_len,
    const int* __restrict__ grid_pos,
    const uint16_t* __restrict__ Wc, const float* __restrict__ be,
    const uint16_t* __restrict__ encWb, const float* __restrict__ encB,
    float* __restrict__ agrid, uint16_t* __restrict__ egoT, uint16_t* __restrict__ feat)
{
  __shared__ __align__(16) uint16_t A[32*96];   // [seq][k] : k<64 h, 64..68 x_t, 69..95 zero
  __shared__ float Xf[32*160];                  // raw seq f32 [32][32][5]
  __shared__ int   idxs[32];

  int t = threadIdx.x, w = t>>6, l = t&63;
  int blk = blockIdx.x;
  bool isEgo = blk < 4;
  int seq0 = isEgo ? blk*32 : (blk-4)*32;
  const float* seqp = (isEgo ? ego_seq : ag_seq) + (size_t)seq0*160;

  for(int i=t;i<32*160;i+=256) Xf[i] = seqp[i];
  if(t < 32){
    int L = isEgo ? ego_len[seq0+t] : ag_len[seq0+t];
    if(L < 1) L = 1;
    idxs[t] = L-1;
  }
  for(int i=t;i<32*96;i+=256) A[i] = 0;

  bfrag bf[4][3];
  float be4[4];
  for(int ct=0;ct<4;ct++){
    int n = (ct*4+w)*16 + (l&15);
    for(int ks=0;ks<3;ks++)
      bf[ct][ks] = *(const bfrag*)(Wc + n*96 + ks*32 + (l>>4)*8);
    be4[ct] = be[n];
  }
  float cst[8], hl[8];
  for(int i=0;i<8;i++){ cst[i]=0.f; hl[i]=0.f; }
  __syncthreads();
  int myidx[8];
  for(int rt=0;rt<2;rt++) for(int r=0;r<4;r++){
    int s = rt*16 + (l>>4)*4 + r;
    myidx[rt*4+r] = idxs[s];
  }

  for(int st=0; st<32; st++){
    if(t < 160){ int s=t/5, kk=t%5; A[s*96+64+kk] = f2b(Xf[s*160 + st*5 + kk]); }
    __syncthreads();
    facc acc[2][4];
    for(int rt=0;rt<2;rt++) for(int ct=0;ct<4;ct++) acc[rt][ct] = facc{0.f,0.f,0.f,0.f};
    #pragma unroll
    for(int ks=0;ks<3;ks++){
      bfrag aA[2];
      #pragma unroll
      for(int rt=0;rt<2;rt++)
        aA[rt] = *(const bfrag*)(A + (rt*16+(l&15))*96 + ks*32 + (l>>4)*8);
      #pragma unroll
      for(int rt=0;rt<2;rt++)
        #pragma unroll
        for(int ct=0;ct<4;ct++)
          acc[rt][ct] = MFMA(aA[rt], bf[ct][ks], acc[rt][ct]);
    }
    __syncthreads();   // all A reads done before h overwrite
    #pragma unroll
    for(int rt=0;rt<2;rt++) for(int r=0;r<4;r++){
      int cell = rt*4+r;
      int s = rt*16 + (l>>4)*4 + r;
      float gi = acc[rt][0][r] + be4[0];
      float gf = acc[rt][1][r] + be4[1];
      float gg = acc[rt][2][r] + be4[2];
      float go = acc[rt][3][r] + be4[3];
      float si = 1.f/(1.f+__expf(-gi));
      float sf = 1.f/(1.f+__expf(-gf));
      float so = 1.f/(1.f+__expf(-go));
      float tg = fast_tanh(gg);
      float c2 = sf*cst[cell] + si*tg;
      cst[cell] = c2;
      float hn = so*fast_tanh(c2);
      A[s*96 + w*16 + (l&15)] = f2b(hn);
      if(st == myidx[cell]) hl[cell] = hn;
    }
  }
  __syncthreads();
  for(int rt=0;rt<2;rt++) for(int r=0;r<4;r++){
    int s = rt*16 + (l>>4)*4 + r;
    A[s*96 + w*16 + (l&15)] = f2b(hl[rt*4+r]);
  }
  __syncthreads();
  bfrag eb[2];
  for(int ks=0;ks<2;ks++)
    eb[ks] = *(const bfrag*)(encWb + (w*16+(l&15))*64 + ks*32 + (l>>4)*8);
  facc ea[2]; ea[0] = facc{0.f,0.f,0.f,0.f}; ea[1] = facc{0.f,0.f,0.f,0.f};
  for(int ks=0;ks<2;ks++){
    for(int rt=0;rt<2;rt++){
      bfrag aA = *(const bfrag*)(A + (rt*16+(l&15))*96 + ks*32 + (l>>4)*8);
      ea[rt] = MFMA(aA, eb[ks], ea[rt]);
    }
  }
  int n = w*16 + (l&15);
  float bn_ = encB[n];
  for(int rt=0;rt<2;rt++) for(int r=0;r<4;r++){
    int s = rt*16 + (l>>4)*4 + r;
    float v = ea[rt][r] + bn_;
    int gs = seq0 + s;
    if(isEgo){
      egoT[(size_t)gs*576 + 512 + n] = f2b(v);
      feat[(size_t)gs*1088 + 1024 + n] = f2b(v);
    } else {
      int py = grid_pos[gs*2+0], px = grid_pos[gs*2+1];
      atomicAdd(&agrid[((size_t)(gs>>5)*196 + py*14 + px)*64 + n], v);
    }
  }
}

// ---------------- pack conv1 input: NCHW f32 (+grid NHWC f32) -> padded NHWC bf16 ----------------
__global__ void k_packx(const float* __restrict__ cnn, const float* __restrict__ agrid,
                        uint16_t* __restrict__ Xp)
{
  __shared__ float tile[32*200];
  int b = blockIdx.x, ch = blockIdx.y, t = threadIdx.x;
  if(ch < 32){
    int c0 = ch*32;
    for(int i=t;i<32*196;i+=256){
      int ci = i/196, s = i%196;
      tile[ci*200+s] = cnn[((size_t)b*1024 + c0+ci)*196 + s];
    }
    __syncthreads();
    for(int i=t;i<32*196;i+=256){
      int s = i>>5, ci = i&31;
      int y = s/14, x = s%14;
      Xp[(((size_t)b*16 + y+1)*16 + x+1)*1088 + c0 + ci] = f2b(tile[ci*200+s]);
    }
  } else {
    int j0 = (ch-32)*32;
    for(int i=t;i<32*196;i+=256){
      int s = i>>5, ji = i&31;
      int y = s/14, x = s%14;
      Xp[(((size_t)b*16 + y+1)*16 + x+1)*1088 + 1024 + j0 + ji] =
          f2b(agrid[((size_t)b*196 + s)*64 + j0 + ji]);
    }
  }
}

// ---------------- pack conv weights OIHW f32 -> [dydx][O][C] bf16 (B^T layout) ----------------
__global__ void k_packw(const float* __restrict__ W, uint16_t* __restrict__ Wp, int O, int C)
{
  int o = blockIdx.x;
  int c = blockIdx.y*64 + threadIdx.x;
  const float* src = W + ((size_t)o*C + c)*9;
  float v[9];
  #pragma unroll
  for(int d=0;d<9;d++) v[d] = src[d];
  #pragma unroll
  for(int d=0;d<9;d++)
    Wp[((size_t)d*O + o)*C + c] = f2b(v[d]);
}

// ================= conv1: 256x256 8-phase pipelined implicit GEMM =================
// M=25088 (98 tiles), N=512 (2 tiles), K=9 taps x 1088 = 153 K-steps of 64.
// 8 waves (2M x 4N), per-wave out 128x64, acc[8][4]. LDS 128KB = 2dbuf x (A 32K + B 32K).
// A half P = rows consumed by quadrant mh=P (per wave rows wm*128+P*64..+63).
// B half P = n-rows consumed by quadrant nh=P (per wave cols wn*64+P*32..+31).
// Stage order per K-tile: {A0,B0,B1,A1}; uniform vmcnt(4) waits (ledger-verified);
// T2 XOR-swizzle: pre-swizzled global source + swizzled ds_read (col ^= (row&7)<<4 bytes).
__global__ __launch_bounds__(512) void k_conv1_8p(
    const uint16_t* __restrict__ Ain, const uint16_t* __restrict__ Wb,
    uint16_t* __restrict__ Out, float* __restrict__ stats)
{
  constexpr int CB = 1088;
  constexpr int NSTEP = 153;          // 17 cc x 9 taps
  __shared__ __align__(16) char LDSb[131072];

  int t = threadIdx.x, w = t>>6, l = t&63;
  int wm = w>>2, wn = w&3;

  // bijective XCD-chunk swizzle (m204), 196 wgs: Q8=24, R8=4; m-major within n-panel
  int xcd = blockIdx.x & 7, pos = blockIdx.x >> 3;
  int wgid = (xcd < 4 ? xcd*25 : 100 + (xcd-4)*24) + pos;
  int m0 = (wgid % 98) * 256;
  int n0 = (wgid / 98) * 256;

  // per-thread staging pointers: A[part][load], B[part][load]
  const uint16_t* aP[2][2];
  const uint16_t* bP[2][2];
  #pragma unroll
  for(int P=0;P<2;P++)
    #pragma unroll
    for(int j=0;j<2;j++){
      int partrow = j*64 + (t>>3);
      int swz = ((t&7) ^ (partrow&7))*8;            // elements
      int gr = P*64 + partrow + ((partrow>=64)?64:0);
      int m = m0 + gr; int b = m/196, s = m%196, y = s/14, x = s%14;
      aP[P][j] = Ain + ((b*16+y)*16+x)*CB + swz;
      int nb = n0 + (partrow>>5)*64 + P*32 + (partrow&31);
      bP[P][j] = Wb + (size_t)nb*CB + swz;
    }

  facc acc[8][4];
  #pragma unroll
  for(int i=0;i<8;i++)
    #pragma unroll
    for(int j=0;j<4;j++) acc[i][j] = facc{0.f,0.f,0.f,0.f};

  int dd = 0;   // tap of NEXT stage position

  // PART: 0=A0, 1=B0, 2=B1, 3=A1
  #define STG(buf, PART) do{                                                   \
    if((PART)==0 || (PART)==3){ const int P_ = ((PART)==3);                    \
      _Pragma("unroll")                                                        \
      for(int j_=0;j_<2;j_++)                                                  \
        gload16(aP[P_][j_], LDSb + (buf)*65536 + P_*16384 + j_*8192 + w*1024); \
    } else { const int P_ = ((PART)==2);                                       \
      _Pragma("unroll")                                                        \
      for(int j_=0;j_<2;j_++)                                                  \
        gload16(bP[P_][j_], LDSb + (buf)*65536 + 32768 + P_*16384 + j_*8192 + w*1024); \
    }                                                                          \
  }while(0)

  #define ADVK() do{                                                          \
    if(dd==8){                                                                \
      _Pragma("unroll")                                                       \
      for(int P_=0;P_<2;P_++) for(int j_=0;j_<2;j_++){                        \
        aP[P_][j_] += 64 - 34*CB; bP[P_][j_] += 64 - 8*512*CB; }              \
      dd = 0;                                                                 \
    } else {                                                                  \
      int sA_ = (dd==2||dd==5) ? 14*CB : CB;                                  \
      _Pragma("unroll")                                                       \
      for(int P_=0;P_<2;P_++) for(int j_=0;j_<2;j_++){                        \
        aP[P_][j_] += sA_; bP[P_][j_] += 512*CB; }                            \
      dd++;                                                                   \
    }                                                                         \
  }while(0)

  #define VM4 asm volatile("s_waitcnt vmcnt(4)" ::: "memory")
  #define VM2 asm volatile("s_waitcnt vmcnt(2)" ::: "memory")
  #define VM0 asm volatile("s_waitcnt vmcnt(0)" ::: "memory")

  // DO_STG: 1 in main loop, 0 in peeled last K-tile. WAIT: end-of-phase vmcnt.
  #define PHASE(mh, nh, SP, DO_STG, WAIT) do{                                 \
    const uint16_t* Ab_ = (const uint16_t*)(LDSb + p*65536 + (mh)*16384);     \
    const uint16_t* Bb_ = (const uint16_t*)(LDSb + p*65536 + 32768 + (nh)*16384); \
    bfrag a_[4][2], b_[2][2];                                                 \
    _Pragma("unroll")                                                         \
    for(int i_=0;i_<4;i_++)                                                   \
      _Pragma("unroll")                                                       \
      for(int ks_=0;ks_<2;ks_++)                                              \
        a_[i_][ks_] = *(const bfrag*)(Ab_ + (wm*64 + i_*16 + (l&15))*64       \
                        + ((ks_*32 + (l>>4)*8) ^ ((l&7)<<3)));                \
    _Pragma("unroll")                                                         \
    for(int j_=0;j_<2;j_++)                                                   \
      _Pragma("unroll")                                                       \
      for(int ks_=0;ks_<2;ks_++)                                              \
        b_[j_][ks_] = *(const bfrag*)(Bb_ + (wn*32 + j_*16 + (l&15))*64       \
                        + ((ks_*32 + (l>>4)*8) ^ ((l&7)<<3)));                \
    if(DO_STG) STG(p^1, SP);                                                  \
    __builtin_amdgcn_sched_barrier(0);                                        \
    __builtin_amdgcn_s_barrier();                                             \
    __builtin_amdgcn_s_setprio(1);                                            \
    _Pragma("unroll")                                                         \
    for(int ks_=0;ks_<2;ks_++)                                                \
      _Pragma("unroll")                                                       \
      for(int i_=0;i_<4;i_++)                                                 \
        _Pragma("unroll")                                                     \
        for(int j_=0;j_<2;j_++)                                               \
          acc[(mh)*4+i_][(nh)*2+j_] =                                         \
            MFMA(a_[i_][ks_], b_[j_][ks_], acc[(mh)*4+i_][(nh)*2+j_]);        \
    __builtin_amdgcn_s_setprio(0);                                            \
    WAIT;                                                                     \
    __builtin_amdgcn_s_barrier();                                             \
  }while(0)

  // prologue: stage K-tile 0 (A0,B0,B1,A1) into buf0; advance to kt=1
  STG(0,0); STG(0,1); STG(0,2); STG(0,3);
  ADVK();
  VM4;
  __builtin_amdgcn_s_barrier();

  for(int kt=0; kt<NSTEP-1; kt++){
    int p = kt&1;
    PHASE(0,0, 0, 1, VM4);
    PHASE(0,1, 1, 1, VM4);
    PHASE(1,0, 2, 1, (void)0);
    PHASE(1,1, 3, 1, VM4);
    if(kt < NSTEP-2) ADVK();
  }
  { // peeled last K-tile (kt=152, buf 0), no staging, drain
    int p = 0;
    PHASE(0,0, 0, 0, VM2);
    PHASE(0,1, 1, 0, VM0);
    PHASE(1,0, 2, 0, (void)0);
    PHASE(1,1, 3, 0, (void)0);
  }

  #undef PHASE
  #undef STG
  #undef ADVK

  // epilogue: padded-offset table, stores, BN partial stats
  __syncthreads();
  int* oo = (int*)LDSb;
  if(t < 256){
    int m = m0 + t; int b = m/196, s = m%196, y = s/14, x = s%14;
    oo[t] = ((b*16 + y+1)*16 + (x+1))*512;
  }
  __syncthreads();
  #pragma unroll
  for(int i=0;i<8;i++)
    #pragma unroll
    for(int j=0;j<4;j++){
      int n = n0 + wn*64 + j*16 + (l&15);
      #pragma unroll
      for(int r=0;r<4;r++){
        int mr = wm*128 + i*16 + (l>>4)*4 + r;
        Out[(size_t)oo[mr] + n] = f2b(acc[i][j][r]);
      }
    }
  __syncthreads();
  float* sred = (float*)LDSb;                 // [256 col][8 rowgrp][2] = 16 KB
  int rg = wm*4 + (l>>4);
  #pragma unroll
  for(int j=0;j<4;j++){
    float s=0.f, q=0.f;
    #pragma unroll
    for(int i=0;i<8;i++)
      #pragma unroll
      for(int r=0;r<4;r++){ float v = acc[i][j][r]; s += v; q += v*v; }
    int nl = wn*64 + j*16 + (l&15);
    sred[(nl*8 + rg)*2+0] = s;
    sred[(nl*8 + rg)*2+1] = q;
  }
  __syncthreads();
  if(t < 256){
    float s=0.f, q=0.f;
    #pragma unroll
    for(int rgi=0;rgi<8;rgi++){ s += sred[(t*8+rgi)*2]; q += sred[(t*8+rgi)*2+1]; }
    atomicAdd(&stats[n0+t], s);
    atomicAdd(&stats[512+n0+t], q);
  }
}

// ---------------- implicit-GEMM conv (R4 single-buffer, cc-outer/tap-inner) ----------------
// MODE 1: conv2 (A=Y1p padded, C=512, stride 2, out [6272][512]) grid 196
// MODE 2: kv 1x1 (A=Y2 [6272][512], out [6272][2048])            grid 784
template<int MODE>
__global__ __launch_bounds__(256) void k_conv(
    const uint16_t* __restrict__ Ain, const uint16_t* __restrict__ Wb,
    uint16_t* __restrict__ Out, float* __restrict__ stats)
{
  constexpr int CB   = 512;
  constexpr int NB   = (MODE==2) ? 2048 : 512;
  constexpr int NDY  = (MODE==2) ? 1 : 9;
  constexpr int NCC  = 8;
  constexpr int MT   = 49;
  constexpr int NT   = NB/128;
  constexpr int NWG  = MT*NT;
  constexpr int Q8   = NWG/8, R8 = NWG%8;

  __shared__ __align__(16) uint16_t As[128*64];
  __shared__ __align__(16) uint16_t Bs[128*64];
  __shared__ int outOff[128];

  int t = threadIdx.x, w = t>>6, l = t&63;

  int xcd = blockIdx.x & 7, pos = blockIdx.x >> 3;
  int wgid = (xcd < R8 ? xcd*(Q8+1) : R8*(Q8+1) + (xcd-R8)*Q8) + pos;
  int n0 = (wgid / MT) * 128;
  int m0 = (wgid % MT) * 128;

  if(t < 128){
    int m = m0 + t;
    outOff[t] = (MODE==1) ? m*512 : m*2048;
  }

  const uint16_t* aP[4];
  const uint16_t* bP[4];
  #pragma unroll
  for(int p=0;p<4;p++){
    int r = w*32 + p*8 + (l>>3);
    int m = m0 + r, ro;
    if(MODE==1){
      int b = m/49, s = m%49, y = s/7, x = s%7;
      ro = ((b*16 + 2*y)*16 + 2*x)*512;
    } else {
      ro = m*512;
    }
    aP[p] = Ain + ro + (l&7)*8;
    bP[p] = Wb + (size_t)(n0 + r)*CB + (l&7)*8;
  }
  __syncthreads();

  facc acc[4][4];
  #pragma unroll
  for(int i=0;i<4;i++)
    #pragma unroll
    for(int j=0;j<4;j++) acc[i][j] = facc{0.f,0.f,0.f,0.f};
  int wm = w>>1, wn = w&1;
  char* asDst = (char*)As + w*4096;
  char* bsDst = (char*)Bs + w*4096;

  for(int cc=0; cc<NCC; cc++){
    for(int d=0; d<NDY; d++){
      #pragma unroll
      for(int p=0;p<4;p++) gload16(aP[p], asDst + p*1024);
      #pragma unroll
      for(int p=0;p<4;p++) gload16(bP[p], bsDst + p*1024);
      if(MODE != 2){
        int stepA = ((d%3)==2) ? 14*CB : CB;
        #pragma unroll
        for(int p=0;p<4;p++){ aP[p] += stepA; bP[p] += NB*CB; }
      }
      __syncthreads();
      #pragma unroll
      for(int ks=0;ks<2;ks++){
        bfrag a[4], b[4];
        #pragma unroll
        for(int i=0;i<4;i++)
          a[i] = *(const bfrag*)(As + (wm*64 + i*16 + (l&15))*64 + ks*32 + (l>>4)*8);
        #pragma unroll
        for(int j=0;j<4;j++)
          b[j] = *(const bfrag*)(Bs + (wn*64 + j*16 + (l&15))*64 + ks*32 + (l>>4)*8);
        #pragma unroll
        for(int i=0;i<4;i++)
          #pragma unroll
          for(int j=0;j<4;j++)
            acc[i][j] = MFMA(a[i], b[j], acc[i][j]);
      }
      __syncthreads();
    }
    int resetA = (MODE==2) ? 64 : 64 - 48*CB;
    int resetB = (MODE==2) ? 64 : 64 - 9*NB*CB;
    #pragma unroll
    for(int p=0;p<4;p++){ aP[p] += resetA; bP[p] += resetB; }
  }

  #pragma unroll
  for(int i=0;i<4;i++)
    #pragma unroll
    for(int j=0;j<4;j++){
      int n = n0 + wn*64 + j*16 + (l&15);
      #pragma unroll
      for(int r=0;r<4;r++){
        int mr = wm*64 + i*16 + (l>>4)*4 + r;
        Out[(size_t)outOff[mr] + n] = f2b(acc[i][j][r]);
      }
    }

  if(MODE != 2){
    __syncthreads();
    float* sred = (float*)As;
    int rg = wm*4 + (l>>4);
    #pragma unroll
    for(int j=0;j<4;j++){
      float s=0.f, q=0.f;
      #pragma unroll
      for(int i=0;i<4;i++)
        #pragma unroll
        for(int r=0;r<4;r++){ float v = acc[i][j][r]; s += v; q += v*v; }
      int nl = wn*64 + j*16 + (l&15);
      sred[(nl*8 + rg)*2+0] = s;
      sred[(nl*8 + rg)*2+1] = q;
    }
    __syncthreads();
    if(t < 128){
      float s=0.f, q=0.f;
      #pragma unroll
      for(int rgi=0;rgi<8;rgi++){ s += sred[(t*8+rgi)*2]; q += sred[(t*8+rgi)*2+1]; }
      atomicAdd(&stats[n0+t], s);
      atomicAdd(&stats[512+n0+t], q);
    }
  }
}

// ---------------- BN apply + ReLU in-place; conv2 variant extracts center into egoT/feat ----------------
// stats layout: [0..511]=sum, [512..1023]=sumsq
template<int PAD>
__global__ void k_bnapply(uint16_t* __restrict__ Y, const float* __restrict__ stats,
                          const float* __restrict__ gg, const float* __restrict__ bb,
                          int M, float invM,
                          uint16_t* __restrict__ egoT, uint16_t* __restrict__ feat)
{
  int t = threadIdx.x;
  int m0 = blockIdx.x*8;
  float mu0 = stats[2*t]*invM,       mu1 = stats[2*t+1]*invM;
  float v0 = stats[512+2*t]*invM - mu0*mu0, v1 = stats[512+2*t+1]*invM - mu1*mu1;
  float sc0 = gg[2*t]  *rsqrtf(v0+1e-5f), sc1 = gg[2*t+1]*rsqrtf(v1+1e-5f);
  float sh0 = bb[2*t]   - mu0*sc0,        sh1 = bb[2*t+1] - mu1*sc1;
  for(int i=0;i<8;i++){
    int m = m0+i; if(m>=M) break;
    size_t off;
    if(PAD){ int b=m/196, s=m%196, y=s/14, x=s%14; off = (((size_t)b*16+y+1)*16 + x+1)*512; }
    else off = (size_t)m*512;
    uint32_t u = *(const uint32_t*)(Y + off + 2*t);
    float a = fmaxf(b2f((uint16_t)u)*sc0 + sh0, 0.f);
    float c = fmaxf(b2f((uint16_t)(u>>16))*sc1 + sh1, 0.f);
    uint32_t pu = (uint32_t)f2b(a) | ((uint32_t)f2b(c)<<16);
    *(uint32_t*)(Y + off + 2*t) = pu;
    if(!PAD && (m%49)==24){
      int b = m/49;
      *(uint32_t*)(egoT + (size_t)b*576 + 2*t) = pu;
      *(uint32_t*)(feat + (size_t)b*1088 + 512 + 2*t) = pu;
    }
  }
}

// ---------------- small-M GEMM (M=128), no LDS ----------------
// flags: 1 = relu, 2 = f32 output (else bf16)
__global__ __launch_bounds__(256) void k_sgemm(
    const uint16_t* __restrict__ A, int lda,
    const uint16_t* __restrict__ B, int ldb,
    const float* __restrict__ bias,
    void* __restrict__ C, int ldc,
    int N, int K, int flags)
{
  int t = threadIdx.x, w = t>>6, l = t&63;
  int nt = blockIdx.x*4 + w;
  int n  = nt*16 + (l&15);
  int m0 = blockIdx.y*16;
  bool nv = n < N;
  facc acc = facc{0.f,0.f,0.f,0.f};
  for(int k=0;k<K;k+=32){
    bfrag af = *(const bfrag*)(A + (size_t)(m0+(l&15))*lda + k + (l>>4)*8);
    bfrag bf_ = {0,0,0,0,0,0,0,0};
    if(nv) bf_ = *(const bfrag*)(B + (size_t)n*ldb + k + (l>>4)*8);
    acc = MFMA(af, bf_, acc);
  }
  if(nv){
    float bv = bias ? bias[n] : 0.f;
    #pragma unroll
    for(int r=0;r<4;r++){
      int m = m0 + (l>>4)*4 + r;
      float v = acc[r] + bv;
      if(flags & 1) v = fmaxf(v, 0.f);
      if(flags & 2) ((float*)C)[(size_t)m*ldc + n] = v;
      else ((uint16_t*)C)[(size_t)m*ldc + n] = f2b(v);
    }
  }
}

// ---------------- attention: one wave per (b,h); ring handled analytically ----------------
__global__ __launch_bounds__(256) void k_attn(
    const float* __restrict__ q, const uint16_t* __restrict__ kv,
    uint16_t* __restrict__ o)
{
  int t = threadIdx.x, w = t>>6, l = t&63;
  int idx = blockIdx.x*4 + w;          // b*16+h
  int b = idx>>4, h = idx&15;
  float qf = q[(size_t)b*1024 + h*64 + l];
  const uint16_t* kp = kv + (size_t)b*49*2048 + h*64 + l;
  float eo = 0.f;
  for(int g=0; g<49; g++){
    float p = qf * b2f(kp[(size_t)g*2048]);
    for(int s=32;s>0;s>>=1) p += __shfl_xor(p, s);
    if(l == g) eo = p;
  }
  float e = (l<49) ? eo*(1.f/32.f) : -1e30f;
  float mx = e;
  for(int s=32;s>0;s>>=1) mx = fmaxf(mx, __shfl_xor(mx, s));
  mx = fmaxf(mx, 0.f);                          // 32 ring slots have energy 0
  float p = (l<49) ? __expf(e-mx) : 0.f;
  float den = p;
  for(int s=32;s>0;s>>=1) den += __shfl_xor(den, s);
  den += 32.f*__expf(-mx);
  const uint16_t* vp = kv + (size_t)b*49*2048 + 1024 + h*64 + l;
  float accv = 0.f;
  for(int g=0; g<49; g++){
    float pg = __shfl(p, g);
    accv += pg * b2f(vp[(size_t)g*2048]);
  }
  o[(size_t)b*1024 + h*64 + l] = f2b(accv/den);
}

// ---------------- trajectory: d2[b][25][16] @ tmat -> out [b][25][19][2] ----------------
__global__ void k_traj(const float* __restrict__ d2, const float* __restrict__ tm,
                       float* __restrict__ out)
{
  int i = blockIdx.x*256 + threadIdx.x;
  if(i >= 3200) return;
  const float* dp = d2 + (size_t)i*16;
  float cx[8], cy[8];
  #pragma unroll
  for(int j=0;j<8;j++){ cx[j]=dp[j]; cy[j]=dp[8+j]; }
  float* op = out + (size_t)i*38;
  for(int tt=0;tt<19;tt++){
    float x=0.f, y=0.f;
    #pragma unroll
    for(int j=0;j<8;j++){ float tv = tm[j*19+tt]; x += cx[j]*tv; y += cy[j]*tv; }
    op[tt*2+0]=x; op[tt*2+1]=y;
  }
}

// ======================= host =======================
extern "C" void kernel_launch(void* const* d_in, const int* in_sizes, int n_in,
                              void* d_out, int out_size, void* d_ws, size_t ws_size,
                              hipStream_t stream)
{
  const float* cnn      = (const float*)d_in[0];
  const float* ego_seq  = (const float*)d_in[1];
  const float* ag_seq   = (const float*)d_in[2];
  const int*   ego_len  = (const int*)d_in[3];
  const int*   ag_len   = (const int*)d_in[4];
  const int*   grid_pos = (const int*)d_in[5];
  const float* sW  = (const float*)d_in[6];
  const float* sb  = (const float*)d_in[7];
  const float* Wih = (const float*)d_in[8];
  const float* Whh = (const float*)d_in[9];
  const float* bih = (const float*)d_in[10];
  const float* bhh = (const float*)d_in[11];
  const float* encW = (const float*)d_in[12];
  const float* encB = (const float*)d_in[13];
  const float* conv1W = (const float*)d_in[14];
  const float* bn1g = (const float*)d_in[15];
  const float* bn1b = (const float*)d_in[16];
  const float* conv2W = (const float*)d_in[17];
  const float* bn2g = (const float*)d_in[18];
  const float* bn2b = (const float*)d_in[19];
  const float* qWf  = (const float*)d_in[20];
  const float* kWf  = (const float*)d_in[21];
  const float* vWf  = (const float*)d_in[22];
  const float* aoW  = (const float*)d_in[23];
  const float* aoB  = (const float*)d_in[24];
  const float* clsWf = (const float*)d_in[25];
  const float* clsB  = (const float*)d_in[26];
  const float* d1Wf  = (const float*)d_in[27];
  const float* d1B   = (const float*)d_in[28];
  const float* d2Wf  = (const float*)d_in[29];
  const float* d2B   = (const float*)d_in[30];

  char* ws = (char*)d_ws;
  const size_t XP_OFF   = 0;                 // 71,303,168
  const size_t KV_OFF   = 0;                 // alias: after Xp dead
  const size_t Y2_OFF   = 29360128;          // alias inside Xp region
  const size_t Y1P_OFF  = 71303168;          // 33,554,432
  const size_t WP1_OFF  = 104857600;
  const size_t WP2_OFF  = 114884608;
  const size_t WKV_OFF  = 119603200;
  const size_t QW_OFF   = 121700352;
  const size_t AOW_OFF  = 122880000;
  const size_t CLSW_OFF = 123928576;
  const size_t D1W_OFF  = 123982976;
  const size_t D2W_OFF  = 124540032;
  const size_t GRID_OFF = 124744832;
  const size_t EGOT_OFF = 131167360;
  const size_t FEAT_OFF = 131314816;
  const size_t QBUF_OFF = 131593344;
  const size_t OBUF_OFF = 132117632;
  const size_t D1_OFF   = 132379776;
  const size_t D2_OFF   = 132445312;
  const size_t WC_OFF   = 132650112;
  const size_t BE_OFF   = 132699264;
  const size_t ENCW_OFF = 132700288;
  const size_t TMAT_OFF = 132708480;
  const size_t ST1_OFF  = 132709120;         // sum 512 + sumsq 512
  const size_t ST2_OFF  = 132713216;

  uint16_t* XP   = (uint16_t*)(ws + XP_OFF);
  uint16_t* KV   = (uint16_t*)(ws + KV_OFF);
  uint16_t* Y2   = (uint16_t*)(ws + Y2_OFF);
  uint16_t* Y1P  = (uint16_t*)(ws + Y1P_OFF);
  uint16_t* WP1  = (uint16_t*)(ws + WP1_OFF);
  uint16_t* WP2  = (uint16_t*)(ws + WP2_OFF);
  uint16_t* WKV  = (uint16_t*)(ws + WKV_OFF);
  uint16_t* QW   = (uint16_t*)(ws + QW_OFF);
  uint16_t* AOW  = (uint16_t*)(ws + AOW_OFF);
  uint16_t* CLSW = (uint16_t*)(ws + CLSW_OFF);
  uint16_t* D1W  = (uint16_t*)(ws + D1W_OFF);
  uint16_t* D2W  = (uint16_t*)(ws + D2W_OFF);
  float*    GRIDB= (float*)(ws + GRID_OFF);
  uint16_t* EGOT = (uint16_t*)(ws + EGOT_OFF);
  uint16_t* FEAT = (uint16_t*)(ws + FEAT_OFF);
  float*    QBUF = (float*)(ws + QBUF_OFF);
  uint16_t* OBUF = (uint16_t*)(ws + OBUF_OFF);
  uint16_t* D1B  = (uint16_t*)(ws + D1_OFF);
  float*    D2B  = (float*)(ws + D2_OFF);
  uint16_t* WC   = (uint16_t*)(ws + WC_OFF);
  float*    BE   = (float*)(ws + BE_OFF);
  uint16_t* ENCWB= (uint16_t*)(ws + ENCW_OFF);
  float*    TMAT = (float*)(ws + TMAT_OFF);
  float*    ST1  = (float*)(ws + ST1_OFF);
  float*    ST2  = (float*)(ws + ST2_OFF);
  float*    outF = (float*)d_out;

  (void)hipMemsetAsync(ws + GRID_OFF, 0, 6422528, stream);
  (void)hipMemsetAsync(ws + ST1_OFF,  0, 8192, stream);

  // border zeros (replaces 71MB + 33MB memsets)
  k_zborder<<<128,256,0,stream>>>(XP, 1088);
  k_zborder<<<128,256,0,stream>>>(Y1P, 512);

  // constants / weight packs
  k_lstm_prep<<<1,256,0,stream>>>(Wih,Whh,bih,bhh,sW,sb,encW, WC,BE,ENCWB, TMAT);
  k_packw<<<dim3(512,17),64,0,stream>>>(conv1W, WP1, 512, 1088);
  k_packw<<<dim3(512,8), 64,0,stream>>>(conv2W, WP2, 512, 512);
  {
    F2BJobs jb;
    jb.s[0]=kWf;  jb.d[0]=WKV;              jb.n[0]=1024*512;
    jb.s[1]=vWf;  jb.d[1]=WKV + 1024*512;   jb.n[1]=1024*512;
    jb.s[2]=qWf;  jb.d[2]=QW;               jb.n[2]=1024*576;
    jb.s[3]=aoW;  jb.d[3]=AOW;              jb.n[3]=512*1024;
    jb.s[4]=clsWf;jb.d[4]=CLSW;             jb.n[4]=25*1088;
    jb.s[5]=d1Wf; jb.d[5]=D1W;              jb.n[5]=256*1088;
    jb.s[6]=d2Wf; jb.d[6]=D2W;              jb.n[6]=400*256;
    k_f2b_multi<<<dim3(48,7),256,0,stream>>>(jb);
  }

  // encoders + scatter
  k_lstm<<<132,256,0,stream>>>(ego_seq, ag_seq, ego_len, ag_len, grid_pos,
                               WC, BE, ENCWB, encB, GRIDB, EGOT, FEAT);
  // conv input pack
  k_packx<<<dim3(128,34),256,0,stream>>>(cnn, GRIDB, XP);
  // conv1 (8-phase 256², +stats) -> BN1 -> relu (in place, padded)
  k_conv1_8p<<<196,512,0,stream>>>(XP, WP1, Y1P, ST1);
  k_bnapply<1><<<3136,256,0,stream>>>(Y1P, ST1, bn1g, bn1b, 25088, 1.f/25088.f, nullptr, nullptr);
  // conv2 (+stats) -> BN2 -> relu (+ center pixel -> egoT/feat)
  k_conv<1><<<196,256,0,stream>>>(Y1P, WP2, Y2, ST2);
  k_bnapply<0><<<784,256,0,stream>>>(Y2, ST2, bn2g, bn2b, 6272, 1.f/6272.f, EGOT, FEAT);
  // k,v 1x1 convs
  k_conv<2><<<784,256,0,stream>>>(Y2, WKV, KV, nullptr);
  // q = egoT @ qW^T  (f32 out)
  k_sgemm<<<dim3(16,8),256,0,stream>>>(EGOT, 576, QW, 576, nullptr, QBUF, 1024, 1024, 576, 2);
  // attention
  k_attn<<<512,256,0,stream>>>(QBUF, KV, OBUF);
  // attn_out -> feat[:,0:512]
  k_sgemm<<<dim3(8,8),256,0,stream>>>(OBUF, 1024, AOW, 1024, aoB, FEAT, 1088, 512, 1024, 0);
  // conf -> d_out[121600:]
  k_sgemm<<<dim3(1,8),256,0,stream>>>(FEAT, 1088, CLSW, 1088, clsB, outF + 121600, 25, 25, 1088, 2);
  // dec1 (relu) -> dec2 -> traj
  k_sgemm<<<dim3(4,8),256,0,stream>>>(FEAT, 1088, D1W, 1088, d1B, D1B, 256, 256, 1088, 1);
  k_sgemm<<<dim3(7,8),256,0,stream>>>(D1B, 256, D2W, 256, d2B, D2B, 400, 400, 256, 2);
  k_traj<<<13,256,0,stream>>>(D2B, TMAT, outF);

  (void)in_sizes; (void)n_in; (void)out_size; (void)ws_size;
}

// Round 7
// 664.294 us; speedup vs baseline: 1.2267x; 1.0192x over previous
//
#include <hip/hip_runtime.h>
#include <stdint.h>
#include <stddef.h>

#define DEVINL static __device__ __forceinline__

typedef __attribute__((ext_vector_type(8))) short  bfrag;   // 8x bf16 (bits)
typedef __attribute__((ext_vector_type(4))) float  facc;    // MFMA accumulator

DEVINL uint16_t f2b(float f){
  uint32_t u = __float_as_uint(f);
  return (uint16_t)((u + 0x7fffu + ((u >> 16) & 1u)) >> 16);   // RNE
}
DEVINL float b2f(uint16_t b){ return __uint_as_float(((uint32_t)b) << 16); }

DEVINL facc MFMA(bfrag a, bfrag b, facc c){
  return __builtin_amdgcn_mfma_f32_16x16x32_bf16(a, b, c, 0, 0, 0);
}

// async global->LDS, 16B per lane; LDS dest = wave-uniform base + lane*16
DEVINL void gload16(const void* g, void* l){
  __builtin_amdgcn_global_load_lds(
      (const __attribute__((address_space(1))) uint32_t*)g,
      (__attribute__((address_space(3))) uint32_t*)l, 16, 0, 0);
}

DEVINL float fast_tanh(float x){           // tanh = 2*sigmoid(2x)-1
  return 2.f/(1.f+__expf(-2.f*x)) - 1.f;
}

// ---------------- multi-buffer f32 -> bf16 convert (one launch) ----------------
struct F2BJobs {
  const float* s[7];
  uint16_t*    d[7];
  int          n[7];
};
__global__ void k_f2b_multi(F2BJobs jobs){
  int j = blockIdx.y;
  const float* s = jobs.s[j];
  uint16_t* d = jobs.d[j];
  int n = jobs.n[j];
  int i = blockIdx.x*256 + threadIdx.x;
  int st = gridDim.x*256;
  for(; i<n; i+=st) d[i] = f2b(s[i]);
}

// ---------------- zero border pixels of padded [128][16][16][C] (both buffers) ----------------
__global__ void k_zborder(uint16_t* __restrict__ X, uint16_t* __restrict__ Y){
  int b = blockIdx.x & 127, t = threadIdx.x;
  uint16_t* base = (blockIdx.x < 128) ? X : Y;
  int C = (blockIdx.x < 128) ? 1088 : 512;
  for(int p=0;p<60;p++){
    int y, x;
    if(p<16){ y=0; x=p; }
    else if(p<32){ y=15; x=p-16; }
    else { int q=p-32; y=1+(q>>1); x=(q&1)?15:0; }
    uint32_t* dst = (uint32_t*)(base + ((size_t)(b*16+y)*16 + x)*C);
    for(int i=t;i<C/2;i+=256) dst[i] = 0;
  }
}

// ---------------- LSTM weight prep + Legendre tmat ----------------
__global__ void k_lstm_prep(const float* __restrict__ Wih, const float* __restrict__ Whh,
                            const float* __restrict__ bih, const float* __restrict__ bhh,
                            const float* __restrict__ sW, const float* __restrict__ sb,
                            const float* __restrict__ encW,
                            uint16_t* __restrict__ Wc, float* __restrict__ be,
                            uint16_t* __restrict__ encWb, float* __restrict__ tm){
  int n = threadIdx.x;
  if(n < 19){
    float tv = (float)(n - 6) / 12.0f;
    float Pm = 1.0f, Pc = tv;
    tm[0*19+n] = Pm * sqrtf(0.5f);
    tm[1*19+n] = Pc * sqrtf(1.5f);
    for(int q=1; q<7; q++){
      float Pn = ((float)(2*q+1)*tv*Pc - (float)q*Pm) / (float)(q+1);
      Pm = Pc; Pc = Pn;
      tm[(q+1)*19+n] = Pc * sqrtf((float)(2*(q+1)+1) * 0.5f);
    }
  }
  for(int k=0;k<64;k++) Wc[n*96+k] = f2b(Whh[n*64+k]);
  for(int k5=0;k5<5;k5++){
    float s = 0.f;
    for(int j=0;j<64;j++) s += Wih[n*64+j]*sW[j*5+k5];
    Wc[n*96+64+k5] = f2b(s);
  }
  for(int k=69;k<96;k++) Wc[n*96+k] = 0;
  float s = 0.f;
  for(int j=0;j<64;j++) s += Wih[n*64+j]*sb[j];
  be[n] = s + bih[n] + bhh[n];
  if(n < 64){
    for(int k=0;k<64;k++) encWb[n*64+k] = f2b(encW[n*64+k]);
  }
}

// ---------------- LSTM: 32 sequences / block, MFMA gates ----------------
__global__ __launch_bounds__(256) void k_lstm(
    const float* __restrict__ ego_seq, const float* __restrict__ ag_seq,
    const int* __restrict__ ego_len, const int* __restrict__ ag_len,
    const int* __restrict__ grid_pos,
    const uint16_t* __restrict__ Wc, const float* __restrict__ be,
    const uint16_t* __restrict__ encWb, const float* __restrict__ encB,
    float* __restrict__ agrid, uint16_t* __restrict__ egoT, uint16_t* __restrict__ feat)
{
  __shared__ __align__(16) uint16_t A[32*96];   // [seq][k] : k<64 h, 64..68 x_t, 69..95 zero
  __shared__ float Xf[32*160];                  // raw seq f32 [32][32][5]
  __shared__ int   idxs[32];

  int t = threadIdx.x, w = t>>6, l = t&63;
  int blk = blockIdx.x;
  bool isEgo = blk < 4;
  int seq0 = isEgo ? blk*32 : (blk-4)*32;
  const float* seqp = (isEgo ? ego_seq : ag_seq) + (size_t)seq0*160;

  for(int i=t;i<32*160;i+=256) Xf[i] = seqp[i];
  if(t < 32){
    int L = isEgo ? ego_len[seq0+t] : ag_len[seq0+t];
    if(L < 1) L = 1;
    idxs[t] = L-1;
  }
  for(int i=t;i<32*96;i+=256) A[i] = 0;

  bfrag bf[4][3];
  float be4[4];
  for(int ct=0;ct<4;ct++){
    int n = (ct*4+w)*16 + (l&15);
    for(int ks=0;ks<3;ks++)
      bf[ct][ks] = *(const bfrag*)(Wc + n*96 + ks*32 + (l>>4)*8);
    be4[ct] = be[n];
  }
  float cst[8], hl[8];
  for(int i=0;i<8;i++){ cst[i]=0.f; hl[i]=0.f; }
  __syncthreads();
  int myidx[8];
  for(int rt=0;rt<2;rt++) for(int r=0;r<4;r++){
    int s = rt*16 + (l>>4)*4 + r;
    myidx[rt*4+r] = idxs[s];
  }

  for(int st=0; st<32; st++){
    if(t < 160){ int s=t/5, kk=t%5; A[s*96+64+kk] = f2b(Xf[s*160 + st*5 + kk]); }
    __syncthreads();
    facc acc[2][4];
    for(int rt=0;rt<2;rt++) for(int ct=0;ct<4;ct++) acc[rt][ct] = facc{0.f,0.f,0.f,0.f};
    #pragma unroll
    for(int ks=0;ks<3;ks++){
      bfrag aA[2];
      #pragma unroll
      for(int rt=0;rt<2;rt++)
        aA[rt] = *(const bfrag*)(A + (rt*16+(l&15))*96 + ks*32 + (l>>4)*8);
      #pragma unroll
      for(int rt=0;rt<2;rt++)
        #pragma unroll
        for(int ct=0;ct<4;ct++)
          acc[rt][ct] = MFMA(aA[rt], bf[ct][ks], acc[rt][ct]);
    }
    __syncthreads();   // all A reads done before h overwrite
    #pragma unroll
    for(int rt=0;rt<2;rt++) for(int r=0;r<4;r++){
      int cell = rt*4+r;
      int s = rt*16 + (l>>4)*4 + r;
      float gi = acc[rt][0][r] + be4[0];
      float gf = acc[rt][1][r] + be4[1];
      float gg = acc[rt][2][r] + be4[2];
      float go = acc[rt][3][r] + be4[3];
      float si = 1.f/(1.f+__expf(-gi));
      float sf = 1.f/(1.f+__expf(-gf));
      float so = 1.f/(1.f+__expf(-go));
      float tg = fast_tanh(gg);
      float c2 = sf*cst[cell] + si*tg;
      cst[cell] = c2;
      float hn = so*fast_tanh(c2);
      A[s*96 + w*16 + (l&15)] = f2b(hn);
      if(st == myidx[cell]) hl[cell] = hn;
    }
  }
  __syncthreads();
  for(int rt=0;rt<2;rt++) for(int r=0;r<4;r++){
    int s = rt*16 + (l>>4)*4 + r;
    A[s*96 + w*16 + (l&15)] = f2b(hl[rt*4+r]);
  }
  __syncthreads();
  bfrag eb[2];
  for(int ks=0;ks<2;ks++)
    eb[ks] = *(const bfrag*)(encWb + (w*16+(l&15))*64 + ks*32 + (l>>4)*8);
  facc ea[2]; ea[0] = facc{0.f,0.f,0.f,0.f}; ea[1] = facc{0.f,0.f,0.f,0.f};
  for(int ks=0;ks<2;ks++){
    for(int rt=0;rt<2;rt++){
      bfrag aA = *(const bfrag*)(A + (rt*16+(l&15))*96 + ks*32 + (l>>4)*8);
      ea[rt] = MFMA(aA, eb[ks], ea[rt]);
    }
  }
  int n = w*16 + (l&15);
  float bn_ = encB[n];
  for(int rt=0;rt<2;rt++) for(int r=0;r<4;r++){
    int s = rt*16 + (l>>4)*4 + r;
    float v = ea[rt][r] + bn_;
    int gs = seq0 + s;
    if(isEgo){
      egoT[(size_t)gs*576 + 512 + n] = f2b(v);
      feat[(size_t)gs*1088 + 1024 + n] = f2b(v);
    } else {
      int py = grid_pos[gs*2+0], px = grid_pos[gs*2+1];
      atomicAdd(&agrid[((size_t)(gs>>5)*196 + py*14 + px)*64 + n], v);
    }
  }
}

// ---------------- pack conv1 input: NCHW f32 (+grid NHWC f32) -> padded NHWC bf16 ----------------
__global__ void k_packx(const float* __restrict__ cnn, const float* __restrict__ agrid,
                        uint16_t* __restrict__ Xp)
{
  __shared__ float tile[32*200];
  int b = blockIdx.x, ch = blockIdx.y, t = threadIdx.x;
  if(ch < 32){
    int c0 = ch*32;
    for(int i=t;i<32*196;i+=256){
      int ci = i/196, s = i%196;
      tile[ci*200+s] = cnn[((size_t)b*1024 + c0+ci)*196 + s];
    }
    __syncthreads();
    for(int i=t;i<32*196;i+=256){
      int s = i>>5, ci = i&31;
      int y = s/14, x = s%14;
      Xp[(((size_t)b*16 + y+1)*16 + x+1)*1088 + c0 + ci] = f2b(tile[ci*200+s]);
    }
  } else {
    int j0 = (ch-32)*32;
    for(int i=t;i<32*196;i+=256){
      int s = i>>5, ji = i&31;
      int y = s/14, x = s%14;
      Xp[(((size_t)b*16 + y+1)*16 + x+1)*1088 + 1024 + j0 + ji] =
          f2b(agrid[((size_t)b*196 + s)*64 + j0 + ji]);
    }
  }
}

// ---------------- pack conv1 weights OIHW f32 -> [dydx][O][C] bf16 ----------------
__global__ void k_packw(const float* __restrict__ W, uint16_t* __restrict__ Wp, int O, int C)
{
  int o = blockIdx.x;
  int c = blockIdx.y*64 + threadIdx.x;
  const float* src = W + ((size_t)o*C + c)*9;
  float v[9];
  #pragma unroll
  for(int d=0;d<9;d++) v[d] = src[d];
  #pragma unroll
  for(int d=0;d<9;d++)
    Wp[((size_t)d*O + o)*C + c] = f2b(v[d]);
}

// ---------------- pack conv2 weights OIHW -> [dy][O][dx*512+c] bf16 (flat K=1536 per dy) ----------------
__global__ void k_packw2(const float* __restrict__ W, uint16_t* __restrict__ Wp)
{
  int o = blockIdx.x;
  int c = blockIdx.y*64 + threadIdx.x;
  const float* src = W + ((size_t)o*512 + c)*9;
  float v[9];
  #pragma unroll
  for(int d=0;d<9;d++) v[d] = src[d];
  #pragma unroll
  for(int dy=0;dy<3;dy++)
    #pragma unroll
    for(int dx=0;dx<3;dx++)
      Wp[((size_t)(dy*512 + o))*1536 + dx*512 + c] = f2b(v[dy*3+dx]);
}

// ================= conv1: 256x256 8-phase pipelined implicit GEMM =================
// (unchanged from R6 — verified: MfmaUtil 34%, bank-conflicts 434x down, absmax canary OK)
__global__ __launch_bounds__(512) void k_conv1_8p(
    const uint16_t* __restrict__ Ain, const uint16_t* __restrict__ Wb,
    uint16_t* __restrict__ Out, float* __restrict__ stats)
{
  constexpr int CB = 1088;
  constexpr int NSTEP = 153;          // 17 cc x 9 taps
  __shared__ __align__(16) char LDSb[131072];

  int t = threadIdx.x, w = t>>6, l = t&63;
  int wm = w>>2, wn = w&3;

  int xcd = blockIdx.x & 7, pos = blockIdx.x >> 3;
  int wgid = (xcd < 4 ? xcd*25 : 100 + (xcd-4)*24) + pos;
  int m0 = (wgid % 98) * 256;
  int n0 = (wgid / 98) * 256;

  const uint16_t* aP[2][2];
  const uint16_t* bP[2][2];
  #pragma unroll
  for(int P=0;P<2;P++)
    #pragma unroll
    for(int j=0;j<2;j++){
      int partrow = j*64 + (t>>3);
      int swz = ((t&7) ^ (partrow&7))*8;            // elements
      int gr = P*64 + partrow + ((partrow>=64)?64:0);
      int m = m0 + gr; int b = m/196, s = m%196, y = s/14, x = s%14;
      aP[P][j] = Ain + ((b*16+y)*16+x)*CB + swz;
      int nb = n0 + (partrow>>5)*64 + P*32 + (partrow&31);
      bP[P][j] = Wb + (size_t)nb*CB + swz;
    }

  facc acc[8][4];
  #pragma unroll
  for(int i=0;i<8;i++)
    #pragma unroll
    for(int j=0;j<4;j++) acc[i][j] = facc{0.f,0.f,0.f,0.f};

  int dd = 0;

  #define STG(buf, PART) do{                                                   \
    if((PART)==0 || (PART)==3){ const int P_ = ((PART)==3);                    \
      _Pragma("unroll")                                                        \
      for(int j_=0;j_<2;j_++)                                                  \
        gload16(aP[P_][j_], LDSb + (buf)*65536 + P_*16384 + j_*8192 + w*1024); \
    } else { const int P_ = ((PART)==2);                                       \
      _Pragma("unroll")                                                        \
      for(int j_=0;j_<2;j_++)                                                  \
        gload16(bP[P_][j_], LDSb + (buf)*65536 + 32768 + P_*16384 + j_*8192 + w*1024); \
    }                                                                          \
  }while(0)

  #define ADVK() do{                                                          \
    if(dd==8){                                                                \
      _Pragma("unroll")                                                       \
      for(int P_=0;P_<2;P_++) for(int j_=0;j_<2;j_++){                        \
        aP[P_][j_] += 64 - 34*CB; bP[P_][j_] += 64 - 8*512*CB; }              \
      dd = 0;                                                                 \
    } else {                                                                  \
      int sA_ = (dd==2||dd==5) ? 14*CB : CB;                                  \
      _Pragma("unroll")                                                       \
      for(int P_=0;P_<2;P_++) for(int j_=0;j_<2;j_++){                        \
        aP[P_][j_] += sA_; bP[P_][j_] += 512*CB; }                            \
      dd++;                                                                   \
    }                                                                         \
  }while(0)

  #define VM4 asm volatile("s_waitcnt vmcnt(4)" ::: "memory")
  #define VM2 asm volatile("s_waitcnt vmcnt(2)" ::: "memory")
  #define VM0 asm volatile("s_waitcnt vmcnt(0)" ::: "memory")

  #define PHASE(mh, nh, SP, DO_STG, WAIT) do{                                 \
    const uint16_t* Ab_ = (const uint16_t*)(LDSb + p*65536 + (mh)*16384);     \
    const uint16_t* Bb_ = (const uint16_t*)(LDSb + p*65536 + 32768 + (nh)*16384); \
    bfrag a_[4][2], b_[2][2];                                                 \
    _Pragma("unroll")                                                         \
    for(int i_=0;i_<4;i_++)                                                   \
      _Pragma("unroll")                                                       \
      for(int ks_=0;ks_<2;ks_++)                                              \
        a_[i_][ks_] = *(const bfrag*)(Ab_ + (wm*64 + i_*16 + (l&15))*64       \
                        + ((ks_*32 + (l>>4)*8) ^ ((l&7)<<3)));                \
    _Pragma("unroll")                                                         \
    for(int j_=0;j_<2;j_++)                                                   \
      _Pragma("unroll")                                                       \
      for(int ks_=0;ks_<2;ks_++)                                              \
        b_[j_][ks_] = *(const bfrag*)(Bb_ + (wn*32 + j_*16 + (l&15))*64       \
                        + ((ks_*32 + (l>>4)*8) ^ ((l&7)<<3)));                \
    if(DO_STG) STG(p^1, SP);                                                  \
    __builtin_amdgcn_sched_barrier(0);                                        \
    __builtin_amdgcn_s_barrier();                                             \
    __builtin_amdgcn_s_setprio(1);                                            \
    _Pragma("unroll")                                                         \
    for(int ks_=0;ks_<2;ks_++)                                                \
      _Pragma("unroll")                                                       \
      for(int i_=0;i_<4;i_++)                                                 \
        _Pragma("unroll")                                                     \
        for(int j_=0;j_<2;j_++)                                               \
          acc[(mh)*4+i_][(nh)*2+j_] =                                         \
            MFMA(a_[i_][ks_], b_[j_][ks_], acc[(mh)*4+i_][(nh)*2+j_]);        \
    __builtin_amdgcn_s_setprio(0);                                            \
    WAIT;                                                                     \
    __builtin_amdgcn_s_barrier();                                             \
  }while(0)

  STG(0,0); STG(0,1); STG(0,2); STG(0,3);
  ADVK();
  VM4;
  __builtin_amdgcn_s_barrier();

  for(int kt=0; kt<NSTEP-1; kt++){
    int p = kt&1;
    PHASE(0,0, 0, 1, VM4);
    PHASE(0,1, 1, 1, VM4);
    PHASE(1,0, 2, 1, (void)0);
    PHASE(1,1, 3, 1, VM4);
    if(kt < NSTEP-2) ADVK();
  }
  {
    int p = 0;
    PHASE(0,0, 0, 0, VM2);
    PHASE(0,1, 1, 0, VM0);
    PHASE(1,0, 2, 0, (void)0);
    PHASE(1,1, 3, 0, (void)0);
  }

  #undef PHASE
  #undef STG
  #undef ADVK

  __syncthreads();
  int* oo = (int*)LDSb;
  if(t < 256){
    int m = m0 + t; int b = m/196, s = m%196, y = s/14, x = s%14;
    oo[t] = ((b*16 + y+1)*16 + (x+1))*512;
  }
  __syncthreads();
  #pragma unroll
  for(int i=0;i<8;i++)
    #pragma unroll
    for(int j=0;j<4;j++){
      int n = n0 + wn*64 + j*16 + (l&15);
      #pragma unroll
      for(int r=0;r<4;r++){
        int mr = wm*128 + i*16 + (l>>4)*4 + r;
        Out[(size_t)oo[mr] + n] = f2b(acc[i][j][r]);
      }
    }
  __syncthreads();
  float* sred = (float*)LDSb;
  int rg = wm*4 + (l>>4);
  #pragma unroll
  for(int j=0;j<4;j++){
    float s=0.f, q=0.f;
    #pragma unroll
    for(int i=0;i<8;i++)
      #pragma unroll
      for(int r=0;r<4;r++){ float v = acc[i][j][r]; s += v; q += v*v; }
    int nl = wn*64 + j*16 + (l&15);
    sred[(nl*8 + rg)*2+0] = s;
    sred[(nl*8 + rg)*2+1] = q;
  }
  __syncthreads();
  if(t < 256){
    float s=0.f, q=0.f;
    #pragma unroll
    for(int rgi=0;rgi<8;rgi++){ s += sred[(t*8+rgi)*2]; q += sred[(t*8+rgi)*2+1]; }
    atomicAdd(&stats[n0+t], s);
    atomicAdd(&stats[512+n0+t], q);
  }
}

// ================= conv2: dy-split flat GEMM (K=1536 contiguous), f32 partials =================
// grid (196, 3): blockIdx.y = dy. 588 blocks -> 2.3 blocks/CU (TLP hides stage latency).
// PS[dy][6272][512] f32; taps at fixed dy are contiguous in padded NHWC (3*512).
__global__ __launch_bounds__(256) void k_conv2dy(
    const uint16_t* __restrict__ Ain, const uint16_t* __restrict__ Wb,
    float* __restrict__ PS)
{
  __shared__ __align__(16) uint16_t As[128*64];
  __shared__ __align__(16) uint16_t Bs[128*64];

  int t = threadIdx.x, w = t>>6, l = t&63;
  int dy = blockIdx.y;

  // bijective XCD-chunk swizzle: 196 wgs, Q8=24, R8=4
  int xcd = blockIdx.x & 7, pos = blockIdx.x >> 3;
  int wgid = (xcd < 4 ? xcd*25 : 100 + (xcd-4)*24) + pos;
  int n0 = (wgid / 49) * 128;
  int m0 = (wgid % 49) * 128;

  const uint16_t* aP[4];
  const uint16_t* bP[4];
  #pragma unroll
  for(int p=0;p<4;p++){
    int r = w*32 + p*8 + (l>>3);
    int m = m0 + r;
    int b = m/49, s = m%49, y = s/7, x = s%7;
    aP[p] = Ain + ((b*16 + 2*y + dy)*16 + 2*x)*512 + (l&7)*8;
    bP[p] = Wb + ((size_t)(dy*512 + n0 + r))*1536 + (l&7)*8;
  }

  facc acc[4][4];
  #pragma unroll
  for(int i=0;i<4;i++)
    #pragma unroll
    for(int j=0;j<4;j++) acc[i][j] = facc{0.f,0.f,0.f,0.f};
  int wm = w>>1, wn = w&1;
  char* asDst = (char*)As + w*4096;
  char* bsDst = (char*)Bs + w*4096;

  for(int stp=0; stp<24; stp++){
    #pragma unroll
    for(int p=0;p<4;p++){ gload16(aP[p], asDst + p*1024); aP[p] += 64; }
    #pragma unroll
    for(int p=0;p<4;p++){ gload16(bP[p], bsDst + p*1024); bP[p] += 64; }
    __syncthreads();
    #pragma unroll
    for(int ks=0;ks<2;ks++){
      bfrag a[4], b[4];
      #pragma unroll
      for(int i=0;i<4;i++)
        a[i] = *(const bfrag*)(As + (wm*64 + i*16 + (l&15))*64 + ks*32 + (l>>4)*8);
      #pragma unroll
      for(int j=0;j<4;j++)
        b[j] = *(const bfrag*)(Bs + (wn*64 + j*16 + (l&15))*64 + ks*32 + (l>>4)*8);
      #pragma unroll
      for(int i=0;i<4;i++)
        #pragma unroll
        for(int j=0;j<4;j++)
          acc[i][j] = MFMA(a[i], b[j], acc[i][j]);
    }
    __syncthreads();
  }

  float* out = PS + (size_t)dy*3211264;
  #pragma unroll
  for(int i=0;i<4;i++)
    #pragma unroll
    for(int j=0;j<4;j++){
      int n = n0 + wn*64 + j*16 + (l&15);
      #pragma unroll
      for(int r=0;r<4;r++){
        int mr = m0 + wm*64 + i*16 + (l>>4)*4 + r;
        out[(size_t)mr*512 + n] = acc[i][j][r];
      }
    }
}

// ---------------- sum conv2 dy-partials -> Y2 bf16 + BN2 stats ----------------
__global__ void k_bn2sum(const float* __restrict__ PS, uint16_t* __restrict__ Y2,
                         float* __restrict__ stats)
{
  int t = threadIdx.x;            // channel pair 2t, 2t+1
  int m0 = blockIdx.x*128;        // grid 49
  float s0=0,s1=0,q0=0,q1=0;
  for(int i=0;i<128;i++){
    size_t off = (size_t)(m0+i)*512 + 2*t;
    float2 p0 = *(const float2*)(PS + off);
    float2 p1 = *(const float2*)(PS + 3211264 + off);
    float2 p2 = *(const float2*)(PS + 6422528 + off);
    float a = p0.x+p1.x+p2.x, c = p0.y+p1.y+p2.y;
    s0+=a; q0+=a*a; s1+=c; q1+=c*c;
    *(uint32_t*)(Y2 + off) = (uint32_t)f2b(a) | ((uint32_t)f2b(c)<<16);
  }
  atomicAdd(&stats[2*t],   s0);
  atomicAdd(&stats[2*t+1], s1);
  atomicAdd(&stats[512+2*t],   q0);
  atomicAdd(&stats[512+2*t+1], q1);
}

// ---------------- kv 1x1 conv (single-buffer, flat GEMM) ----------------
__global__ __launch_bounds__(256) void k_convkv(
    const uint16_t* __restrict__ Ain, const uint16_t* __restrict__ Wb,
    uint16_t* __restrict__ Out)
{
  constexpr int CB = 512;
  constexpr int NB = 2048;
  constexpr int NWG = 49*16;              // 784, Q8=98, R8=0
  constexpr int Q8 = NWG/8;

  __shared__ __align__(16) uint16_t As[128*64];
  __shared__ __align__(16) uint16_t Bs[128*64];

  int t = threadIdx.x, w = t>>6, l = t&63;

  int xcd = blockIdx.x & 7, pos = blockIdx.x >> 3;
  int wgid = xcd*Q8 + pos;
  int n0 = (wgid / 49) * 128;
  int m0 = (wgid % 49) * 128;

  const uint16_t* aP[4];
  const uint16_t* bP[4];
  #pragma unroll
  for(int p=0;p<4;p++){
    int r = w*32 + p*8 + (l>>3);
    aP[p] = Ain + (size_t)(m0 + r)*512 + (l&7)*8;
    bP[p] = Wb + (size_t)(n0 + r)*CB + (l&7)*8;
  }

  facc acc[4][4];
  #pragma unroll
  for(int i=0;i<4;i++)
    #pragma unroll
    for(int j=0;j<4;j++) acc[i][j] = facc{0.f,0.f,0.f,0.f};
  int wm = w>>1, wn = w&1;
  char* asDst = (char*)As + w*4096;
  char* bsDst = (char*)Bs + w*4096;

  for(int cc=0; cc<8; cc++){
    #pragma unroll
    for(int p=0;p<4;p++){ gload16(aP[p], asDst + p*1024); aP[p] += 64; }
    #pragma unroll
    for(int p=0;p<4;p++){ gload16(bP[p], bsDst + p*1024); bP[p] += 64; }
    __syncthreads();
    #pragma unroll
    for(int ks=0;ks<2;ks++){
      bfrag a[4], b[4];
      #pragma unroll
      for(int i=0;i<4;i++)
        a[i] = *(const bfrag*)(As + (wm*64 + i*16 + (l&15))*64 + ks*32 + (l>>4)*8);
      #pragma unroll
      for(int j=0;j<4;j++)
        b[j] = *(const bfrag*)(Bs + (wn*64 + j*16 + (l&15))*64 + ks*32 + (l>>4)*8);
      #pragma unroll
      for(int i=0;i<4;i++)
        #pragma unroll
        for(int j=0;j<4;j++)
          acc[i][j] = MFMA(a[i], b[j], acc[i][j]);
    }
    __syncthreads();
  }

  #pragma unroll
  for(int i=0;i<4;i++)
    #pragma unroll
    for(int j=0;j<4;j++){
      int n = n0 + wn*64 + j*16 + (l&15);
      #pragma unroll
      for(int r=0;r<4;r++){
        int mr = m0 + wm*64 + i*16 + (l>>4)*4 + r;
        Out[(size_t)mr*2048 + n] = f2b(acc[i][j][r]);
      }
    }
}

// ---------------- BN apply + ReLU in-place; conv2 variant extracts center into egoT/feat ----------------
template<int PAD>
__global__ void k_bnapply(uint16_t* __restrict__ Y, const float* __restrict__ stats,
                          const float* __restrict__ gg, const float* __restrict__ bb,
                          int M, float invM,
                          uint16_t* __restrict__ egoT, uint16_t* __restrict__ feat)
{
  int t = threadIdx.x;
  int m0 = blockIdx.x*8;
  float mu0 = stats[2*t]*invM,       mu1 = stats[2*t+1]*invM;
  float v0 = stats[512+2*t]*invM - mu0*mu0, v1 = stats[512+2*t+1]*invM - mu1*mu1;
  float sc0 = gg[2*t]  *rsqrtf(v0+1e-5f), sc1 = gg[2*t+1]*rsqrtf(v1+1e-5f);
  float sh0 = bb[2*t]   - mu0*sc0,        sh1 = bb[2*t+1] - mu1*sc1;
  for(int i=0;i<8;i++){
    int m = m0+i; if(m>=M) break;
    size_t off;
    if(PAD){ int b=m/196, s=m%196, y=s/14, x=s%14; off = (((size_t)b*16+y+1)*16 + x+1)*512; }
    else off = (size_t)m*512;
    uint32_t u = *(const uint32_t*)(Y + off + 2*t);
    float a = fmaxf(b2f((uint16_t)u)*sc0 + sh0, 0.f);
    float c = fmaxf(b2f((uint16_t)(u>>16))*sc1 + sh1, 0.f);
    uint32_t pu = (uint32_t)f2b(a) | ((uint32_t)f2b(c)<<16);
    *(uint32_t*)(Y + off + 2*t) = pu;
    if(!PAD && (m%49)==24){
      int b = m/49;
      *(uint32_t*)(egoT + (size_t)b*576 + 2*t) = pu;
      *(uint32_t*)(feat + (size_t)b*1088 + 512 + 2*t) = pu;
    }
  }
}

// ---------------- small-M GEMM (M=128), no LDS ----------------
// flags: 1 = relu, 2 = f32 output (else bf16)
__global__ __launch_bounds__(256) void k_sgemm(
    const uint16_t* __restrict__ A, int lda,
    const uint16_t* __restrict__ B, int ldb,
    const float* __restrict__ bias,
    void* __restrict__ C, int ldc,
    int N, int K, int flags)
{
  int t = threadIdx.x, w = t>>6, l = t&63;
  int nt = blockIdx.x*4 + w;
  int n  = nt*16 + (l&15);
  int m0 = blockIdx.y*16;
  bool nv = n < N;
  facc acc = facc{0.f,0.f,0.f,0.f};
  for(int k=0;k<K;k+=32){
    bfrag af = *(const bfrag*)(A + (size_t)(m0+(l&15))*lda + k + (l>>4)*8);
    bfrag bf_ = {0,0,0,0,0,0,0,0};
    if(nv) bf_ = *(const bfrag*)(B + (size_t)n*ldb + k + (l>>4)*8);
    acc = MFMA(af, bf_, acc);
  }
  if(nv){
    float bv = bias ? bias[n] : 0.f;
    #pragma unroll
    for(int r=0;r<4;r++){
      int m = m0 + (l>>4)*4 + r;
      float v = acc[r] + bv;
      if(flags & 1) v = fmaxf(v, 0.f);
      if(flags & 2) ((float*)C)[(size_t)m*ldc + n] = v;
      else ((uint16_t*)C)[(size_t)m*ldc + n] = f2b(v);
    }
  }
}

// ---------------- attention: one wave per (b,h); ring handled analytically ----------------
__global__ __launch_bounds__(256) void k_attn(
    const float* __restrict__ q, const uint16_t* __restrict__ kv,
    uint16_t* __restrict__ o)
{
  int t = threadIdx.x, w = t>>6, l = t&63;
  int idx = blockIdx.x*4 + w;          // b*16+h
  int b = idx>>4, h = idx&15;
  float qf = q[(size_t)b*1024 + h*64 + l];
  const uint16_t* kp = kv + (size_t)b*49*2048 + h*64 + l;
  float eo = 0.f;
  for(int g=0; g<49; g++){
    float p = qf * b2f(kp[(size_t)g*2048]);
    for(int s=32;s>0;s>>=1) p += __shfl_xor(p, s);
    if(l == g) eo = p;
  }
  float e = (l<49) ? eo*(1.f/32.f) : -1e30f;
  float mx = e;
  for(int s=32;s>0;s>>=1) mx = fmaxf(mx, __shfl_xor(mx, s));
  mx = fmaxf(mx, 0.f);                          // 32 ring slots have energy 0
  float p = (l<49) ? __expf(e-mx) : 0.f;
  float den = p;
  for(int s=32;s>0;s>>=1) den += __shfl_xor(den, s);
  den += 32.f*__expf(-mx);
  const uint16_t* vp = kv + (size_t)b*49*2048 + 1024 + h*64 + l;
  float accv = 0.f;
  for(int g=0; g<49; g++){
    float pg = __shfl(p, g);
    accv += pg * b2f(vp[(size_t)g*2048]);
  }
  o[(size_t)b*1024 + h*64 + l] = f2b(accv/den);
}

// ---------------- trajectory: d2[b][25][16] @ tmat -> out [b][25][19][2] ----------------
__global__ void k_traj(const float* __restrict__ d2, const float* __restrict__ tm,
                       float* __restrict__ out)
{
  int i = blockIdx.x*256 + threadIdx.x;
  if(i >= 3200) return;
  const float* dp = d2 + (size_t)i*16;
  float cx[8], cy[8];
  #pragma unroll
  for(int j=0;j<8;j++){ cx[j]=dp[j]; cy[j]=dp[8+j]; }
  float* op = out + (size_t)i*38;
  for(int tt=0;tt<19;tt++){
    float x=0.f, y=0.f;
    #pragma unroll
    for(int j=0;j<8;j++){ float tv = tm[j*19+tt]; x += cx[j]*tv; y += cy[j]*tv; }
    op[tt*2+0]=x; op[tt*2+1]=y;
  }
}

// ======================= host =======================
extern "C" void kernel_launch(void* const* d_in, const int* in_sizes, int n_in,
                              void* d_out, int out_size, void* d_ws, size_t ws_size,
                              hipStream_t stream)
{
  const float* cnn      = (const float*)d_in[0];
  const float* ego_seq  = (const float*)d_in[1];
  const float* ag_seq   = (const float*)d_in[2];
  const int*   ego_len  = (const int*)d_in[3];
  const int*   ag_len   = (const int*)d_in[4];
  const int*   grid_pos = (const int*)d_in[5];
  const float* sW  = (const float*)d_in[6];
  const float* sb  = (const float*)d_in[7];
  const float* Wih = (const float*)d_in[8];
  const float* Whh = (const float*)d_in[9];
  const float* bih = (const float*)d_in[10];
  const float* bhh = (const float*)d_in[11];
  const float* encW = (const float*)d_in[12];
  const float* encB = (const float*)d_in[13];
  const float* conv1W = (const float*)d_in[14];
  const float* bn1g = (const float*)d_in[15];
  const float* bn1b = (const float*)d_in[16];
  const float* conv2W = (const float*)d_in[17];
  const float* bn2g = (const float*)d_in[18];
  const float* bn2b = (const float*)d_in[19];
  const float* qWf  = (const float*)d_in[20];
  const float* kWf  = (const float*)d_in[21];
  const float* vWf  = (const float*)d_in[22];
  const float* aoW  = (const float*)d_in[23];
  const float* aoB  = (const float*)d_in[24];
  const float* clsWf = (const float*)d_in[25];
  const float* clsB  = (const float*)d_in[26];
  const float* d1Wf  = (const float*)d_in[27];
  const float* d1B   = (const float*)d_in[28];
  const float* d2Wf  = (const float*)d_in[29];
  const float* d2B   = (const float*)d_in[30];

  char* ws = (char*)d_ws;
  const size_t XP_OFF   = 0;                 // 71,303,168 (dead after conv1)
  const size_t PS_OFF   = 0;                 // 38,535,168 f32 partials (alias in XP)
  const size_t KV_OFF   = 0;                 // 25,690,112 (alias; after PS dead)
  const size_t Y2_OFF   = 41943040;          // 6,422,528 (inside old XP, after PS)
  const size_t Y1P_OFF  = 71303168;          // 33,554,432
  const size_t WP1_OFF  = 104857600;
  const size_t WP2_OFF  = 114884608;         // 4,718,592 (3*512*1536*2)
  const size_t WKV_OFF  = 119603200;
  const size_t QW_OFF   = 121700352;
  const size_t AOW_OFF  = 122880000;
  const size_t CLSW_OFF = 123928576;
  const size_t D1W_OFF  = 123982976;
  const size_t D2W_OFF  = 124540032;
  const size_t GRID_OFF = 124744832;
  const size_t EGOT_OFF = 131167360;
  const size_t FEAT_OFF = 131314816;
  const size_t QBUF_OFF = 131593344;
  const size_t OBUF_OFF = 132117632;
  const size_t D1_OFF   = 132379776;
  const size_t D2_OFF   = 132445312;
  const size_t WC_OFF   = 132650112;
  const size_t BE_OFF   = 132699264;
  const size_t ENCW_OFF = 132700288;
  const size_t TMAT_OFF = 132708480;
  const size_t ST1_OFF  = 132709120;         // sum 512 + sumsq 512
  const size_t ST2_OFF  = 132713216;

  uint16_t* XP   = (uint16_t*)(ws + XP_OFF);
  float*    PS   = (float*)(ws + PS_OFF);
  uint16_t* KV   = (uint16_t*)(ws + KV_OFF);
  uint16_t* Y2   = (uint16_t*)(ws + Y2_OFF);
  uint16_t* Y1P  = (uint16_t*)(ws + Y1P_OFF);
  uint16_t* WP1  = (uint16_t*)(ws + WP1_OFF);
  uint16_t* WP2  = (uint16_t*)(ws + WP2_OFF);
  uint16_t* WKV  = (uint16_t*)(ws + WKV_OFF);
  uint16_t* QW   = (uint16_t*)(ws + QW_OFF);
  uint16_t* AOW  = (uint16_t*)(ws + AOW_OFF);
  uint16_t* CLSW = (uint16_t*)(ws + CLSW_OFF);
  uint16_t* D1W  = (uint16_t*)(ws + D1W_OFF);
  uint16_t* D2W  = (uint16_t*)(ws + D2W_OFF);
  float*    GRIDB= (float*)(ws + GRID_OFF);
  uint16_t* EGOT = (uint16_t*)(ws + EGOT_OFF);
  uint16_t* FEAT = (uint16_t*)(ws + FEAT_OFF);
  float*    QBUF = (float*)(ws + QBUF_OFF);
  uint16_t* OBUF = (uint16_t*)(ws + OBUF_OFF);
  uint16_t* D1B  = (uint16_t*)(ws + D1_OFF);
  float*    D2B  = (float*)(ws + D2_OFF);
  uint16_t* WC   = (uint16_t*)(ws + WC_OFF);
  float*    BE   = (float*)(ws + BE_OFF);
  uint16_t* ENCWB= (uint16_t*)(ws + ENCW_OFF);
  float*    TMAT = (float*)(ws + TMAT_OFF);
  float*    ST1  = (float*)(ws + ST1_OFF);
  float*    ST2  = (float*)(ws + ST2_OFF);
  float*    outF = (float*)d_out;

  (void)hipMemsetAsync(ws + GRID_OFF, 0, 6422528, stream);
  (void)hipMemsetAsync(ws + ST1_OFF,  0, 8192, stream);

  // border zeros for both padded buffers (one launch)
  k_zborder<<<256,256,0,stream>>>(XP, Y1P);

  // constants / weight packs
  k_lstm_prep<<<1,256,0,stream>>>(Wih,Whh,bih,bhh,sW,sb,encW, WC,BE,ENCWB, TMAT);
  k_packw<<<dim3(512,17),64,0,stream>>>(conv1W, WP1, 512, 1088);
  k_packw2<<<dim3(512,8),64,0,stream>>>(conv2W, WP2);
  {
    F2BJobs jb;
    jb.s[0]=kWf;  jb.d[0]=WKV;              jb.n[0]=1024*512;
    jb.s[1]=vWf;  jb.d[1]=WKV + 1024*512;   jb.n[1]=1024*512;
    jb.s[2]=qWf;  jb.d[2]=QW;               jb.n[2]=1024*576;
    jb.s[3]=aoW;  jb.d[3]=AOW;              jb.n[3]=512*1024;
    jb.s[4]=clsWf;jb.d[4]=CLSW;             jb.n[4]=25*1088;
    jb.s[5]=d1Wf; jb.d[5]=D1W;              jb.n[5]=256*1088;
    jb.s[6]=d2Wf; jb.d[6]=D2W;              jb.n[6]=400*256;
    k_f2b_multi<<<dim3(48,7),256,0,stream>>>(jb);
  }

  // encoders + scatter
  k_lstm<<<132,256,0,stream>>>(ego_seq, ag_seq, ego_len, ag_len, grid_pos,
                               WC, BE, ENCWB, encB, GRIDB, EGOT, FEAT);
  // conv input pack
  k_packx<<<dim3(128,34),256,0,stream>>>(cnn, GRIDB, XP);
  // conv1 (8-phase 256², +stats) -> BN1 -> relu (in place, padded)
  k_conv1_8p<<<196,512,0,stream>>>(XP, WP1, Y1P, ST1);
  k_bnapply<1><<<3136,256,0,stream>>>(Y1P, ST1, bn1g, bn1b, 25088, 1.f/25088.f, nullptr, nullptr);
  // conv2: dy-split f32 partials -> sum+stats -> BN2 apply (+ center -> egoT/feat)
  k_conv2dy<<<dim3(196,3),256,0,stream>>>(Y1P, WP2, PS);
  k_bn2sum<<<49,256,0,stream>>>(PS, Y2, ST2);
  k_bnapply<0><<<784,256,0,stream>>>(Y2, ST2, bn2g, bn2b, 6272, 1.f/6272.f, EGOT, FEAT);
  // k,v 1x1 convs
  k_convkv<<<784,256,0,stream>>>(Y2, WKV, KV);
  // q = egoT @ qW^T  (f32 out)
  k_sgemm<<<dim3(16,8),256,0,stream>>>(EGOT, 576, QW, 576, nullptr, QBUF, 1024, 1024, 576, 2);
  // attention
  k_attn<<<512,256,0,stream>>>(QBUF, KV, OBUF);
  // attn_out -> feat[:,0:512]
  k_sgemm<<<dim3(8,8),256,0,stream>>>(OBUF, 1024, AOW, 1024, aoB, FEAT, 1088, 512, 1024, 0);
  // conf -> d_out[121600:]
  k_sgemm<<<dim3(1,8),256,0,stream>>>(FEAT, 1088, CLSW, 1088, clsB, outF + 121600, 25, 25, 1088, 2);
  // dec1 (relu) -> dec2 -> traj
  k_sgemm<<<dim3(4,8),256,0,stream>>>(FEAT, 1088, D1W, 1088, d1B, D1B, 256, 256, 1088, 1);
  k_sgemm<<<dim3(7,8),256,0,stream>>>(D1B, 256, D2W, 256, d2B, D2B, 400, 400, 256, 2);
  k_traj<<<13,256,0,stream>>>(D2B, TMAT, outF);

  (void)in_sizes; (void)n_in; (void)out_size; (void)ws_size;
}

// Round 8
// 629.557 us; speedup vs baseline: 1.2944x; 1.0552x over previous
//
#include <hip/hip_runtime.h>
#include <stdint.h>
#include <stddef.h>

#define DEVINL static __device__ __forceinline__

typedef __attribute__((ext_vector_type(8))) short  bfrag;   // 8x bf16 (bits)
typedef __attribute__((ext_vector_type(4))) float  facc;    // MFMA accumulator

DEVINL uint16_t f2b(float f){
  uint32_t u = __float_as_uint(f);
  return (uint16_t)((u + 0x7fffu + ((u >> 16) & 1u)) >> 16);   // RNE
}
DEVINL float b2f(uint16_t b){ return __uint_as_float(((uint32_t)b) << 16); }

DEVINL facc MFMA(bfrag a, bfrag b, facc c){
  return __builtin_amdgcn_mfma_f32_16x16x32_bf16(a, b, c, 0, 0, 0);
}

// async global->LDS, 16B per lane; LDS dest = wave-uniform base + lane*16
DEVINL void gload16(const void* g, void* l){
  __builtin_amdgcn_global_load_lds(
      (const __attribute__((address_space(1))) uint32_t*)g,
      (__attribute__((address_space(3))) uint32_t*)l, 16, 0, 0);
}

DEVINL float fast_tanh(float x){           // tanh = 2*sigmoid(2x)-1
  return 2.f/(1.f+__expf(-2.f*x)) - 1.f;
}

// ---------------- multi-buffer f32 -> bf16 convert (one launch) ----------------
struct F2BJobs {
  const float* s[7];
  uint16_t*    d[7];
  int          n[7];
};
__global__ void k_f2b_multi(F2BJobs jobs){
  int j = blockIdx.y;
  const float* s = jobs.s[j];
  uint16_t* d = jobs.d[j];
  int n = jobs.n[j];
  int i = blockIdx.x*256 + threadIdx.x;
  int st = gridDim.x*256;
  for(; i<n; i+=st) d[i] = f2b(s[i]);
}

// ---------------- zero border pixels of padded [128][16][16][C] (both buffers) ----------------
__global__ void k_zborder(uint16_t* __restrict__ X, uint16_t* __restrict__ Y){
  int b = blockIdx.x & 127, t = threadIdx.x;
  uint16_t* base = (blockIdx.x < 128) ? X : Y;
  int C = (blockIdx.x < 128) ? 1088 : 512;
  for(int p=0;p<60;p++){
    int y, x;
    if(p<16){ y=0; x=p; }
    else if(p<32){ y=15; x=p-16; }
    else { int q=p-32; y=1+(q>>1); x=(q&1)?15:0; }
    uint32_t* dst = (uint32_t*)(base + ((size_t)(b*16+y)*16 + x)*C);
    for(int i=t;i<C/2;i+=256) dst[i] = 0;
  }
}

// ---------------- LSTM weight prep + Legendre tmat ----------------
__global__ void k_lstm_prep(const float* __restrict__ Wih, const float* __restrict__ Whh,
                            const float* __restrict__ bih, const float* __restrict__ bhh,
                            const float* __restrict__ sW, const float* __restrict__ sb,
                            const float* __restrict__ encW,
                            uint16_t* __restrict__ Wc, float* __restrict__ be,
                            uint16_t* __restrict__ encWb, float* __restrict__ tm){
  int n = threadIdx.x;
  if(n < 19){
    float tv = (float)(n - 6) / 12.0f;
    float Pm = 1.0f, Pc = tv;
    tm[0*19+n] = Pm * sqrtf(0.5f);
    tm[1*19+n] = Pc * sqrtf(1.5f);
    for(int q=1; q<7; q++){
      float Pn = ((float)(2*q+1)*tv*Pc - (float)q*Pm) / (float)(q+1);
      Pm = Pc; Pc = Pn;
      tm[(q+1)*19+n] = Pc * sqrtf((float)(2*(q+1)+1) * 0.5f);
    }
  }
  for(int k=0;k<64;k++) Wc[n*96+k] = f2b(Whh[n*64+k]);
  for(int k5=0;k5<5;k5++){
    float s = 0.f;
    for(int j=0;j<64;j++) s += Wih[n*64+j]*sW[j*5+k5];
    Wc[n*96+64+k5] = f2b(s);
  }
  for(int k=69;k<96;k++) Wc[n*96+k] = 0;
  float s = 0.f;
  for(int j=0;j<64;j++) s += Wih[n*64+j]*sb[j];
  be[n] = s + bih[n] + bhh[n];
  if(n < 64){
    for(int k=0;k<64;k++) encWb[n*64+k] = f2b(encW[n*64+k]);
  }
}

// ---------------- LSTM: 32 sequences / block, MFMA gates ----------------
__global__ __launch_bounds__(256) void k_lstm(
    const float* __restrict__ ego_seq, const float* __restrict__ ag_seq,
    const int* __restrict__ ego_len, const int* __restrict__ ag_len,
    const int* __restrict__ grid_pos,
    const uint16_t* __restrict__ Wc, const float* __restrict__ be,
    const uint16_t* __restrict__ encWb, const float* __restrict__ encB,
    float* __restrict__ agrid, uint16_t* __restrict__ egoT, uint16_t* __restrict__ feat)
{
  __shared__ __align__(16) uint16_t A[32*96];   // [seq][k] : k<64 h, 64..68 x_t, 69..95 zero
  __shared__ float Xf[32*160];                  // raw seq f32 [32][32][5]
  __shared__ int   idxs[32];

  int t = threadIdx.x, w = t>>6, l = t&63;
  int blk = blockIdx.x;
  bool isEgo = blk < 4;
  int seq0 = isEgo ? blk*32 : (blk-4)*32;
  const float* seqp = (isEgo ? ego_seq : ag_seq) + (size_t)seq0*160;

  for(int i=t;i<32*160;i+=256) Xf[i] = seqp[i];
  if(t < 32){
    int L = isEgo ? ego_len[seq0+t] : ag_len[seq0+t];
    if(L < 1) L = 1;
    idxs[t] = L-1;
  }
  for(int i=t;i<32*96;i+=256) A[i] = 0;

  bfrag bf[4][3];
  float be4[4];
  for(int ct=0;ct<4;ct++){
    int n = (ct*4+w)*16 + (l&15);
    for(int ks=0;ks<3;ks++)
      bf[ct][ks] = *(const bfrag*)(Wc + n*96 + ks*32 + (l>>4)*8);
    be4[ct] = be[n];
  }
  float cst[8], hl[8];
  for(int i=0;i<8;i++){ cst[i]=0.f; hl[i]=0.f; }
  __syncthreads();
  int myidx[8];
  for(int rt=0;rt<2;rt++) for(int r=0;r<4;r++){
    int s = rt*16 + (l>>4)*4 + r;
    myidx[rt*4+r] = idxs[s];
  }

  for(int st=0; st<32; st++){
    if(t < 160){ int s=t/5, kk=t%5; A[s*96+64+kk] = f2b(Xf[s*160 + st*5 + kk]); }
    __syncthreads();
    facc acc[2][4];
    for(int rt=0;rt<2;rt++) for(int ct=0;ct<4;ct++) acc[rt][ct] = facc{0.f,0.f,0.f,0.f};
    #pragma unroll
    for(int ks=0;ks<3;ks++){
      bfrag aA[2];
      #pragma unroll
      for(int rt=0;rt<2;rt++)
        aA[rt] = *(const bfrag*)(A + (rt*16+(l&15))*96 + ks*32 + (l>>4)*8);
      #pragma unroll
      for(int rt=0;rt<2;rt++)
        #pragma unroll
        for(int ct=0;ct<4;ct++)
          acc[rt][ct] = MFMA(aA[rt], bf[ct][ks], acc[rt][ct]);
    }
    __syncthreads();   // all A reads done before h overwrite
    #pragma unroll
    for(int rt=0;rt<2;rt++) for(int r=0;r<4;r++){
      int cell = rt*4+r;
      int s = rt*16 + (l>>4)*4 + r;
      float gi = acc[rt][0][r] + be4[0];
      float gf = acc[rt][1][r] + be4[1];
      float gg = acc[rt][2][r] + be4[2];
      float go = acc[rt][3][r] + be4[3];
      float si = 1.f/(1.f+__expf(-gi));
      float sf = 1.f/(1.f+__expf(-gf));
      float so = 1.f/(1.f+__expf(-go));
      float tg = fast_tanh(gg);
      float c2 = sf*cst[cell] + si*tg;
      cst[cell] = c2;
      float hn = so*fast_tanh(c2);
      A[s*96 + w*16 + (l&15)] = f2b(hn);
      if(st == myidx[cell]) hl[cell] = hn;
    }
  }
  __syncthreads();
  for(int rt=0;rt<2;rt++) for(int r=0;r<4;r++){
    int s = rt*16 + (l>>4)*4 + r;
    A[s*96 + w*16 + (l&15)] = f2b(hl[rt*4+r]);
  }
  __syncthreads();
  bfrag eb[2];
  for(int ks=0;ks<2;ks++)
    eb[ks] = *(const bfrag*)(encWb + (w*16+(l&15))*64 + ks*32 + (l>>4)*8);
  facc ea[2]; ea[0] = facc{0.f,0.f,0.f,0.f}; ea[1] = facc{0.f,0.f,0.f,0.f};
  for(int ks=0;ks<2;ks++){
    for(int rt=0;rt<2;rt++){
      bfrag aA = *(const bfrag*)(A + (rt*16+(l&15))*96 + ks*32 + (l>>4)*8);
      ea[rt] = MFMA(aA, eb[ks], ea[rt]);
    }
  }
  int n = w*16 + (l&15);
  float bn_ = encB[n];
  for(int rt=0;rt<2;rt++) for(int r=0;r<4;r++){
    int s = rt*16 + (l>>4)*4 + r;
    float v = ea[rt][r] + bn_;
    int gs = seq0 + s;
    if(isEgo){
      egoT[(size_t)gs*576 + 512 + n] = f2b(v);
      feat[(size_t)gs*1088 + 1024 + n] = f2b(v);
    } else {
      int py = grid_pos[gs*2+0], px = grid_pos[gs*2+1];
      atomicAdd(&agrid[((size_t)(gs>>5)*196 + py*14 + px)*64 + n], v);
    }
  }
}

// ---------------- pack conv1 input: NCHW f32 (+grid NHWC f32) -> padded NHWC bf16 ----------------
__global__ void k_packx(const float* __restrict__ cnn, const float* __restrict__ agrid,
                        uint16_t* __restrict__ Xp)
{
  __shared__ float tile[32*200];
  int b = blockIdx.x, ch = blockIdx.y, t = threadIdx.x;
  if(ch < 32){
    int c0 = ch*32;
    for(int i=t;i<32*196;i+=256){
      int ci = i/196, s = i%196;
      tile[ci*200+s] = cnn[((size_t)b*1024 + c0+ci)*196 + s];
    }
    __syncthreads();
    for(int i=t;i<32*196;i+=256){
      int s = i>>5, ci = i&31;
      int y = s/14, x = s%14;
      Xp[(((size_t)b*16 + y+1)*16 + x+1)*1088 + c0 + ci] = f2b(tile[ci*200+s]);
    }
  } else {
    int j0 = (ch-32)*32;
    for(int i=t;i<32*196;i+=256){
      int s = i>>5, ji = i&31;
      int y = s/14, x = s%14;
      Xp[(((size_t)b*16 + y+1)*16 + x+1)*1088 + 1024 + j0 + ji] =
          f2b(agrid[((size_t)b*196 + s)*64 + j0 + ji]);
    }
  }
}

// ---------------- pack conv1 weights OIHW f32 -> [dydx][O][C] bf16 ----------------
__global__ void k_packw(const float* __restrict__ W, uint16_t* __restrict__ Wp, int O, int C)
{
  int o = blockIdx.x;
  int c = blockIdx.y*64 + threadIdx.x;
  const float* src = W + ((size_t)o*C + c)*9;
  float v[9];
  #pragma unroll
  for(int d=0;d<9;d++) v[d] = src[d];
  #pragma unroll
  for(int d=0;d<9;d++)
    Wp[((size_t)d*O + o)*C + c] = f2b(v[d]);
}

// ---------------- pack conv2 weights OIHW -> [dy][O][dx*512+c] bf16 (flat K=1536 per dy) ----------------
__global__ void k_packw2(const float* __restrict__ W, uint16_t* __restrict__ Wp)
{
  int o = blockIdx.x;
  int c = blockIdx.y*64 + threadIdx.x;
  const float* src = W + ((size_t)o*512 + c)*9;
  float v[9];
  #pragma unroll
  for(int d=0;d<9;d++) v[d] = src[d];
  #pragma unroll
  for(int dy=0;dy<3;dy++)
    #pragma unroll
    for(int dx=0;dx<3;dx++)
      Wp[((size_t)(dy*512 + o))*1536 + dx*512 + c] = f2b(v[dy*3+dx]);
}

// ================= conv1: 256x256 8-phase pipelined implicit GEMM =================
// R7: operand-reuse phase order (0,0)->(0,1)->(1,1)->(1,0) with persistent register
// fragments: LDS reads per K-step drop 48->28 b128/wave. Stage schedule and vmcnt
// ledger IDENTICAL to R6 (verified); K-order per acc element unchanged (canary).
__global__ __launch_bounds__(512) void k_conv1_8p(
    const uint16_t* __restrict__ Ain, const uint16_t* __restrict__ Wb,
    uint16_t* __restrict__ Out, float* __restrict__ stats)
{
  constexpr int CB = 1088;
  constexpr int NSTEP = 153;          // 17 cc x 9 taps
  __shared__ __align__(16) char LDSb[131072];

  int t = threadIdx.x, w = t>>6, l = t&63;
  int wm = w>>2, wn = w&3;

  int xcd = blockIdx.x & 7, pos = blockIdx.x >> 3;
  int wgid = (xcd < 4 ? xcd*25 : 100 + (xcd-4)*24) + pos;
  int m0 = (wgid % 98) * 256;
  int n0 = (wgid / 98) * 256;

  const uint16_t* aP[2][2];
  const uint16_t* bP[2][2];
  #pragma unroll
  for(int P=0;P<2;P++)
    #pragma unroll
    for(int j=0;j<2;j++){
      int partrow = j*64 + (t>>3);
      int swz = ((t&7) ^ (partrow&7))*8;            // elements
      int gr = P*64 + partrow + ((partrow>=64)?64:0);
      int m = m0 + gr; int b = m/196, s = m%196, y = s/14, x = s%14;
      aP[P][j] = Ain + ((b*16+y)*16+x)*CB + swz;
      int nb = n0 + (partrow>>5)*64 + P*32 + (partrow&31);
      bP[P][j] = Wb + (size_t)nb*CB + swz;
    }

  facc acc[8][4];
  #pragma unroll
  for(int i=0;i<8;i++)
    #pragma unroll
    for(int j=0;j<4;j++) acc[i][j] = facc{0.f,0.f,0.f,0.f};

  bfrag aF[4][2], bF[2][2];      // persistent operand fragments
  int dd = 0;

  #define STG(buf, PART) do{                                                   \
    if((PART)==0 || (PART)==3){ const int P_ = ((PART)==3);                    \
      _Pragma("unroll")                                                        \
      for(int j_=0;j_<2;j_++)                                                  \
        gload16(aP[P_][j_], LDSb + (buf)*65536 + P_*16384 + j_*8192 + w*1024); \
    } else { const int P_ = ((PART)==2);                                       \
      _Pragma("unroll")                                                        \
      for(int j_=0;j_<2;j_++)                                                  \
        gload16(bP[P_][j_], LDSb + (buf)*65536 + 32768 + P_*16384 + j_*8192 + w*1024); \
    }                                                                          \
  }while(0)

  #define ADVK() do{                                                          \
    if(dd==8){                                                                \
      _Pragma("unroll")                                                       \
      for(int P_=0;P_<2;P_++) for(int j_=0;j_<2;j_++){                        \
        aP[P_][j_] += 64 - 34*CB; bP[P_][j_] += 64 - 8*512*CB; }              \
      dd = 0;                                                                 \
    } else {                                                                  \
      int sA_ = (dd==2||dd==5) ? 14*CB : CB;                                  \
      _Pragma("unroll")                                                       \
      for(int P_=0;P_<2;P_++) for(int j_=0;j_<2;j_++){                        \
        aP[P_][j_] += sA_; bP[P_][j_] += 512*CB; }                            \
      dd++;                                                                   \
    }                                                                         \
  }while(0)

  #define VM4 asm volatile("s_waitcnt vmcnt(4)" ::: "memory")
  #define VM2 asm volatile("s_waitcnt vmcnt(2)" ::: "memory")
  #define VM0 asm volatile("s_waitcnt vmcnt(0)" ::: "memory")

  #define LDA(mh) do{                                                         \
    const uint16_t* Ab_ = (const uint16_t*)(LDSb + p*65536 + (mh)*16384);     \
    _Pragma("unroll")                                                         \
    for(int i_=0;i_<4;i_++)                                                   \
      _Pragma("unroll")                                                       \
      for(int ks_=0;ks_<2;ks_++)                                              \
        aF[i_][ks_] = *(const bfrag*)(Ab_ + (wm*64 + i_*16 + (l&15))*64       \
                        + ((ks_*32 + (l>>4)*8) ^ ((l&7)<<3)));                \
  }while(0)

  #define LDB(nh) do{                                                         \
    const uint16_t* Bb_ = (const uint16_t*)(LDSb + p*65536 + 32768 + (nh)*16384); \
    _Pragma("unroll")                                                         \
    for(int j_=0;j_<2;j_++)                                                   \
      _Pragma("unroll")                                                       \
      for(int ks_=0;ks_<2;ks_++)                                              \
        bF[j_][ks_] = *(const bfrag*)(Bb_ + (wn*32 + j_*16 + (l&15))*64       \
                        + ((ks_*32 + (l>>4)*8) ^ ((l&7)<<3)));                \
  }while(0)

  #define MM(mh, nh) do{                                                      \
    __builtin_amdgcn_s_setprio(1);                                            \
    _Pragma("unroll")                                                         \
    for(int ks_=0;ks_<2;ks_++)                                                \
      _Pragma("unroll")                                                       \
      for(int i_=0;i_<4;i_++)                                                 \
        _Pragma("unroll")                                                     \
        for(int j_=0;j_<2;j_++)                                               \
          acc[(mh)*4+i_][(nh)*2+j_] =                                         \
            MFMA(aF[i_][ks_], bF[j_][ks_], acc[(mh)*4+i_][(nh)*2+j_]);        \
    __builtin_amdgcn_s_setprio(0);                                            \
  }while(0)

  #define BARS do{ __builtin_amdgcn_sched_barrier(0); __builtin_amdgcn_s_barrier(); }while(0)
  #define EBAR __builtin_amdgcn_s_barrier()

  // prologue: stage K-tile 0 (A0,B0,B1,A1) into buf0
  STG(0,0); STG(0,1); STG(0,2); STG(0,3);
  ADVK();
  VM4;
  EBAR;

  for(int kt=0; kt<NSTEP-1; kt++){
    int p = kt&1;
    LDA(0); LDB(0); STG(p^1,0); BARS; MM(0,0); VM4; EBAR;
    LDB(1);         STG(p^1,1); BARS; MM(0,1); VM4; EBAR;
    LDA(1);         STG(p^1,2); BARS; MM(1,1);      EBAR;
    LDB(0);         STG(p^1,3); BARS; MM(1,0); VM4; EBAR;
    if(kt < NSTEP-2) ADVK();
  }
  { // peeled last K-tile (buf 0), no staging, drain
    int p = 0;
    LDA(0); LDB(0); BARS; MM(0,0); VM2; EBAR;
    LDB(1);         BARS; MM(0,1); VM0; EBAR;
    LDA(1);         BARS; MM(1,1);      EBAR;
    LDB(0);         BARS; MM(1,0);      EBAR;
  }

  #undef LDA
  #undef LDB
  #undef MM
  #undef BARS
  #undef EBAR
  #undef STG
  #undef ADVK

  __syncthreads();
  int* oo = (int*)LDSb;
  if(t < 256){
    int m = m0 + t; int b = m/196, s = m%196, y = s/14, x = s%14;
    oo[t] = ((b*16 + y+1)*16 + (x+1))*512;
  }
  __syncthreads();
  #pragma unroll
  for(int i=0;i<8;i++)
    #pragma unroll
    for(int j=0;j<4;j++){
      int n = n0 + wn*64 + j*16 + (l&15);
      #pragma unroll
      for(int r=0;r<4;r++){
        int mr = wm*128 + i*16 + (l>>4)*4 + r;
        Out[(size_t)oo[mr] + n] = f2b(acc[i][j][r]);
      }
    }
  __syncthreads();
  float* sred = (float*)LDSb;
  int rg = wm*4 + (l>>4);
  #pragma unroll
  for(int j=0;j<4;j++){
    float s=0.f, q=0.f;
    #pragma unroll
    for(int i=0;i<8;i++)
      #pragma unroll
      for(int r=0;r<4;r++){ float v = acc[i][j][r]; s += v; q += v*v; }
    int nl = wn*64 + j*16 + (l&15);
    sred[(nl*8 + rg)*2+0] = s;
    sred[(nl*8 + rg)*2+1] = q;
  }
  __syncthreads();
  if(t < 256){
    float s=0.f, q=0.f;
    #pragma unroll
    for(int rgi=0;rgi<8;rgi++){ s += sred[(t*8+rgi)*2]; q += sred[(t*8+rgi)*2+1]; }
    atomicAdd(&stats[n0+t], s);
    atomicAdd(&stats[512+n0+t], q);
  }
}

// ================= conv2: dy-split flat GEMM (K=1536 contiguous), f32 partials =================
__global__ __launch_bounds__(256) void k_conv2dy(
    const uint16_t* __restrict__ Ain, const uint16_t* __restrict__ Wb,
    float* __restrict__ PS)
{
  __shared__ __align__(16) uint16_t As[128*64];
  __shared__ __align__(16) uint16_t Bs[128*64];

  int t = threadIdx.x, w = t>>6, l = t&63;
  int dy = blockIdx.y;

  int xcd = blockIdx.x & 7, pos = blockIdx.x >> 3;
  int wgid = (xcd < 4 ? xcd*25 : 100 + (xcd-4)*24) + pos;
  int n0 = (wgid / 49) * 128;
  int m0 = (wgid % 49) * 128;

  const uint16_t* aP[4];
  const uint16_t* bP[4];
  #pragma unroll
  for(int p=0;p<4;p++){
    int r = w*32 + p*8 + (l>>3);
    int m = m0 + r;
    int b = m/49, s = m%49, y = s/7, x = s%7;
    aP[p] = Ain + ((b*16 + 2*y + dy)*16 + 2*x)*512 + (l&7)*8;
    bP[p] = Wb + ((size_t)(dy*512 + n0 + r))*1536 + (l&7)*8;
  }

  facc acc[4][4];
  #pragma unroll
  for(int i=0;i<4;i++)
    #pragma unroll
    for(int j=0;j<4;j++) acc[i][j] = facc{0.f,0.f,0.f,0.f};
  int wm = w>>1, wn = w&1;
  char* asDst = (char*)As + w*4096;
  char* bsDst = (char*)Bs + w*4096;

  for(int stp=0; stp<24; stp++){
    #pragma unroll
    for(int p=0;p<4;p++){ gload16(aP[p], asDst + p*1024); aP[p] += 64; }
    #pragma unroll
    for(int p=0;p<4;p++){ gload16(bP[p], bsDst + p*1024); bP[p] += 64; }
    __syncthreads();
    #pragma unroll
    for(int ks=0;ks<2;ks++){
      bfrag a[4], b[4];
      #pragma unroll
      for(int i=0;i<4;i++)
        a[i] = *(const bfrag*)(As + (wm*64 + i*16 + (l&15))*64 + ks*32 + (l>>4)*8);
      #pragma unroll
      for(int j=0;j<4;j++)
        b[j] = *(const bfrag*)(Bs + (wn*64 + j*16 + (l&15))*64 + ks*32 + (l>>4)*8);
      #pragma unroll
      for(int i=0;i<4;i++)
        #pragma unroll
        for(int j=0;j<4;j++)
          acc[i][j] = MFMA(a[i], b[j], acc[i][j]);
    }
    __syncthreads();
  }

  float* out = PS + (size_t)dy*3211264;
  #pragma unroll
  for(int i=0;i<4;i++)
    #pragma unroll
    for(int j=0;j<4;j++){
      int n = n0 + wn*64 + j*16 + (l&15);
      #pragma unroll
      for(int r=0;r<4;r++){
        int mr = m0 + wm*64 + i*16 + (l>>4)*4 + r;
        out[(size_t)mr*512 + n] = acc[i][j][r];
      }
    }
}

// ---------------- sum conv2 dy-partials -> Y2 bf16 + BN2 stats ----------------
__global__ void k_bn2sum(const float* __restrict__ PS, uint16_t* __restrict__ Y2,
                         float* __restrict__ stats)
{
  int t = threadIdx.x;            // channel pair 2t, 2t+1
  int m0 = blockIdx.x*16;         // grid 392
  float s0=0,s1=0,q0=0,q1=0;
  for(int i=0;i<16;i++){
    size_t off = (size_t)(m0+i)*512 + 2*t;
    float2 p0 = *(const float2*)(PS + off);
    float2 p1 = *(const float2*)(PS + 3211264 + off);
    float2 p2 = *(const float2*)(PS + 6422528 + off);
    float a = p0.x+p1.x+p2.x, c = p0.y+p1.y+p2.y;
    s0+=a; q0+=a*a; s1+=c; q1+=c*c;
    *(uint32_t*)(Y2 + off) = (uint32_t)f2b(a) | ((uint32_t)f2b(c)<<16);
  }
  atomicAdd(&stats[2*t],   s0);
  atomicAdd(&stats[2*t+1], s1);
  atomicAdd(&stats[512+2*t],   q0);
  atomicAdd(&stats[512+2*t+1], q1);
}

// ---------------- kv 1x1 conv (single-buffer, flat GEMM) ----------------
__global__ __launch_bounds__(256) void k_convkv(
    const uint16_t* __restrict__ Ain, const uint16_t* __restrict__ Wb,
    uint16_t* __restrict__ Out)
{
  constexpr int CB = 512;
  constexpr int NWG = 49*16;              // 784, Q8=98, R8=0
  constexpr int Q8 = NWG/8;

  __shared__ __align__(16) uint16_t As[128*64];
  __shared__ __align__(16) uint16_t Bs[128*64];

  int t = threadIdx.x, w = t>>6, l = t&63;

  int xcd = blockIdx.x & 7, pos = blockIdx.x >> 3;
  int wgid = xcd*Q8 + pos;
  int n0 = (wgid / 49) * 128;
  int m0 = (wgid % 49) * 128;

  const uint16_t* aP[4];
  const uint16_t* bP[4];
  #pragma unroll
  for(int p=0;p<4;p++){
    int r = w*32 + p*8 + (l>>3);
    aP[p] = Ain + (size_t)(m0 + r)*512 + (l&7)*8;
    bP[p] = Wb + (size_t)(n0 + r)*CB + (l&7)*8;
  }

  facc acc[4][4];
  #pragma unroll
  for(int i=0;i<4;i++)
    #pragma unroll
    for(int j=0;j<4;j++) acc[i][j] = facc{0.f,0.f,0.f,0.f};
  int wm = w>>1, wn = w&1;
  char* asDst = (char*)As + w*4096;
  char* bsDst = (char*)Bs + w*4096;

  for(int cc=0; cc<8; cc++){
    #pragma unroll
    for(int p=0;p<4;p++){ gload16(aP[p], asDst + p*1024); aP[p] += 64; }
    #pragma unroll
    for(int p=0;p<4;p++){ gload16(bP[p], bsDst + p*1024); bP[p] += 64; }
    __syncthreads();
    #pragma unroll
    for(int ks=0;ks<2;ks++){
      bfrag a[4], b[4];
      #pragma unroll
      for(int i=0;i<4;i++)
        a[i] = *(const bfrag*)(As + (wm*64 + i*16 + (l&15))*64 + ks*32 + (l>>4)*8);
      #pragma unroll
      for(int j=0;j<4;j++)
        b[j] = *(const bfrag*)(Bs + (wn*64 + j*16 + (l&15))*64 + ks*32 + (l>>4)*8);
      #pragma unroll
      for(int i=0;i<4;i++)
        #pragma unroll
        for(int j=0;j<4;j++)
          acc[i][j] = MFMA(a[i], b[j], acc[i][j]);
    }
    __syncthreads();
  }

  #pragma unroll
  for(int i=0;i<4;i++)
    #pragma unroll
    for(int j=0;j<4;j++){
      int n = n0 + wn*64 + j*16 + (l&15);
      #pragma unroll
      for(int r=0;r<4;r++){
        int mr = m0 + wm*64 + i*16 + (l>>4)*4 + r;
        Out[(size_t)mr*2048 + n] = f2b(acc[i][j][r]);
      }
    }
}

// ---------------- BN apply + ReLU in-place; conv2 variant extracts center into egoT/feat ----------------
template<int PAD>
__global__ void k_bnapply(uint16_t* __restrict__ Y, const float* __restrict__ stats,
                          const float* __restrict__ gg, const float* __restrict__ bb,
                          int M, float invM,
                          uint16_t* __restrict__ egoT, uint16_t* __restrict__ feat)
{
  int t = threadIdx.x;
  int m0 = blockIdx.x*8;
  float mu0 = stats[2*t]*invM,       mu1 = stats[2*t+1]*invM;
  float v0 = stats[512+2*t]*invM - mu0*mu0, v1 = stats[512+2*t+1]*invM - mu1*mu1;
  float sc0 = gg[2*t]  *rsqrtf(v0+1e-5f), sc1 = gg[2*t+1]*rsqrtf(v1+1e-5f);
  float sh0 = bb[2*t]   - mu0*sc0,        sh1 = bb[2*t+1] - mu1*sc1;
  for(int i=0;i<8;i++){
    int m = m0+i; if(m>=M) break;
    size_t off;
    if(PAD){ int b=m/196, s=m%196, y=s/14, x=s%14; off = (((size_t)b*16+y+1)*16 + x+1)*512; }
    else off = (size_t)m*512;
    uint32_t u = *(const uint32_t*)(Y + off + 2*t);
    float a = fmaxf(b2f((uint16_t)u)*sc0 + sh0, 0.f);
    float c = fmaxf(b2f((uint16_t)(u>>16))*sc1 + sh1, 0.f);
    uint32_t pu = (uint32_t)f2b(a) | ((uint32_t)f2b(c)<<16);
    *(uint32_t*)(Y + off + 2*t) = pu;
    if(!PAD && (m%49)==24){
      int b = m/49;
      *(uint32_t*)(egoT + (size_t)b*576 + 2*t) = pu;
      *(uint32_t*)(feat + (size_t)b*1088 + 512 + 2*t) = pu;
    }
  }
}

// ---------------- small-M GEMM (M=128), no LDS ----------------
// flags: 1 = relu, 2 = f32 output (else bf16)
__global__ __launch_bounds__(256) void k_sgemm(
    const uint16_t* __restrict__ A, int lda,
    const uint16_t* __restrict__ B, int ldb,
    const float* __restrict__ bias,
    void* __restrict__ C, int ldc,
    int N, int K, int flags)
{
  int t = threadIdx.x, w = t>>6, l = t&63;
  int nt = blockIdx.x*4 + w;
  int n  = nt*16 + (l&15);
  int m0 = blockIdx.y*16;
  bool nv = n < N;
  facc acc = facc{0.f,0.f,0.f,0.f};
  for(int k=0;k<K;k+=32){
    bfrag af = *(const bfrag*)(A + (size_t)(m0+(l&15))*lda + k + (l>>4)*8);
    bfrag bf_ = {0,0,0,0,0,0,0,0};
    if(nv) bf_ = *(const bfrag*)(B + (size_t)n*ldb + k + (l>>4)*8);
    acc = MFMA(af, bf_, acc);
  }
  if(nv){
    float bv = bias ? bias[n] : 0.f;
    #pragma unroll
    for(int r=0;r<4;r++){
      int m = m0 + (l>>4)*4 + r;
      float v = acc[r] + bv;
      if(flags & 1) v = fmaxf(v, 0.f);
      if(flags & 2) ((float*)C)[(size_t)m*ldc + n] = v;
      else ((uint16_t*)C)[(size_t)m*ldc + n] = f2b(v);
    }
  }
}

// ---------------- attention: one wave per (b,h); ring handled analytically ----------------
__global__ __launch_bounds__(256) void k_attn(
    const float* __restrict__ q, const uint16_t* __restrict__ kv,
    uint16_t* __restrict__ o)
{
  int t = threadIdx.x, w = t>>6, l = t&63;
  int idx = blockIdx.x*4 + w;          // b*16+h
  int b = idx>>4, h = idx&15;
  float qf = q[(size_t)b*1024 + h*64 + l];
  const uint16_t* kp = kv + (size_t)b*49*2048 + h*64 + l;
  float eo = 0.f;
  for(int g=0; g<49; g++){
    float p = qf * b2f(kp[(size_t)g*2048]);
    for(int s=32;s>0;s>>=1) p += __shfl_xor(p, s);
    if(l == g) eo = p;
  }
  float e = (l<49) ? eo*(1.f/32.f) : -1e30f;
  float mx = e;
  for(int s=32;s>0;s>>=1) mx = fmaxf(mx, __shfl_xor(mx, s));
  mx = fmaxf(mx, 0.f);                          // 32 ring slots have energy 0
  float p = (l<49) ? __expf(e-mx) : 0.f;
  float den = p;
  for(int s=32;s>0;s>>=1) den += __shfl_xor(den, s);
  den += 32.f*__expf(-mx);
  const uint16_t* vp = kv + (size_t)b*49*2048 + 1024 + h*64 + l;
  float accv = 0.f;
  for(int g=0; g<49; g++){
    float pg = __shfl(p, g);
    accv += pg * b2f(vp[(size_t)g*2048]);
  }
  o[(size_t)b*1024 + h*64 + l] = f2b(accv/den);
}

// ---------------- trajectory: d2[b][25][16] @ tmat -> out [b][25][19][2] ----------------
__global__ void k_traj(const float* __restrict__ d2, const float* __restrict__ tm,
                       float* __restrict__ out)
{
  int i = blockIdx.x*256 + threadIdx.x;
  if(i >= 3200) return;
  const float* dp = d2 + (size_t)i*16;
  float cx[8], cy[8];
  #pragma unroll
  for(int j=0;j<8;j++){ cx[j]=dp[j]; cy[j]=dp[8+j]; }
  float* op = out + (size_t)i*38;
  for(int tt=0;tt<19;tt++){
    float x=0.f, y=0.f;
    #pragma unroll
    for(int j=0;j<8;j++){ float tv = tm[j*19+tt]; x += cx[j]*tv; y += cy[j]*tv; }
    op[tt*2+0]=x; op[tt*2+1]=y;
  }
}

// ======================= host =======================
extern "C" void kernel_launch(void* const* d_in, const int* in_sizes, int n_in,
                              void* d_out, int out_size, void* d_ws, size_t ws_size,
                              hipStream_t stream)
{
  const float* cnn      = (const float*)d_in[0];
  const float* ego_seq  = (const float*)d_in[1];
  const float* ag_seq   = (const float*)d_in[2];
  const int*   ego_len  = (const int*)d_in[3];
  const int*   ag_len   = (const int*)d_in[4];
  const int*   grid_pos = (const int*)d_in[5];
  const float* sW  = (const float*)d_in[6];
  const float* sb  = (const float*)d_in[7];
  const float* Wih = (const float*)d_in[8];
  const float* Whh = (const float*)d_in[9];
  const float* bih = (const float*)d_in[10];
  const float* bhh = (const float*)d_in[11];
  const float* encW = (const float*)d_in[12];
  const float* encB = (const float*)d_in[13];
  const float* conv1W = (const float*)d_in[14];
  const float* bn1g = (const float*)d_in[15];
  const float* bn1b = (const float*)d_in[16];
  const float* conv2W = (const float*)d_in[17];
  const float* bn2g = (const float*)d_in[18];
  const float* bn2b = (const float*)d_in[19];
  const float* qWf  = (const float*)d_in[20];
  const float* kWf  = (const float*)d_in[21];
  const float* vWf  = (const float*)d_in[22];
  const float* aoW  = (const float*)d_in[23];
  const float* aoB  = (const float*)d_in[24];
  const float* clsWf = (const float*)d_in[25];
  const float* clsB  = (const float*)d_in[26];
  const float* d1Wf  = (const float*)d_in[27];
  const float* d1B   = (const float*)d_in[28];
  const float* d2Wf  = (const float*)d_in[29];
  const float* d2B   = (const float*)d_in[30];

  char* ws = (char*)d_ws;
  const size_t XP_OFF   = 0;
  const size_t PS_OFF   = 0;
  const size_t KV_OFF   = 0;
  const size_t Y2_OFF   = 41943040;
  const size_t Y1P_OFF  = 71303168;
  const size_t WP1_OFF  = 104857600;
  const size_t WP2_OFF  = 114884608;
  const size_t WKV_OFF  = 119603200;
  const size_t QW_OFF   = 121700352;
  const size_t AOW_OFF  = 122880000;
  const size_t CLSW_OFF = 123928576;
  const size_t D1W_OFF  = 123982976;
  const size_t D2W_OFF  = 124540032;
  const size_t GRID_OFF = 124744832;
  const size_t EGOT_OFF = 131167360;
  const size_t FEAT_OFF = 131314816;
  const size_t QBUF_OFF = 131593344;
  const size_t OBUF_OFF = 132117632;
  const size_t D1_OFF   = 132379776;
  const size_t D2_OFF   = 132445312;
  const size_t WC_OFF   = 132650112;
  const size_t BE_OFF   = 132699264;
  const size_t ENCW_OFF = 132700288;
  const size_t TMAT_OFF = 132708480;
  const size_t ST1_OFF  = 132709120;
  const size_t ST2_OFF  = 132713216;

  uint16_t* XP   = (uint16_t*)(ws + XP_OFF);
  float*    PS   = (float*)(ws + PS_OFF);
  uint16_t* KV   = (uint16_t*)(ws + KV_OFF);
  uint16_t* Y2   = (uint16_t*)(ws + Y2_OFF);
  uint16_t* Y1P  = (uint16_t*)(ws + Y1P_OFF);
  uint16_t* WP1  = (uint16_t*)(ws + WP1_OFF);
  uint16_t* WP2  = (uint16_t*)(ws + WP2_OFF);
  uint16_t* WKV  = (uint16_t*)(ws + WKV_OFF);
  uint16_t* QW   = (uint16_t*)(ws + QW_OFF);
  uint16_t* AOW  = (uint16_t*)(ws + AOW_OFF);
  uint16_t* CLSW = (uint16_t*)(ws + CLSW_OFF);
  uint16_t* D1W  = (uint16_t*)(ws + D1W_OFF);
  uint16_t* D2W  = (uint16_t*)(ws + D2W_OFF);
  float*    GRIDB= (float*)(ws + GRID_OFF);
  uint16_t* EGOT = (uint16_t*)(ws + EGOT_OFF);
  uint16_t* FEAT = (uint16_t*)(ws + FEAT_OFF);
  float*    QBUF = (float*)(ws + QBUF_OFF);
  uint16_t* OBUF = (uint16_t*)(ws + OBUF_OFF);
  uint16_t* D1B  = (uint16_t*)(ws + D1_OFF);
  float*    D2B  = (float*)(ws + D2_OFF);
  uint16_t* WC   = (uint16_t*)(ws + WC_OFF);
  float*    BE   = (float*)(ws + BE_OFF);
  uint16_t* ENCWB= (uint16_t*)(ws + ENCW_OFF);
  float*    TMAT = (float*)(ws + TMAT_OFF);
  float*    ST1  = (float*)(ws + ST1_OFF);
  float*    ST2  = (float*)(ws + ST2_OFF);
  float*    outF = (float*)d_out;

  (void)hipMemsetAsync(ws + GRID_OFF, 0, 6422528, stream);
  (void)hipMemsetAsync(ws + ST1_OFF,  0, 8192, stream);

  // border zeros for both padded buffers (one launch)
  k_zborder<<<256,256,0,stream>>>(XP, Y1P);

  // constants / weight packs
  k_lstm_prep<<<1,256,0,stream>>>(Wih,Whh,bih,bhh,sW,sb,encW, WC,BE,ENCWB, TMAT);
  k_packw<<<dim3(512,17),64,0,stream>>>(conv1W, WP1, 512, 1088);
  k_packw2<<<dim3(512,8),64,0,stream>>>(conv2W, WP2);
  {
    F2BJobs jb;
    jb.s[0]=kWf;  jb.d[0]=WKV;              jb.n[0]=1024*512;
    jb.s[1]=vWf;  jb.d[1]=WKV + 1024*512;   jb.n[1]=1024*512;
    jb.s[2]=qWf;  jb.d[2]=QW;               jb.n[2]=1024*576;
    jb.s[3]=aoW;  jb.d[3]=AOW;              jb.n[3]=512*1024;
    jb.s[4]=clsWf;jb.d[4]=CLSW;             jb.n[4]=25*1088;
    jb.s[5]=d1Wf; jb.d[5]=D1W;              jb.n[5]=256*1088;
    jb.s[6]=d2Wf; jb.d[6]=D2W;              jb.n[6]=400*256;
    k_f2b_multi<<<dim3(48,7),256,0,stream>>>(jb);
  }

  // encoders + scatter
  k_lstm<<<132,256,0,stream>>>(ego_seq, ag_seq, ego_len, ag_len, grid_pos,
                               WC, BE, ENCWB, encB, GRIDB, EGOT, FEAT);
  // conv input pack
  k_packx<<<dim3(128,34),256,0,stream>>>(cnn, GRIDB, XP);
  // conv1 (8-phase 256², +stats) -> BN1 -> relu (in place, padded)
  k_conv1_8p<<<196,512,0,stream>>>(XP, WP1, Y1P, ST1);
  k_bnapply<1><<<3136,256,0,stream>>>(Y1P, ST1, bn1g, bn1b, 25088, 1.f/25088.f, nullptr, nullptr);
  // conv2: dy-split f32 partials -> sum+stats -> BN2 apply (+ center -> egoT/feat)
  k_conv2dy<<<dim3(196,3),256,0,stream>>>(Y1P, WP2, PS);
  k_bn2sum<<<392,256,0,stream>>>(PS, Y2, ST2);
  k_bnapply<0><<<784,256,0,stream>>>(Y2, ST2, bn2g, bn2b, 6272, 1.f/6272.f, EGOT, FEAT);
  // k,v 1x1 convs
  k_convkv<<<784,256,0,stream>>>(Y2, WKV, KV);
  // q = egoT @ qW^T  (f32 out)
  k_sgemm<<<dim3(16,8),256,0,stream>>>(EGOT, 576, QW, 576, nullptr, QBUF, 1024, 1024, 576, 2);
  // attention
  k_attn<<<512,256,0,stream>>>(QBUF, KV, OBUF);
  // attn_out -> feat[:,0:512]
  k_sgemm<<<dim3(8,8),256,0,stream>>>(OBUF, 1024, AOW, 1024, aoB, FEAT, 1088, 512, 1024, 0);
  // conf -> d_out[121600:]
  k_sgemm<<<dim3(1,8),256,0,stream>>>(FEAT, 1088, CLSW, 1088, clsB, outF + 121600, 25, 25, 1088, 2);
  // dec1 (relu) -> dec2 -> traj
  k_sgemm<<<dim3(4,8),256,0,stream>>>(FEAT, 1088, D1W, 1088, d1B, D1B, 256, 256, 1088, 1);
  k_sgemm<<<dim3(7,8),256,0,stream>>>(D1B, 256, D2W, 256, d2B, D2B, 400, 400, 256, 2);
  k_traj<<<13,256,0,stream>>>(D2B, TMAT, outF);

  (void)in_sizes; (void)n_in; (void)out_size; (void)ws_size;
}

// Round 9
// 598.998 us; speedup vs baseline: 1.3604x; 1.0510x over previous
//
#include <hip/hip_runtime.h>
#include <stdint.h>
#include <stddef.h>

#define DEVINL static __device__ __forceinline__

typedef __attribute__((ext_vector_type(8))) short  bfrag;   // 8x bf16 (bits)
typedef __attribute__((ext_vector_type(4))) float  facc;    // MFMA accumulator

DEVINL uint16_t f2b(float f){
  uint32_t u = __float_as_uint(f);
  return (uint16_t)((u + 0x7fffu + ((u >> 16) & 1u)) >> 16);   // RNE
}
DEVINL float b2f(uint16_t b){ return __uint_as_float(((uint32_t)b) << 16); }

DEVINL facc MFMA(bfrag a, bfrag b, facc c){
  return __builtin_amdgcn_mfma_f32_16x16x32_bf16(a, b, c, 0, 0, 0);
}

// async global->LDS, 16B per lane; LDS dest = wave-uniform base + lane*16
DEVINL void gload16(const void* g, void* l){
  __builtin_amdgcn_global_load_lds(
      (const __attribute__((address_space(1))) uint32_t*)g,
      (__attribute__((address_space(3))) uint32_t*)l, 16, 0, 0);
}

DEVINL float fast_tanh(float x){           // tanh = 2*sigmoid(2x)-1
  return 2.f/(1.f+__expf(-2.f*x)) - 1.f;
}

// ---------------- multi-buffer f32 -> bf16 convert (one launch) ----------------
struct F2BJobs {
  const float* s[6];
  uint16_t*    d[6];
  int          n[6];
};
__global__ void k_f2b_multi(F2BJobs jobs){
  int j = blockIdx.y;
  const float* s = jobs.s[j];
  uint16_t* d = jobs.d[j];
  int n = jobs.n[j];
  int i = blockIdx.x*256 + threadIdx.x;
  int st = gridDim.x*256;
  for(; i<n; i+=st) d[i] = f2b(s[i]);
}

// ---------------- zero border pixels of padded [128][16][16][C] (both buffers) ----------------
__global__ void k_zborder(uint16_t* __restrict__ X, uint16_t* __restrict__ Y){
  int b = blockIdx.x & 127, t = threadIdx.x;
  uint16_t* base = (blockIdx.x < 128) ? X : Y;
  int C = (blockIdx.x < 128) ? 1088 : 512;
  for(int p=0;p<60;p++){
    int y, x;
    if(p<16){ y=0; x=p; }
    else if(p<32){ y=15; x=p-16; }
    else { int q=p-32; y=1+(q>>1); x=(q&1)?15:0; }
    uint32_t* dst = (uint32_t*)(base + ((size_t)(b*16+y)*16 + x)*C);
    for(int i=t;i<C/2;i+=256) dst[i] = 0;
  }
}

// ---------------- LSTM weight prep + Legendre tmat ----------------
__global__ void k_lstm_prep(const float* __restrict__ Wih, const float* __restrict__ Whh,
                            const float* __restrict__ bih, const float* __restrict__ bhh,
                            const float* __restrict__ sW, const float* __restrict__ sb,
                            const float* __restrict__ encW,
                            uint16_t* __restrict__ Wc, float* __restrict__ be,
                            uint16_t* __restrict__ encWb, float* __restrict__ tm){
  int n = threadIdx.x;
  if(n < 19){
    float tv = (float)(n - 6) / 12.0f;
    float Pm = 1.0f, Pc = tv;
    tm[0*19+n] = Pm * sqrtf(0.5f);
    tm[1*19+n] = Pc * sqrtf(1.5f);
    for(int q=1; q<7; q++){
      float Pn = ((float)(2*q+1)*tv*Pc - (float)q*Pm) / (float)(q+1);
      Pm = Pc; Pc = Pn;
      tm[(q+1)*19+n] = Pc * sqrtf((float)(2*(q+1)+1) * 0.5f);
    }
  }
  for(int k=0;k<64;k++) Wc[n*96+k] = f2b(Whh[n*64+k]);
  for(int k5=0;k5<5;k5++){
    float s = 0.f;
    for(int j=0;j<64;j++) s += Wih[n*64+j]*sW[j*5+k5];
    Wc[n*96+64+k5] = f2b(s);
  }
  for(int k=69;k<96;k++) Wc[n*96+k] = 0;
  float s = 0.f;
  for(int j=0;j<64;j++) s += Wih[n*64+j]*sb[j];
  be[n] = s + bih[n] + bhh[n];
  if(n < 64){
    for(int k=0;k<64;k++) encWb[n*64+k] = f2b(encW[n*64+k]);
  }
}

// ---------------- LSTM: 32 sequences / block, MFMA gates ----------------
__global__ __launch_bounds__(256) void k_lstm(
    const float* __restrict__ ego_seq, const float* __restrict__ ag_seq,
    const int* __restrict__ ego_len, const int* __restrict__ ag_len,
    const int* __restrict__ grid_pos,
    const uint16_t* __restrict__ Wc, const float* __restrict__ be,
    const uint16_t* __restrict__ encWb, const float* __restrict__ encB,
    float* __restrict__ agrid, uint16_t* __restrict__ egoT, uint16_t* __restrict__ feat)
{
  __shared__ __align__(16) uint16_t A[32*96];   // [seq][k] : k<64 h, 64..68 x_t, 69..95 zero
  __shared__ float Xf[32*160];                  // raw seq f32 [32][32][5]
  __shared__ int   idxs[32];

  int t = threadIdx.x, w = t>>6, l = t&63;
  int blk = blockIdx.x;
  bool isEgo = blk < 4;
  int seq0 = isEgo ? blk*32 : (blk-4)*32;
  const float* seqp = (isEgo ? ego_seq : ag_seq) + (size_t)seq0*160;

  for(int i=t;i<32*160;i+=256) Xf[i] = seqp[i];
  if(t < 32){
    int L = isEgo ? ego_len[seq0+t] : ag_len[seq0+t];
    if(L < 1) L = 1;
    idxs[t] = L-1;
  }
  for(int i=t;i<32*96;i+=256) A[i] = 0;

  bfrag bf[4][3];
  float be4[4];
  for(int ct=0;ct<4;ct++){
    int n = (ct*4+w)*16 + (l&15);
    for(int ks=0;ks<3;ks++)
      bf[ct][ks] = *(const bfrag*)(Wc + n*96 + ks*32 + (l>>4)*8);
    be4[ct] = be[n];
  }
  float cst[8], hl[8];
  for(int i=0;i<8;i++){ cst[i]=0.f; hl[i]=0.f; }
  __syncthreads();
  int myidx[8];
  for(int rt=0;rt<2;rt++) for(int r=0;r<4;r++){
    int s = rt*16 + (l>>4)*4 + r;
    myidx[rt*4+r] = idxs[s];
  }

  for(int st=0; st<32; st++){
    if(t < 160){ int s=t/5, kk=t%5; A[s*96+64+kk] = f2b(Xf[s*160 + st*5 + kk]); }
    __syncthreads();
    facc acc[2][4];
    for(int rt=0;rt<2;rt++) for(int ct=0;ct<4;ct++) acc[rt][ct] = facc{0.f,0.f,0.f,0.f};
    #pragma unroll
    for(int ks=0;ks<3;ks++){
      bfrag aA[2];
      #pragma unroll
      for(int rt=0;rt<2;rt++)
        aA[rt] = *(const bfrag*)(A + (rt*16+(l&15))*96 + ks*32 + (l>>4)*8);
      #pragma unroll
      for(int rt=0;rt<2;rt++)
        #pragma unroll
        for(int ct=0;ct<4;ct++)
          acc[rt][ct] = MFMA(aA[rt], bf[ct][ks], acc[rt][ct]);
    }
    __syncthreads();   // all A reads done before h overwrite
    #pragma unroll
    for(int rt=0;rt<2;rt++) for(int r=0;r<4;r++){
      int cell = rt*4+r;
      int s = rt*16 + (l>>4)*4 + r;
      float gi = acc[rt][0][r] + be4[0];
      float gf = acc[rt][1][r] + be4[1];
      float gg = acc[rt][2][r] + be4[2];
      float go = acc[rt][3][r] + be4[3];
      float si = 1.f/(1.f+__expf(-gi));
      float sf = 1.f/(1.f+__expf(-gf));
      float so = 1.f/(1.f+__expf(-go));
      float tg = fast_tanh(gg);
      float c2 = sf*cst[cell] + si*tg;
      cst[cell] = c2;
      float hn = so*fast_tanh(c2);
      A[s*96 + w*16 + (l&15)] = f2b(hn);
      if(st == myidx[cell]) hl[cell] = hn;
    }
  }
  __syncthreads();
  for(int rt=0;rt<2;rt++) for(int r=0;r<4;r++){
    int s = rt*16 + (l>>4)*4 + r;
    A[s*96 + w*16 + (l&15)] = f2b(hl[rt*4+r]);
  }
  __syncthreads();
  bfrag eb[2];
  for(int ks=0;ks<2;ks++)
    eb[ks] = *(const bfrag*)(encWb + (w*16+(l&15))*64 + ks*32 + (l>>4)*8);
  facc ea[2]; ea[0] = facc{0.f,0.f,0.f,0.f}; ea[1] = facc{0.f,0.f,0.f,0.f};
  for(int ks=0;ks<2;ks++){
    for(int rt=0;rt<2;rt++){
      bfrag aA = *(const bfrag*)(A + (rt*16+(l&15))*96 + ks*32 + (l>>4)*8);
      ea[rt] = MFMA(aA, eb[ks], ea[rt]);
    }
  }
  int n = w*16 + (l&15);
  float bn_ = encB[n];
  for(int rt=0;rt<2;rt++) for(int r=0;r<4;r++){
    int s = rt*16 + (l>>4)*4 + r;
    float v = ea[rt][r] + bn_;
    int gs = seq0 + s;
    if(isEgo){
      egoT[(size_t)gs*576 + 512 + n] = f2b(v);
      feat[(size_t)gs*1088 + 1024 + n] = f2b(v);
    } else {
      int py = grid_pos[gs*2+0], px = grid_pos[gs*2+1];
      atomicAdd(&agrid[((size_t)(gs>>5)*196 + py*14 + px)*64 + n], v);
    }
  }
}

// ---------------- pack conv1 input: NCHW f32 (+grid NHWC f32) -> padded NHWC bf16 ----------------
__global__ void k_packx(const float* __restrict__ cnn, const float* __restrict__ agrid,
                        uint16_t* __restrict__ Xp)
{
  __shared__ float tile[32*200];
  int b = blockIdx.x, ch = blockIdx.y, t = threadIdx.x;
  if(ch < 32){
    int c0 = ch*32;
    for(int i=t;i<32*196;i+=256){
      int ci = i/196, s = i%196;
      tile[ci*200+s] = cnn[((size_t)b*1024 + c0+ci)*196 + s];
    }
    __syncthreads();
    for(int i=t;i<32*196;i+=256){
      int s = i>>5, ci = i&31;
      int y = s/14, x = s%14;
      Xp[(((size_t)b*16 + y+1)*16 + x+1)*1088 + c0 + ci] = f2b(tile[ci*200+s]);
    }
  } else {
    int j0 = (ch-32)*32;
    for(int i=t;i<32*196;i+=256){
      int s = i>>5, ji = i&31;
      int y = s/14, x = s%14;
      Xp[(((size_t)b*16 + y+1)*16 + x+1)*1088 + 1024 + j0 + ji] =
          f2b(agrid[((size_t)b*196 + s)*64 + j0 + ji]);
    }
  }
}

// ---------------- pack conv1 weights OIHW f32 -> [dydx][O][C] bf16 ----------------
__global__ void k_packw(const float* __restrict__ W, uint16_t* __restrict__ Wp, int O, int C)
{
  int o = blockIdx.x;
  int c = blockIdx.y*64 + threadIdx.x;
  const float* src = W + ((size_t)o*C + c)*9;
  float v[9];
  #pragma unroll
  for(int d=0;d<9;d++) v[d] = src[d];
  #pragma unroll
  for(int d=0;d<9;d++)
    Wp[((size_t)d*O + o)*C + c] = f2b(v[d]);
}

// ---------------- pack conv2 weights OIHW -> [dy][O][dx*512+c] bf16 (flat K=1536 per dy) ----------------
__global__ void k_packw2(const float* __restrict__ W, uint16_t* __restrict__ Wp)
{
  int o = blockIdx.x;
  int c = blockIdx.y*64 + threadIdx.x;
  const float* src = W + ((size_t)o*512 + c)*9;
  float v[9];
  #pragma unroll
  for(int d=0;d<9;d++) v[d] = src[d];
  #pragma unroll
  for(int dy=0;dy<3;dy++)
    #pragma unroll
    for(int dx=0;dx<3;dx++)
      Wp[((size_t)(dy*512 + o))*1536 + dx*512 + c] = f2b(v[dy*3+dx]);
}

// ---------------- pack Wk transposed per head: WKT[h][c][d] = kW[(h*64+d)*512+c] ----------------
__global__ void k_packwk(const float* __restrict__ kW, uint16_t* __restrict__ WKT)
{
  int h = blockIdx.x;            // 16
  int c0 = blockIdx.y*32;        // 16 blocks
  int t = threadIdx.x;
  int d = t & 63;
  for(int ci = t>>6; ci<32; ci+=4){
    int c = c0 + ci;
    WKT[((size_t)h*512 + c)*64 + d] = f2b(kW[((size_t)(h*64+d))*512 + c]);
  }
}

// ================= conv1: 256x256 8-phase pipelined implicit GEMM =================
// R9: dual persistent B register sets (bF0 lives phases 1->4, bF1 phases 2->3):
// LDS reads 28 -> 24 b128/wave/K-step. Stage schedule, vmcnt ledger, barrier
// structure and per-element K-order IDENTICAL to R8 (canary must hold on conv).
__global__ __launch_bounds__(512) void k_conv1_8p(
    const uint16_t* __restrict__ Ain, const uint16_t* __restrict__ Wb,
    uint16_t* __restrict__ Out, float* __restrict__ stats)
{
  constexpr int CB = 1088;
  constexpr int NSTEP = 153;          // 17 cc x 9 taps
  __shared__ __align__(16) char LDSb[131072];

  int t = threadIdx.x, w = t>>6, l = t&63;
  int wm = w>>2, wn = w&3;

  int xcd = blockIdx.x & 7, pos = blockIdx.x >> 3;
  int wgid = (xcd < 4 ? xcd*25 : 100 + (xcd-4)*24) + pos;
  int m0 = (wgid % 98) * 256;
  int n0 = (wgid / 98) * 256;

  const uint16_t* aP[2][2];
  const uint16_t* bP[2][2];
  #pragma unroll
  for(int P=0;P<2;P++)
    #pragma unroll
    for(int j=0;j<2;j++){
      int partrow = j*64 + (t>>3);
      int swz = ((t&7) ^ (partrow&7))*8;            // elements
      int gr = P*64 + partrow + ((partrow>=64)?64:0);
      int m = m0 + gr; int b = m/196, s = m%196, y = s/14, x = s%14;
      aP[P][j] = Ain + ((b*16+y)*16+x)*CB + swz;
      int nb = n0 + (partrow>>5)*64 + P*32 + (partrow&31);
      bP[P][j] = Wb + (size_t)nb*CB + swz;
    }

  facc acc[8][4];
  #pragma unroll
  for(int i=0;i<8;i++)
    #pragma unroll
    for(int j=0;j<4;j++) acc[i][j] = facc{0.f,0.f,0.f,0.f};

  bfrag aF[4][2], bF0[2][2], bF1[2][2];   // persistent operand fragments
  int dd = 0;

  #define STG(buf, PART) do{                                                   \
    if((PART)==0 || (PART)==3){ const int P_ = ((PART)==3);                    \
      _Pragma("unroll")                                                        \
      for(int j_=0;j_<2;j_++)                                                  \
        gload16(aP[P_][j_], LDSb + (buf)*65536 + P_*16384 + j_*8192 + w*1024); \
    } else { const int P_ = ((PART)==2);                                       \
      _Pragma("unroll")                                                        \
      for(int j_=0;j_<2;j_++)                                                  \
        gload16(bP[P_][j_], LDSb + (buf)*65536 + 32768 + P_*16384 + j_*8192 + w*1024); \
    }                                                                          \
  }while(0)

  #define ADVK() do{                                                          \
    if(dd==8){                                                                \
      _Pragma("unroll")                                                       \
      for(int P_=0;P_<2;P_++) for(int j_=0;j_<2;j_++){                        \
        aP[P_][j_] += 64 - 34*CB; bP[P_][j_] += 64 - 8*512*CB; }              \
      dd = 0;                                                                 \
    } else {                                                                  \
      int sA_ = (dd==2||dd==5) ? 14*CB : CB;                                  \
      _Pragma("unroll")                                                       \
      for(int P_=0;P_<2;P_++) for(int j_=0;j_<2;j_++){                        \
        aP[P_][j_] += sA_; bP[P_][j_] += 512*CB; }                            \
      dd++;                                                                   \
    }                                                                         \
  }while(0)

  #define VM4 asm volatile("s_waitcnt vmcnt(4)" ::: "memory")
  #define VM2 asm volatile("s_waitcnt vmcnt(2)" ::: "memory")
  #define VM0 asm volatile("s_waitcnt vmcnt(0)" ::: "memory")

  #define LDA(mh) do{                                                         \
    const uint16_t* Ab_ = (const uint16_t*)(LDSb + p*65536 + (mh)*16384);     \
    _Pragma("unroll")                                                         \
    for(int i_=0;i_<4;i_++)                                                   \
      _Pragma("unroll")                                                       \
      for(int ks_=0;ks_<2;ks_++)                                              \
        aF[i_][ks_] = *(const bfrag*)(Ab_ + (wm*64 + i_*16 + (l&15))*64       \
                        + ((ks_*32 + (l>>4)*8) ^ ((l&7)<<3)));                \
  }while(0)

  #define LDB(dst, nh) do{                                                   \
    const uint16_t* Bb_ = (const uint16_t*)(LDSb + p*65536 + 32768 + (nh)*16384); \
    _Pragma("unroll")                                                         \
    for(int j_=0;j_<2;j_++)                                                   \
      _Pragma("unroll")                                                       \
      for(int ks_=0;ks_<2;ks_++)                                              \
        dst[j_][ks_] = *(const bfrag*)(Bb_ + (wn*32 + j_*16 + (l&15))*64      \
                        + ((ks_*32 + (l>>4)*8) ^ ((l&7)<<3)));                \
  }while(0)

  #define MM(mh, nh, bsrc) do{                                               \
    __builtin_amdgcn_s_setprio(1);                                           \
    _Pragma("unroll")                                                        \
    for(int ks_=0;ks_<2;ks_++)                                               \
      _Pragma("unroll")                                                      \
      for(int i_=0;i_<4;i_++)                                                \
        _Pragma("unroll")                                                    \
        for(int j_=0;j_<2;j_++)                                              \
          acc[(mh)*4+i_][(nh)*2+j_] =                                        \
            MFMA(aF[i_][ks_], bsrc[j_][ks_], acc[(mh)*4+i_][(nh)*2+j_]);     \
    __builtin_amdgcn_s_setprio(0);                                           \
  }while(0)

  #define BARS do{ __builtin_amdgcn_sched_barrier(0); __builtin_amdgcn_s_barrier(); }while(0)
  #define EBAR __builtin_amdgcn_s_barrier()

  // prologue: stage K-tile 0 (A0,B0,B1,A1) into buf0
  STG(0,0); STG(0,1); STG(0,2); STG(0,3);
  ADVK();
  VM4;
  EBAR;

  for(int kt=0; kt<NSTEP-1; kt++){
    int p = kt&1;
    LDA(0); LDB(bF0,0); STG(p^1,0); BARS; MM(0,0,bF0); VM4; EBAR;
    LDB(bF1,1);         STG(p^1,1); BARS; MM(0,1,bF1); VM4; EBAR;
    LDA(1);             STG(p^1,2); BARS; MM(1,1,bF1);      EBAR;
                        STG(p^1,3); BARS; MM(1,0,bF0); VM4; EBAR;
    if(kt < NSTEP-2) ADVK();
  }
  { // peeled last K-tile (buf 0), no staging, drain
    int p = 0;
    LDA(0); LDB(bF0,0); BARS; MM(0,0,bF0); VM2; EBAR;
    LDB(bF1,1);         BARS; MM(0,1,bF1); VM0; EBAR;
    LDA(1);             BARS; MM(1,1,bF1);      EBAR;
                        BARS; MM(1,0,bF0);      EBAR;
  }

  #undef LDA
  #undef LDB
  #undef MM
  #undef BARS
  #undef EBAR
  #undef STG
  #undef ADVK

  __syncthreads();
  int* oo = (int*)LDSb;
  if(t < 256){
    int m = m0 + t; int b = m/196, s = m%196, y = s/14, x = s%14;
    oo[t] = ((b*16 + y+1)*16 + (x+1))*512;
  }
  __syncthreads();
  #pragma unroll
  for(int i=0;i<8;i++)
    #pragma unroll
    for(int j=0;j<4;j++){
      int n = n0 + wn*64 + j*16 + (l&15);
      #pragma unroll
      for(int r=0;r<4;r++){
        int mr = wm*128 + i*16 + (l>>4)*4 + r;
        Out[(size_t)oo[mr] + n] = f2b(acc[i][j][r]);
      }
    }
  __syncthreads();
  float* sred = (float*)LDSb;
  int rg = wm*4 + (l>>4);
  #pragma unroll
  for(int j=0;j<4;j++){
    float s=0.f, q=0.f;
    #pragma unroll
    for(int i=0;i<8;i++)
      #pragma unroll
      for(int r=0;r<4;r++){ float v = acc[i][j][r]; s += v; q += v*v; }
    int nl = wn*64 + j*16 + (l&15);
    sred[(nl*8 + rg)*2+0] = s;
    sred[(nl*8 + rg)*2+1] = q;
  }
  __syncthreads();
  if(t < 256){
    float s=0.f, q=0.f;
    #pragma unroll
    for(int rgi=0;rgi<8;rgi++){ s += sred[(t*8+rgi)*2]; q += sred[(t*8+rgi)*2+1]; }
    atomicAdd(&stats[n0+t], s);
    atomicAdd(&stats[512+n0+t], q);
  }
}

// ================= conv2: dy-split flat GEMM (K=1536 contiguous), f32 partials =================
__global__ __launch_bounds__(256) void k_conv2dy(
    const uint16_t* __restrict__ Ain, const uint16_t* __restrict__ Wb,
    float* __restrict__ PS)
{
  __shared__ __align__(16) uint16_t As[128*64];
  __shared__ __align__(16) uint16_t Bs[128*64];

  int t = threadIdx.x, w = t>>6, l = t&63;
  int dy = blockIdx.y;

  int xcd = blockIdx.x & 7, pos = blockIdx.x >> 3;
  int wgid = (xcd < 4 ? xcd*25 : 100 + (xcd-4)*24) + pos;
  int n0 = (wgid / 49) * 128;
  int m0 = (wgid % 49) * 128;

  const uint16_t* aP[4];
  const uint16_t* bP[4];
  #pragma unroll
  for(int p=0;p<4;p++){
    int r = w*32 + p*8 + (l>>3);
    int m = m0 + r;
    int b = m/49, s = m%49, y = s/7, x = s%7;
    aP[p] = Ain + ((b*16 + 2*y + dy)*16 + 2*x)*512 + (l&7)*8;
    bP[p] = Wb + ((size_t)(dy*512 + n0 + r))*1536 + (l&7)*8;
  }

  facc acc[4][4];
  #pragma unroll
  for(int i=0;i<4;i++)
    #pragma unroll
    for(int j=0;j<4;j++) acc[i][j] = facc{0.f,0.f,0.f,0.f};
  int wm = w>>1, wn = w&1;
  char* asDst = (char*)As + w*4096;
  char* bsDst = (char*)Bs + w*4096;

  for(int stp=0; stp<24; stp++){
    #pragma unroll
    for(int p=0;p<4;p++){ gload16(aP[p], asDst + p*1024); aP[p] += 64; }
    #pragma unroll
    for(int p=0;p<4;p++){ gload16(bP[p], bsDst + p*1024); bP[p] += 64; }
    __syncthreads();
    #pragma unroll
    for(int ks=0;ks<2;ks++){
      bfrag a[4], b[4];
      #pragma unroll
      for(int i=0;i<4;i++)
        a[i] = *(const bfrag*)(As + (wm*64 + i*16 + (l&15))*64 + ks*32 + (l>>4)*8);
      #pragma unroll
      for(int j=0;j<4;j++)
        b[j] = *(const bfrag*)(Bs + (wn*64 + j*16 + (l&15))*64 + ks*32 + (l>>4)*8);
      #pragma unroll
      for(int i=0;i<4;i++)
        #pragma unroll
        for(int j=0;j<4;j++)
          acc[i][j] = MFMA(a[i], b[j], acc[i][j]);
    }
    __syncthreads();
  }

  float* out = PS + (size_t)dy*3211264;
  #pragma unroll
  for(int i=0;i<4;i++)
    #pragma unroll
    for(int j=0;j<4;j++){
      int n = n0 + wn*64 + j*16 + (l&15);
      #pragma unroll
      for(int r=0;r<4;r++){
        int mr = m0 + wm*64 + i*16 + (l>>4)*4 + r;
        out[(size_t)mr*512 + n] = acc[i][j][r];
      }
    }
}

// ---------------- sum conv2 dy-partials -> Y2 bf16 + BN2 stats ----------------
__global__ void k_bn2sum(const float* __restrict__ PS, uint16_t* __restrict__ Y2,
                         float* __restrict__ stats)
{
  int t = threadIdx.x;            // channel pair 2t, 2t+1
  int m0 = blockIdx.x*16;         // grid 392
  float s0=0,s1=0,q0=0,q1=0;
  for(int i=0;i<16;i++){
    size_t off = (size_t)(m0+i)*512 + 2*t;
    float2 p0 = *(const float2*)(PS + off);
    float2 p1 = *(const float2*)(PS + 3211264 + off);
    float2 p2 = *(const float2*)(PS + 6422528 + off);
    float a = p0.x+p1.x+p2.x, c = p0.y+p1.y+p2.y;
    s0+=a; q0+=a*a; s1+=c; q1+=c*c;
    *(uint32_t*)(Y2 + off) = (uint32_t)f2b(a) | ((uint32_t)f2b(c)<<16);
  }
  atomicAdd(&stats[2*t],   s0);
  atomicAdd(&stats[2*t+1], s1);
  atomicAdd(&stats[512+2*t],   q0);
  atomicAdd(&stats[512+2*t+1], q1);
}

// ---------------- BN apply + ReLU in-place; conv2 variant extracts center into egoT/feat ----------------
template<int PAD>
__global__ void k_bnapply(uint16_t* __restrict__ Y, const float* __restrict__ stats,
                          const float* __restrict__ gg, const float* __restrict__ bb,
                          int M, float invM,
                          uint16_t* __restrict__ egoT, uint16_t* __restrict__ feat)
{
  int t = threadIdx.x;
  int m0 = blockIdx.x*8;
  float mu0 = stats[2*t]*invM,       mu1 = stats[2*t+1]*invM;
  float v0 = stats[512+2*t]*invM - mu0*mu0, v1 = stats[512+2*t+1]*invM - mu1*mu1;
  float sc0 = gg[2*t]  *rsqrtf(v0+1e-5f), sc1 = gg[2*t+1]*rsqrtf(v1+1e-5f);
  float sh0 = bb[2*t]   - mu0*sc0,        sh1 = bb[2*t+1] - mu1*sc1;
  for(int i=0;i<8;i++){
    int m = m0+i; if(m>=M) break;
    size_t off;
    if(PAD){ int b=m/196, s=m%196, y=s/14, x=s%14; off = (((size_t)b*16+y+1)*16 + x+1)*512; }
    else off = (size_t)m*512;
    uint32_t u = *(const uint32_t*)(Y + off + 2*t);
    float a = fmaxf(b2f((uint16_t)u)*sc0 + sh0, 0.f);
    float c = fmaxf(b2f((uint16_t)(u>>16))*sc1 + sh1, 0.f);
    uint32_t pu = (uint32_t)f2b(a) | ((uint32_t)f2b(c)<<16);
    *(uint32_t*)(Y + off + 2*t) = pu;
    if(!PAD && (m%49)==24){
      int b = m/49;
      *(uint32_t*)(egoT + (size_t)b*576 + 2*t) = pu;
      *(uint32_t*)(feat + (size_t)b*1088 + 512 + 2*t) = pu;
    }
  }
}

// ---------------- small-M GEMM (M=128), no LDS ----------------
// flags: 1 = relu, 2 = f32 output (else bf16)
__global__ __launch_bounds__(256) void k_sgemm(
    const uint16_t* __restrict__ A, int lda,
    const uint16_t* __restrict__ B, int ldb,
    const float* __restrict__ bias,
    void* __restrict__ C, int ldc,
    int N, int K, int flags)
{
  int t = threadIdx.x, w = t>>6, l = t&63;
  int nt = blockIdx.x*4 + w;
  int n  = nt*16 + (l&15);
  int m0 = blockIdx.y*16;
  bool nv = n < N;
  facc acc = facc{0.f,0.f,0.f,0.f};
  for(int k=0;k<K;k+=32){
    bfrag af = *(const bfrag*)(A + (size_t)(m0+(l&15))*lda + k + (l>>4)*8);
    bfrag bf_ = {0,0,0,0,0,0,0,0};
    if(nv) bf_ = *(const bfrag*)(B + (size_t)n*ldb + k + (l>>4)*8);
    acc = MFMA(af, bf_, acc);
  }
  if(nv){
    float bv = bias ? bias[n] : 0.f;
    #pragma unroll
    for(int r=0;r<4;r++){
      int m = m0 + (l>>4)*4 + r;
      float v = acc[r] + bv;
      if(flags & 1) v = fmaxf(v, 0.f);
      if(flags & 2) ((float*)C)[(size_t)m*ldc + n] = v;
      else ((uint16_t*)C)[(size_t)m*ldc + n] = f2b(v);
    }
  }
}

// ---------------- batched per-head GEMM: C[m, z*coffs+n] = A[m, z*aoffs+k] . B[(z*brows+n), k] ----------------
__global__ __launch_bounds__(256) void k_bgemm(
    const uint16_t* __restrict__ A, int lda, int aoffs,
    const uint16_t* __restrict__ B, int ldb, int brows,
    uint16_t* __restrict__ C, int ldc, int coffs,
    int K)
{
  int t = threadIdx.x, w = t>>6, l = t&63;
  int z = blockIdx.z;
  int n = (blockIdx.x*4 + w)*16 + (l&15);
  int m0 = blockIdx.y*16;
  const uint16_t* Ab = A + (size_t)z*aoffs;
  const uint16_t* Bb = B + (size_t)z*brows*ldb;
  facc acc = facc{0.f,0.f,0.f,0.f};
  for(int k=0;k<K;k+=32){
    bfrag af = *(const bfrag*)(Ab + (size_t)(m0+(l&15))*lda + k + (l>>4)*8);
    bfrag bf_ = *(const bfrag*)(Bb + (size_t)n*ldb + k + (l>>4)*8);
    acc = MFMA(af, bf_, acc);
  }
  #pragma unroll
  for(int r=0;r<4;r++){
    int m = m0 + (l>>4)*4 + r;
    C[(size_t)m*ldc + z*coffs + n] = f2b(acc[r]);
  }
}

// ---------------- attention core: energy = U.y2, softmax (analytic ring), z = sum p*y2 ----------------
// block 512 thr (8 waves = 8 heads), grid 256 = b*2+half. y2 staged swizzled in LDS.
__global__ __launch_bounds__(512) void k_attn2(
    const uint16_t* __restrict__ U16, const uint16_t* __restrict__ y2,
    uint16_t* __restrict__ zout)
{
  __shared__ __align__(16) char LA[49*1024 + 8*1024];
  uint16_t* uls = (uint16_t*)(LA + 49*1024);
  int t = threadIdx.x, w = t>>6, l = t&63;
  int b = blockIdx.x >> 1, half = blockIdx.x & 1;
  int h = half*8 + w;

  for(int i=t; i<3136; i+=512){
    int g = i>>6, c16 = i&63;
    *(uint4*)(LA + g*1024 + ((c16*16) ^ ((g&31)<<4))) =
        *(const uint4*)(y2 + ((size_t)(b*49+g)*512 + c16*8));
  }
  *(uint4*)((char*)uls + w*1024 + l*16) =
      *(const uint4*)(U16 + (size_t)b*8192 + h*512 + l*8);
  __syncthreads();

  float dot = 0.f;
  if(l < 49){
    const char* yrow = LA + l*1024;
    const char* ur = (const char*)uls + w*1024;
    for(int c16=0;c16<64;c16++){
      uint4 uv = *(const uint4*)(ur + c16*16);
      uint4 yv = *(const uint4*)(yrow + ((c16*16) ^ ((l&31)<<4)));
      const uint16_t* up = (const uint16_t*)&uv;
      const uint16_t* yp = (const uint16_t*)&yv;
      #pragma unroll
      for(int j=0;j<8;j++) dot += b2f(up[j])*b2f(yp[j]);
    }
  }
  float e = (l<49) ? dot*(1.f/32.f) : -1e30f;
  float mx = e;
  for(int s=32;s>0;s>>=1) mx = fmaxf(mx, __shfl_xor(mx, s));
  mx = fmaxf(mx, 0.f);                      // 32 ring slots have energy 0
  float p = (l<49) ? __expf(e-mx) : 0.f;
  float den = p;
  for(int s=32;s>0;s>>=1) den += __shfl_xor(den, s);
  den += 32.f*__expf(-mx);

  float z[8];
  #pragma unroll
  for(int j=0;j<8;j++) z[j]=0.f;
  for(int g=0; g<49; g++){
    float pg = __shfl(p, g);
    uint4 yv = *(const uint4*)(LA + g*1024 + ((l*16) ^ ((g&31)<<4)));
    const uint16_t* yp = (const uint16_t*)&yv;
    #pragma unroll
    for(int j=0;j<8;j++) z[j] += pg*b2f(yp[j]);
  }
  float inv = 1.f/den;
  uint16_t zr[8];
  #pragma unroll
  for(int j=0;j<8;j++) zr[j] = f2b(z[j]*inv);
  *(uint4*)(zout + ((size_t)(b*16+h)*512) + l*8) = *(uint4*)zr;
}

// ---------------- trajectory: d2[b][25][16] @ tmat -> out [b][25][19][2] ----------------
__global__ void k_traj(const float* __restrict__ d2, const float* __restrict__ tm,
                       float* __restrict__ out)
{
  int i = blockIdx.x*256 + threadIdx.x;
  if(i >= 3200) return;
  const float* dp = d2 + (size_t)i*16;
  float cx[8], cy[8];
  #pragma unroll
  for(int j=0;j<8;j++){ cx[j]=dp[j]; cy[j]=dp[8+j]; }
  float* op = out + (size_t)i*38;
  for(int tt=0;tt<19;tt++){
    float x=0.f, y=0.f;
    #pragma unroll
    for(int j=0;j<8;j++){ float tv = tm[j*19+tt]; x += cx[j]*tv; y += cy[j]*tv; }
    op[tt*2+0]=x; op[tt*2+1]=y;
  }
}

// ======================= host =======================
extern "C" void kernel_launch(void* const* d_in, const int* in_sizes, int n_in,
                              void* d_out, int out_size, void* d_ws, size_t ws_size,
                              hipStream_t stream)
{
  const float* cnn      = (const float*)d_in[0];
  const float* ego_seq  = (const float*)d_in[1];
  const float* ag_seq   = (const float*)d_in[2];
  const int*   ego_len  = (const int*)d_in[3];
  const int*   ag_len   = (const int*)d_in[4];
  const int*   grid_pos = (const int*)d_in[5];
  const float* sW  = (const float*)d_in[6];
  const float* sb  = (const float*)d_in[7];
  const float* Wih = (const float*)d_in[8];
  const float* Whh = (const float*)d_in[9];
  const float* bih = (const float*)d_in[10];
  const float* bhh = (const float*)d_in[11];
  const float* encW = (const float*)d_in[12];
  const float* encB = (const float*)d_in[13];
  const float* conv1W = (const float*)d_in[14];
  const float* bn1g = (const float*)d_in[15];
  const float* bn1b = (const float*)d_in[16];
  const float* conv2W = (const float*)d_in[17];
  const float* bn2g = (const float*)d_in[18];
  const float* bn2b = (const float*)d_in[19];
  const float* qWf  = (const float*)d_in[20];
  const float* kWf  = (const float*)d_in[21];
  const float* vWf  = (const float*)d_in[22];
  const float* aoW  = (const float*)d_in[23];
  const float* aoB  = (const float*)d_in[24];
  const float* clsWf = (const float*)d_in[25];
  const float* clsB  = (const float*)d_in[26];
  const float* d1Wf  = (const float*)d_in[27];
  const float* d1B   = (const float*)d_in[28];
  const float* d2Wf  = (const float*)d_in[29];
  const float* d2B   = (const float*)d_in[30];

  char* ws = (char*)d_ws;
  const size_t XP_OFF   = 0;                 // 71 MB (dead after conv1)
  const size_t PS_OFF   = 0;                 // 38.5 MB f32 partials (alias)
  const size_t U_OFF    = 0;                 // 2 MB (alias; after PS dead)
  const size_t ZB_OFF   = 2097152;           // 2 MB
  const size_t Y2_OFF   = 41943040;          // 6.4 MB
  const size_t Y1P_OFF  = 71303168;          // 33.5 MB
  const size_t WP1_OFF  = 104857600;
  const size_t WP2_OFF  = 114884608;
  const size_t WKT_OFF  = 119603200;         // 1 MB
  const size_t WVB_OFF  = 120651776;         // 1 MB
  const size_t QW_OFF   = 121700352;
  const size_t AOW_OFF  = 122880000;
  const size_t CLSW_OFF = 123928576;
  const size_t D1W_OFF  = 123982976;
  const size_t D2W_OFF  = 124540032;
  const size_t GRID_OFF = 124744832;
  const size_t EGOT_OFF = 131167360;
  const size_t FEAT_OFF = 131314816;
  const size_t QB_OFF   = 131593344;         // q bf16 [128][1024] = 256 KB
  const size_t OBUF_OFF = 132117632;
  const size_t D1_OFF   = 132379776;
  const size_t D2_OFF   = 132445312;
  const size_t WC_OFF   = 132650112;
  const size_t BE_OFF   = 132699264;
  const size_t ENCW_OFF = 132700288;
  const size_t TMAT_OFF = 132708480;
  const size_t ST1_OFF  = 132709120;
  const size_t ST2_OFF  = 132713216;

  uint16_t* XP   = (uint16_t*)(ws + XP_OFF);
  float*    PS   = (float*)(ws + PS_OFF);
  uint16_t* U16  = (uint16_t*)(ws + U_OFF);
  uint16_t* ZB16 = (uint16_t*)(ws + ZB_OFF);
  uint16_t* Y2   = (uint16_t*)(ws + Y2_OFF);
  uint16_t* Y1P  = (uint16_t*)(ws + Y1P_OFF);
  uint16_t* WP1  = (uint16_t*)(ws + WP1_OFF);
  uint16_t* WP2  = (uint16_t*)(ws + WP2_OFF);
  uint16_t* WKT  = (uint16_t*)(ws + WKT_OFF);
  uint16_t* WVB  = (uint16_t*)(ws + WVB_OFF);
  uint16_t* QW   = (uint16_t*)(ws + QW_OFF);
  uint16_t* AOW  = (uint16_t*)(ws + AOW_OFF);
  uint16_t* CLSW = (uint16_t*)(ws + CLSW_OFF);
  uint16_t* D1W  = (uint16_t*)(ws + D1W_OFF);
  uint16_t* D2W  = (uint16_t*)(ws + D2W_OFF);
  float*    GRIDB= (float*)(ws + GRID_OFF);
  uint16_t* EGOT = (uint16_t*)(ws + EGOT_OFF);
  uint16_t* FEAT = (uint16_t*)(ws + FEAT_OFF);
  uint16_t* QB16 = (uint16_t*)(ws + QB_OFF);
  uint16_t* OBUF = (uint16_t*)(ws + OBUF_OFF);
  uint16_t* D1B  = (uint16_t*)(ws + D1_OFF);
  float*    D2B  = (float*)(ws + D2_OFF);
  uint16_t* WC   = (uint16_t*)(ws + WC_OFF);
  float*    BE   = (float*)(ws + BE_OFF);
  uint16_t* ENCWB= (uint16_t*)(ws + ENCW_OFF);
  float*    TMAT = (float*)(ws + TMAT_OFF);
  float*    ST1  = (float*)(ws + ST1_OFF);
  float*    ST2  = (float*)(ws + ST2_OFF);
  float*    outF = (float*)d_out;

  (void)hipMemsetAsync(ws + GRID_OFF, 0, 6422528, stream);
  (void)hipMemsetAsync(ws + ST1_OFF,  0, 8192, stream);

  // border zeros for both padded buffers (one launch)
  k_zborder<<<256,256,0,stream>>>(XP, Y1P);

  // constants / weight packs
  k_lstm_prep<<<1,256,0,stream>>>(Wih,Whh,bih,bhh,sW,sb,encW, WC,BE,ENCWB, TMAT);
  k_packw<<<dim3(512,17),64,0,stream>>>(conv1W, WP1, 512, 1088);
  k_packw2<<<dim3(512,8),64,0,stream>>>(conv2W, WP2);
  k_packwk<<<dim3(16,16),256,0,stream>>>(kWf, WKT);
  {
    F2BJobs jb;
    jb.s[0]=vWf;  jb.d[0]=WVB;   jb.n[0]=1024*512;
    jb.s[1]=qWf;  jb.d[1]=QW;    jb.n[1]=1024*576;
    jb.s[2]=aoW;  jb.d[2]=AOW;   jb.n[2]=512*1024;
    jb.s[3]=clsWf;jb.d[3]=CLSW;  jb.n[3]=25*1088;
    jb.s[4]=d1Wf; jb.d[4]=D1W;   jb.n[4]=256*1088;
    jb.s[5]=d2Wf; jb.d[5]=D2W;   jb.n[5]=400*256;
    k_f2b_multi<<<dim3(48,6),256,0,stream>>>(jb);
  }

  // encoders + scatter
  k_lstm<<<132,256,0,stream>>>(ego_seq, ag_seq, ego_len, ag_len, grid_pos,
                               WC, BE, ENCWB, encB, GRIDB, EGOT, FEAT);
  // conv input pack
  k_packx<<<dim3(128,34),256,0,stream>>>(cnn, GRIDB, XP);
  // conv1 (8-phase 256², +stats) -> BN1 -> relu (in place, padded)
  k_conv1_8p<<<196,512,0,stream>>>(XP, WP1, Y1P, ST1);
  k_bnapply<1><<<3136,256,0,stream>>>(Y1P, ST1, bn1g, bn1b, 25088, 1.f/25088.f, nullptr, nullptr);
  // conv2: dy-split f32 partials -> sum+stats -> BN2 apply (+ center -> egoT/feat)
  k_conv2dy<<<dim3(196,3),256,0,stream>>>(Y1P, WP2, PS);
  k_bn2sum<<<392,256,0,stream>>>(PS, Y2, ST2);
  k_bnapply<0><<<784,256,0,stream>>>(Y2, ST2, bn2g, bn2b, 6272, 1.f/6272.f, EGOT, FEAT);
  // q = egoT @ qW^T (bf16)
  k_sgemm<<<dim3(16,8),256,0,stream>>>(EGOT, 576, QW, 576, nullptr, QB16, 1024, 1024, 576, 0);
  // U = q @ Wk (per head), attn core, o = z @ Wv^T (per head)
  k_bgemm<<<dim3(8,8,16),256,0,stream>>>(QB16, 1024, 64, WKT, 64, 512, U16, 8192, 512, 64);
  k_attn2<<<256,512,0,stream>>>(U16, Y2, ZB16);
  k_bgemm<<<dim3(1,8,16),256,0,stream>>>(ZB16, 8192, 512, WVB, 512, 64, OBUF, 1024, 64, 512);
  // attn_out -> feat[:,0:512]
  k_sgemm<<<dim3(8,8),256,0,stream>>>(OBUF, 1024, AOW, 1024, aoB, FEAT, 1088, 512, 1024, 0);
  // conf -> d_out[121600:]
  k_sgemm<<<dim3(1,8),256,0,stream>>>(FEAT, 1088, CLSW, 1088, clsB, outF + 121600, 25, 25, 1088, 2);
  // dec1 (relu) -> dec2 -> traj
  k_sgemm<<<dim3(4,8),256,0,stream>>>(FEAT, 1088, D1W, 1088, d1B, D1B, 256, 256, 1088, 1);
  k_sgemm<<<dim3(7,8),256,0,stream>>>(D1B, 256, D2W, 256, d2B, D2B, 400, 400, 256, 2);
  k_traj<<<13,256,0,stream>>>(D2B, TMAT, outF);

  (void)in_sizes; (void)n_in; (void)out_size; (void)ws_size;
}

// Round 10
// 596.310 us; speedup vs baseline: 1.3665x; 1.0045x over previous
//
#include <hip/hip_runtime.h>
#include <stdint.h>
#include <stddef.h>

#define DEVINL static __device__ __forceinline__

typedef __attribute__((ext_vector_type(8))) short  bfrag;   // 8x bf16 (bits)
typedef __attribute__((ext_vector_type(4))) float  facc;    // MFMA accumulator

DEVINL uint16_t f2b(float f){
  uint32_t u = __float_as_uint(f);
  return (uint16_t)((u + 0x7fffu + ((u >> 16) & 1u)) >> 16);   // RNE
}
DEVINL float b2f(uint16_t b){ return __uint_as_float(((uint32_t)b) << 16); }

DEVINL facc MFMA(bfrag a, bfrag b, facc c){
  return __builtin_amdgcn_mfma_f32_16x16x32_bf16(a, b, c, 0, 0, 0);
}

// async global->LDS, 16B per lane; LDS dest = wave-uniform base + lane*16
DEVINL void gload16(const void* g, void* l){
  __builtin_amdgcn_global_load_lds(
      (const __attribute__((address_space(1))) uint32_t*)g,
      (__attribute__((address_space(3))) uint32_t*)l, 16, 0, 0);
}

DEVINL float fast_tanh(float x){           // tanh = 2*sigmoid(2x)-1
  return 2.f/(1.f+__expf(-2.f*x)) - 1.f;
}

// ---------------- multi-buffer f32 -> bf16 convert (one launch) ----------------
struct F2BJobs {
  const float* s[6];
  uint16_t*    d[6];
  int          n[6];
};
__global__ void k_f2b_multi(F2BJobs jobs){
  int j = blockIdx.y;
  const float* s = jobs.s[j];
  uint16_t* d = jobs.d[j];
  int n = jobs.n[j];
  int i = blockIdx.x*256 + threadIdx.x;
  int st = gridDim.x*256;
  for(; i<n; i+=st) d[i] = f2b(s[i]);
}

// ---------------- zero border pixels of padded buffers + GRIDB scatter buffer ----------------
__global__ void k_zborder(uint16_t* __restrict__ X, uint16_t* __restrict__ Y,
                          float* __restrict__ gridb){
  int b = blockIdx.x & 127, t = threadIdx.x;
  uint16_t* base = (blockIdx.x < 128) ? X : Y;
  int C = (blockIdx.x < 128) ? 1088 : 512;
  for(int p=0;p<60;p++){
    int y, x;
    if(p<16){ y=0; x=p; }
    else if(p<32){ y=15; x=p-16; }
    else { int q=p-32; y=1+(q>>1); x=(q&1)?15:0; }
    uint32_t* dst = (uint32_t*)(base + ((size_t)(b*16+y)*16 + x)*C);
    for(int i=t;i<C/2;i+=256) dst[i] = 0;
  }
  // zero 6.4MB GRIDB: 256 blocks x 6272 floats
  float* g = gridb + (size_t)blockIdx.x*6272;
  for(int i=t;i<6272;i+=256) g[i] = 0.f;
}

// ---------------- LSTM weight prep + Legendre tmat ----------------
__global__ void k_lstm_prep(const float* __restrict__ Wih, const float* __restrict__ Whh,
                            const float* __restrict__ bih, const float* __restrict__ bhh,
                            const float* __restrict__ sW, const float* __restrict__ sb,
                            const float* __restrict__ encW,
                            uint16_t* __restrict__ Wc, float* __restrict__ be,
                            uint16_t* __restrict__ encWb, float* __restrict__ tm){
  int n = threadIdx.x;
  if(n < 19){
    float tv = (float)(n - 6) / 12.0f;
    float Pm = 1.0f, Pc = tv;
    tm[0*19+n] = Pm * sqrtf(0.5f);
    tm[1*19+n] = Pc * sqrtf(1.5f);
    for(int q=1; q<7; q++){
      float Pn = ((float)(2*q+1)*tv*Pc - (float)q*Pm) / (float)(q+1);
      Pm = Pc; Pc = Pn;
      tm[(q+1)*19+n] = Pc * sqrtf((float)(2*(q+1)+1) * 0.5f);
    }
  }
  for(int k=0;k<64;k++) Wc[n*96+k] = f2b(Whh[n*64+k]);
  for(int k5=0;k5<5;k5++){
    float s = 0.f;
    for(int j=0;j<64;j++) s += Wih[n*64+j]*sW[j*5+k5];
    Wc[n*96+64+k5] = f2b(s);
  }
  for(int k=69;k<96;k++) Wc[n*96+k] = 0;
  float s = 0.f;
  for(int j=0;j<64;j++) s += Wih[n*64+j]*sb[j];
  be[n] = s + bih[n] + bhh[n];
  if(n < 64){
    for(int k=0;k<64;k++) encWb[n*64+k] = f2b(encW[n*64+k]);
  }
}

// ---------------- LSTM: 32 sequences / block, MFMA gates ----------------
__global__ __launch_bounds__(256) void k_lstm(
    const float* __restrict__ ego_seq, const float* __restrict__ ag_seq,
    const int* __restrict__ ego_len, const int* __restrict__ ag_len,
    const int* __restrict__ grid_pos,
    const uint16_t* __restrict__ Wc, const float* __restrict__ be,
    const uint16_t* __restrict__ encWb, const float* __restrict__ encB,
    float* __restrict__ agrid, uint16_t* __restrict__ egoT, uint16_t* __restrict__ feat)
{
  __shared__ __align__(16) uint16_t A[32*96];   // [seq][k] : k<64 h, 64..68 x_t, 69..95 zero
  __shared__ float Xf[32*160];                  // raw seq f32 [32][32][5]
  __shared__ int   idxs[32];

  int t = threadIdx.x, w = t>>6, l = t&63;
  int blk = blockIdx.x;
  bool isEgo = blk < 4;
  int seq0 = isEgo ? blk*32 : (blk-4)*32;
  const float* seqp = (isEgo ? ego_seq : ag_seq) + (size_t)seq0*160;

  for(int i=t;i<32*160;i+=256) Xf[i] = seqp[i];
  if(t < 32){
    int L = isEgo ? ego_len[seq0+t] : ag_len[seq0+t];
    if(L < 1) L = 1;
    idxs[t] = L-1;
  }
  for(int i=t;i<32*96;i+=256) A[i] = 0;

  bfrag bf[4][3];
  float be4[4];
  for(int ct=0;ct<4;ct++){
    int n = (ct*4+w)*16 + (l&15);
    for(int ks=0;ks<3;ks++)
      bf[ct][ks] = *(const bfrag*)(Wc + n*96 + ks*32 + (l>>4)*8);
    be4[ct] = be[n];
  }
  float cst[8], hl[8];
  for(int i=0;i<8;i++){ cst[i]=0.f; hl[i]=0.f; }
  __syncthreads();
  int myidx[8];
  for(int rt=0;rt<2;rt++) for(int r=0;r<4;r++){
    int s = rt*16 + (l>>4)*4 + r;
    myidx[rt*4+r] = idxs[s];
  }

  for(int st=0; st<32; st++){
    if(t < 160){ int s=t/5, kk=t%5; A[s*96+64+kk] = f2b(Xf[s*160 + st*5 + kk]); }
    __syncthreads();
    facc acc[2][4];
    for(int rt=0;rt<2;rt++) for(int ct=0;ct<4;ct++) acc[rt][ct] = facc{0.f,0.f,0.f,0.f};
    #pragma unroll
    for(int ks=0;ks<3;ks++){
      bfrag aA[2];
      #pragma unroll
      for(int rt=0;rt<2;rt++)
        aA[rt] = *(const bfrag*)(A + (rt*16+(l&15))*96 + ks*32 + (l>>4)*8);
      #pragma unroll
      for(int rt=0;rt<2;rt++)
        #pragma unroll
        for(int ct=0;ct<4;ct++)
          acc[rt][ct] = MFMA(aA[rt], bf[ct][ks], acc[rt][ct]);
    }
    __syncthreads();   // all A reads done before h overwrite
    #pragma unroll
    for(int rt=0;rt<2;rt++) for(int r=0;r<4;r++){
      int cell = rt*4+r;
      int s = rt*16 + (l>>4)*4 + r;
      float gi = acc[rt][0][r] + be4[0];
      float gf = acc[rt][1][r] + be4[1];
      float gg = acc[rt][2][r] + be4[2];
      float go = acc[rt][3][r] + be4[3];
      float si = 1.f/(1.f+__expf(-gi));
      float sf = 1.f/(1.f+__expf(-gf));
      float so = 1.f/(1.f+__expf(-go));
      float tg = fast_tanh(gg);
      float c2 = sf*cst[cell] + si*tg;
      cst[cell] = c2;
      float hn = so*fast_tanh(c2);
      A[s*96 + w*16 + (l&15)] = f2b(hn);
      if(st == myidx[cell]) hl[cell] = hn;
    }
  }
  __syncthreads();
  for(int rt=0;rt<2;rt++) for(int r=0;r<4;r++){
    int s = rt*16 + (l>>4)*4 + r;
    A[s*96 + w*16 + (l&15)] = f2b(hl[rt*4+r]);
  }
  __syncthreads();
  bfrag eb[2];
  for(int ks=0;ks<2;ks++)
    eb[ks] = *(const bfrag*)(encWb + (w*16+(l&15))*64 + ks*32 + (l>>4)*8);
  facc ea[2]; ea[0] = facc{0.f,0.f,0.f,0.f}; ea[1] = facc{0.f,0.f,0.f,0.f};
  for(int ks=0;ks<2;ks++){
    for(int rt=0;rt<2;rt++){
      bfrag aA = *(const bfrag*)(A + (rt*16+(l&15))*96 + ks*32 + (l>>4)*8);
      ea[rt] = MFMA(aA, eb[ks], ea[rt]);
    }
  }
  int n = w*16 + (l&15);
  float bn_ = encB[n];
  for(int rt=0;rt<2;rt++) for(int r=0;r<4;r++){
    int s = rt*16 + (l>>4)*4 + r;
    float v = ea[rt][r] + bn_;
    int gs = seq0 + s;
    if(isEgo){
      egoT[(size_t)gs*576 + 512 + n] = f2b(v);
      feat[(size_t)gs*1088 + 1024 + n] = f2b(v);
    } else {
      int py = grid_pos[gs*2+0], px = grid_pos[gs*2+1];
      atomicAdd(&agrid[((size_t)(gs>>5)*196 + py*14 + px)*64 + n], v);
    }
  }
}

// ---------------- pack conv1 input: NCHW f32 (+grid NHWC f32) -> padded NHWC bf16 ----------------
// R10: paired-channel u32 stores (was scalar u16).
__global__ void k_packx(const float* __restrict__ cnn, const float* __restrict__ agrid,
                        uint16_t* __restrict__ Xp)
{
  __shared__ float tile[32*200];
  int b = blockIdx.x, ch = blockIdx.y, t = threadIdx.x;
  if(ch < 32){
    int c0 = ch*32;
    for(int i=t;i<32*196;i+=256){
      int ci = i/196, s = i%196;
      tile[ci*200+s] = cnn[((size_t)b*1024 + c0+ci)*196 + s];
    }
    __syncthreads();
    for(int i=t;i<16*196;i+=256){
      int s = i>>4, c2 = i&15;
      int y = s/14, x = s%14;
      uint32_t pu = (uint32_t)f2b(tile[(2*c2)*200+s]) |
                    ((uint32_t)f2b(tile[(2*c2+1)*200+s])<<16);
      *(uint32_t*)(Xp + (((size_t)b*16 + y+1)*16 + x+1)*1088 + c0 + 2*c2) = pu;
    }
  } else {
    int j0 = (ch-32)*32;
    for(int i=t;i<16*196;i+=256){
      int s = i>>4, j2 = i&15;
      int y = s/14, x = s%14;
      const float* gsrc = agrid + ((size_t)b*196 + s)*64 + j0 + 2*j2;
      uint32_t pu = (uint32_t)f2b(gsrc[0]) | ((uint32_t)f2b(gsrc[1])<<16);
      *(uint32_t*)(Xp + (((size_t)b*16 + y+1)*16 + x+1)*1088 + 1024 + j0 + 2*j2) = pu;
    }
  }
}

// ---------------- pack conv1 weights OIHW f32 -> [dydx][O][C] bf16 ----------------
__global__ void k_packw(const float* __restrict__ W, uint16_t* __restrict__ Wp, int O, int C)
{
  int o = blockIdx.x;
  int c = blockIdx.y*64 + threadIdx.x;
  const float* src = W + ((size_t)o*C + c)*9;
  float v[9];
  #pragma unroll
  for(int d=0;d<9;d++) v[d] = src[d];
  #pragma unroll
  for(int d=0;d<9;d++)
    Wp[((size_t)d*O + o)*C + c] = f2b(v[d]);
}

// ---------------- pack conv2 weights OIHW -> [dy][O][dx*512+c] bf16 (flat K=1536 per dy) ----------------
__global__ void k_packw2(const float* __restrict__ W, uint16_t* __restrict__ Wp)
{
  int o = blockIdx.x;
  int c = blockIdx.y*64 + threadIdx.x;
  const float* src = W + ((size_t)o*512 + c)*9;
  float v[9];
  #pragma unroll
  for(int d=0;d<9;d++) v[d] = src[d];
  #pragma unroll
  for(int dy=0;dy<3;dy++)
    #pragma unroll
    for(int dx=0;dx<3;dx++)
      Wp[((size_t)(dy*512 + o))*1536 + dx*512 + c] = f2b(v[dy*3+dx]);
}

// ---------------- pack Wk transposed per head: WKT[h][c][d] = kW[(h*64+d)*512+c] ----------------
__global__ void k_packwk(const float* __restrict__ kW, uint16_t* __restrict__ WKT)
{
  int h = blockIdx.x;            // 16
  int c0 = blockIdx.y*32;        // 16 blocks
  int t = threadIdx.x;
  int d = t & 63;
  for(int ci = t>>6; ci<32; ci+=4){
    int c = c0 + ci;
    WKT[((size_t)h*512 + c)*64 + d] = f2b(kW[((size_t)(h*64+d))*512 + c]);
  }
}

// ================= conv1: 256x256 8-phase pipelined implicit GEMM =================
// (frozen from R9: 277us, MfmaUtil 39; dual persistent B regs; vmcnt ledger verified)
__global__ __launch_bounds__(512) void k_conv1_8p(
    const uint16_t* __restrict__ Ain, const uint16_t* __restrict__ Wb,
    uint16_t* __restrict__ Out, float* __restrict__ stats)
{
  constexpr int CB = 1088;
  constexpr int NSTEP = 153;          // 17 cc x 9 taps
  __shared__ __align__(16) char LDSb[131072];

  int t = threadIdx.x, w = t>>6, l = t&63;
  int wm = w>>2, wn = w&3;

  int xcd = blockIdx.x & 7, pos = blockIdx.x >> 3;
  int wgid = (xcd < 4 ? xcd*25 : 100 + (xcd-4)*24) + pos;
  int m0 = (wgid % 98) * 256;
  int n0 = (wgid / 98) * 256;

  const uint16_t* aP[2][2];
  const uint16_t* bP[2][2];
  #pragma unroll
  for(int P=0;P<2;P++)
    #pragma unroll
    for(int j=0;j<2;j++){
      int partrow = j*64 + (t>>3);
      int swz = ((t&7) ^ (partrow&7))*8;            // elements
      int gr = P*64 + partrow + ((partrow>=64)?64:0);
      int m = m0 + gr; int b = m/196, s = m%196, y = s/14, x = s%14;
      aP[P][j] = Ain + ((b*16+y)*16+x)*CB + swz;
      int nb = n0 + (partrow>>5)*64 + P*32 + (partrow&31);
      bP[P][j] = Wb + (size_t)nb*CB + swz;
    }

  facc acc[8][4];
  #pragma unroll
  for(int i=0;i<8;i++)
    #pragma unroll
    for(int j=0;j<4;j++) acc[i][j] = facc{0.f,0.f,0.f,0.f};

  bfrag aF[4][2], bF0[2][2], bF1[2][2];   // persistent operand fragments
  int dd = 0;

  #define STG(buf, PART) do{                                                   \
    if((PART)==0 || (PART)==3){ const int P_ = ((PART)==3);                    \
      _Pragma("unroll")                                                        \
      for(int j_=0;j_<2;j_++)                                                  \
        gload16(aP[P_][j_], LDSb + (buf)*65536 + P_*16384 + j_*8192 + w*1024); \
    } else { const int P_ = ((PART)==2);                                       \
      _Pragma("unroll")                                                        \
      for(int j_=0;j_<2;j_++)                                                  \
        gload16(bP[P_][j_], LDSb + (buf)*65536 + 32768 + P_*16384 + j_*8192 + w*1024); \
    }                                                                          \
  }while(0)

  #define ADVK() do{                                                          \
    if(dd==8){                                                                \
      _Pragma("unroll")                                                       \
      for(int P_=0;P_<2;P_++) for(int j_=0;j_<2;j_++){                        \
        aP[P_][j_] += 64 - 34*CB; bP[P_][j_] += 64 - 8*512*CB; }              \
      dd = 0;                                                                 \
    } else {                                                                  \
      int sA_ = (dd==2||dd==5) ? 14*CB : CB;                                  \
      _Pragma("unroll")                                                       \
      for(int P_=0;P_<2;P_++) for(int j_=0;j_<2;j_++){                        \
        aP[P_][j_] += sA_; bP[P_][j_] += 512*CB; }                            \
      dd++;                                                                   \
    }                                                                         \
  }while(0)

  #define VM4 asm volatile("s_waitcnt vmcnt(4)" ::: "memory")
  #define VM2 asm volatile("s_waitcnt vmcnt(2)" ::: "memory")
  #define VM0 asm volatile("s_waitcnt vmcnt(0)" ::: "memory")

  #define LDA(mh) do{                                                         \
    const uint16_t* Ab_ = (const uint16_t*)(LDSb + p*65536 + (mh)*16384);     \
    _Pragma("unroll")                                                         \
    for(int i_=0;i_<4;i_++)                                                   \
      _Pragma("unroll")                                                       \
      for(int ks_=0;ks_<2;ks_++)                                              \
        aF[i_][ks_] = *(const bfrag*)(Ab_ + (wm*64 + i_*16 + (l&15))*64       \
                        + ((ks_*32 + (l>>4)*8) ^ ((l&7)<<3)));                \
  }while(0)

  #define LDB(dst, nh) do{                                                   \
    const uint16_t* Bb_ = (const uint16_t*)(LDSb + p*65536 + 32768 + (nh)*16384); \
    _Pragma("unroll")                                                         \
    for(int j_=0;j_<2;j_++)                                                   \
      _Pragma("unroll")                                                       \
      for(int ks_=0;ks_<2;ks_++)                                              \
        dst[j_][ks_] = *(const bfrag*)(Bb_ + (wn*32 + j_*16 + (l&15))*64      \
                        + ((ks_*32 + (l>>4)*8) ^ ((l&7)<<3)));                \
  }while(0)

  #define MM(mh, nh, bsrc) do{                                               \
    __builtin_amdgcn_s_setprio(1);                                           \
    _Pragma("unroll")                                                        \
    for(int ks_=0;ks_<2;ks_++)                                               \
      _Pragma("unroll")                                                      \
      for(int i_=0;i_<4;i_++)                                                \
        _Pragma("unroll")                                                    \
        for(int j_=0;j_<2;j_++)                                              \
          acc[(mh)*4+i_][(nh)*2+j_] =                                        \
            MFMA(aF[i_][ks_], bsrc[j_][ks_], acc[(mh)*4+i_][(nh)*2+j_]);     \
    __builtin_amdgcn_s_setprio(0);                                           \
  }while(0)

  #define BARS do{ __builtin_amdgcn_sched_barrier(0); __builtin_amdgcn_s_barrier(); }while(0)
  #define EBAR __builtin_amdgcn_s_barrier()

  // prologue: stage K-tile 0 (A0,B0,B1,A1) into buf0
  STG(0,0); STG(0,1); STG(0,2); STG(0,3);
  ADVK();
  VM4;
  EBAR;

  for(int kt=0; kt<NSTEP-1; kt++){
    int p = kt&1;
    LDA(0); LDB(bF0,0); STG(p^1,0); BARS; MM(0,0,bF0); VM4; EBAR;
    LDB(bF1,1);         STG(p^1,1); BARS; MM(0,1,bF1); VM4; EBAR;
    LDA(1);             STG(p^1,2); BARS; MM(1,1,bF1);      EBAR;
                        STG(p^1,3); BARS; MM(1,0,bF0); VM4; EBAR;
    if(kt < NSTEP-2) ADVK();
  }
  { // peeled last K-tile (buf 0), no staging, drain
    int p = 0;
    LDA(0); LDB(bF0,0); BARS; MM(0,0,bF0); VM2; EBAR;
    LDB(bF1,1);         BARS; MM(0,1,bF1); VM0; EBAR;
    LDA(1);             BARS; MM(1,1,bF1);      EBAR;
                        BARS; MM(1,0,bF0);      EBAR;
  }

  #undef LDA
  #undef LDB
  #undef MM
  #undef BARS
  #undef EBAR
  #undef STG
  #undef ADVK

  __syncthreads();
  int* oo = (int*)LDSb;
  if(t < 256){
    int m = m0 + t; int b = m/196, s = m%196, y = s/14, x = s%14;
    oo[t] = ((b*16 + y+1)*16 + (x+1))*512;
  }
  __syncthreads();
  #pragma unroll
  for(int i=0;i<8;i++)
    #pragma unroll
    for(int j=0;j<4;j++){
      int n = n0 + wn*64 + j*16 + (l&15);
      #pragma unroll
      for(int r=0;r<4;r++){
        int mr = wm*128 + i*16 + (l>>4)*4 + r;
        Out[(size_t)oo[mr] + n] = f2b(acc[i][j][r]);
      }
    }
  __syncthreads();
  float* sred = (float*)LDSb;
  int rg = wm*4 + (l>>4);
  #pragma unroll
  for(int j=0;j<4;j++){
    float s=0.f, q=0.f;
    #pragma unroll
    for(int i=0;i<8;i++)
      #pragma unroll
      for(int r=0;r<4;r++){ float v = acc[i][j][r]; s += v; q += v*v; }
    int nl = wn*64 + j*16 + (l&15);
    sred[(nl*8 + rg)*2+0] = s;
    sred[(nl*8 + rg)*2+1] = q;
  }
  __syncthreads();
  if(t < 256){
    float s=0.f, q=0.f;
    #pragma unroll
    for(int rgi=0;rgi<8;rgi++){ s += sred[(t*8+rgi)*2]; q += sred[(t*8+rgi)*2+1]; }
    atomicAdd(&stats[n0+t], s);
    atomicAdd(&stats[512+n0+t], q);
  }
}

// ================= conv2: dy-split flat GEMM (K=1536 contiguous), bf16 partials =================
__global__ __launch_bounds__(256) void k_conv2dy(
    const uint16_t* __restrict__ Ain, const uint16_t* __restrict__ Wb,
    uint16_t* __restrict__ PS)
{
  __shared__ __align__(16) uint16_t As[128*64];
  __shared__ __align__(16) uint16_t Bs[128*64];

  int t = threadIdx.x, w = t>>6, l = t&63;
  int dy = blockIdx.y;

  int xcd = blockIdx.x & 7, pos = blockIdx.x >> 3;
  int wgid = (xcd < 4 ? xcd*25 : 100 + (xcd-4)*24) + pos;
  int n0 = (wgid / 49) * 128;
  int m0 = (wgid % 49) * 128;

  const uint16_t* aP[4];
  const uint16_t* bP[4];
  #pragma unroll
  for(int p=0;p<4;p++){
    int r = w*32 + p*8 + (l>>3);
    int m = m0 + r;
    int b = m/49, s = m%49, y = s/7, x = s%7;
    aP[p] = Ain + ((b*16 + 2*y + dy)*16 + 2*x)*512 + (l&7)*8;
    bP[p] = Wb + ((size_t)(dy*512 + n0 + r))*1536 + (l&7)*8;
  }

  facc acc[4][4];
  #pragma unroll
  for(int i=0;i<4;i++)
    #pragma unroll
    for(int j=0;j<4;j++) acc[i][j] = facc{0.f,0.f,0.f,0.f};
  int wm = w>>1, wn = w&1;
  char* asDst = (char*)As + w*4096;
  char* bsDst = (char*)Bs + w*4096;

  for(int stp=0; stp<24; stp++){
    #pragma unroll
    for(int p=0;p<4;p++){ gload16(aP[p], asDst + p*1024); aP[p] += 64; }
    #pragma unroll
    for(int p=0;p<4;p++){ gload16(bP[p], bsDst + p*1024); bP[p] += 64; }
    __syncthreads();
    #pragma unroll
    for(int ks=0;ks<2;ks++){
      bfrag a[4], b[4];
      #pragma unroll
      for(int i=0;i<4;i++)
        a[i] = *(const bfrag*)(As + (wm*64 + i*16 + (l&15))*64 + ks*32 + (l>>4)*8);
      #pragma unroll
      for(int j=0;j<4;j++)
        b[j] = *(const bfrag*)(Bs + (wn*64 + j*16 + (l&15))*64 + ks*32 + (l>>4)*8);
      #pragma unroll
      for(int i=0;i<4;i++)
        #pragma unroll
        for(int j=0;j<4;j++)
          acc[i][j] = MFMA(a[i], b[j], acc[i][j]);
    }
    __syncthreads();
  }

  uint16_t* out = PS + (size_t)dy*3211264;
  #pragma unroll
  for(int i=0;i<4;i++)
    #pragma unroll
    for(int j=0;j<4;j++){
      int n = n0 + wn*64 + j*16 + (l&15);
      #pragma unroll
      for(int r=0;r<4;r++){
        int mr = m0 + wm*64 + i*16 + (l>>4)*4 + r;
        out[(size_t)mr*512 + n] = f2b(acc[i][j][r]);
      }
    }
}

// ---------------- sum conv2 dy-partials (bf16) -> Y2 bf16 + BN2 stats ----------------
__global__ void k_bn2sum(const uint16_t* __restrict__ PS, uint16_t* __restrict__ Y2,
                         float* __restrict__ stats)
{
  int t = threadIdx.x;            // channel pair 2t, 2t+1
  int m0 = blockIdx.x*16;         // grid 392
  float s0=0,s1=0,q0=0,q1=0;
  for(int i=0;i<16;i++){
    size_t off = (size_t)(m0+i)*512 + 2*t;
    uint32_t u0 = *(const uint32_t*)(PS + off);
    uint32_t u1 = *(const uint32_t*)(PS + 3211264 + off);
    uint32_t u2 = *(const uint32_t*)(PS + 6422528 + off);
    float a = b2f((uint16_t)u0)+b2f((uint16_t)u1)+b2f((uint16_t)u2);
    float c = b2f((uint16_t)(u0>>16))+b2f((uint16_t)(u1>>16))+b2f((uint16_t)(u2>>16));
    s0+=a; q0+=a*a; s1+=c; q1+=c*c;
    *(uint32_t*)(Y2 + off) = (uint32_t)f2b(a) | ((uint32_t)f2b(c)<<16);
  }
  atomicAdd(&stats[2*t],   s0);
  atomicAdd(&stats[2*t+1], s1);
  atomicAdd(&stats[512+2*t],   q0);
  atomicAdd(&stats[512+2*t+1], q1);
}

// ---------------- BN apply + ReLU in-place; conv2 variant extracts center into egoT/feat ----------------
template<int PAD>
__global__ void k_bnapply(uint16_t* __restrict__ Y, const float* __restrict__ stats,
                          const float* __restrict__ gg, const float* __restrict__ bb,
                          int M, float invM,
                          uint16_t* __restrict__ egoT, uint16_t* __restrict__ feat)
{
  int t = threadIdx.x;
  int m0 = blockIdx.x*8;
  float mu0 = stats[2*t]*invM,       mu1 = stats[2*t+1]*invM;
  float v0 = stats[512+2*t]*invM - mu0*mu0, v1 = stats[512+2*t+1]*invM - mu1*mu1;
  float sc0 = gg[2*t]  *rsqrtf(v0+1e-5f), sc1 = gg[2*t+1]*rsqrtf(v1+1e-5f);
  float sh0 = bb[2*t]   - mu0*sc0,        sh1 = bb[2*t+1] - mu1*sc1;
  for(int i=0;i<8;i++){
    int m = m0+i; if(m>=M) break;
    size_t off;
    if(PAD){ int b=m/196, s=m%196, y=s/14, x=s%14; off = (((size_t)b*16+y+1)*16 + x+1)*512; }
    else off = (size_t)m*512;
    uint32_t u = *(const uint32_t*)(Y + off + 2*t);
    float a = fmaxf(b2f((uint16_t)u)*sc0 + sh0, 0.f);
    float c = fmaxf(b2f((uint16_t)(u>>16))*sc1 + sh1, 0.f);
    uint32_t pu = (uint32_t)f2b(a) | ((uint32_t)f2b(c)<<16);
    *(uint32_t*)(Y + off + 2*t) = pu;
    if(!PAD && (m%49)==24){
      int b = m/49;
      *(uint32_t*)(egoT + (size_t)b*576 + 2*t) = pu;
      *(uint32_t*)(feat + (size_t)b*1088 + 512 + 2*t) = pu;
    }
  }
}

// ---------------- small-M GEMM (M=128), no LDS ----------------
// flags: 1 = relu, 2 = f32 output (else bf16)
__global__ __launch_bounds__(256) void k_sgemm(
    const uint16_t* __restrict__ A, int lda,
    const uint16_t* __restrict__ B, int ldb,
    const float* __restrict__ bias,
    void* __restrict__ C, int ldc,
    int N, int K, int flags)
{
  int t = threadIdx.x, w = t>>6, l = t&63;
  int nt = blockIdx.x*4 + w;
  int n  = nt*16 + (l&15);
  int m0 = blockIdx.y*16;
  bool nv = n < N;
  facc acc = facc{0.f,0.f,0.f,0.f};
  for(int k=0;k<K;k+=32){
    bfrag af = *(const bfrag*)(A + (size_t)(m0+(l&15))*lda + k + (l>>4)*8);
    bfrag bf_ = {0,0,0,0,0,0,0,0};
    if(nv) bf_ = *(const bfrag*)(B + (size_t)n*ldb + k + (l>>4)*8);
    acc = MFMA(af, bf_, acc);
  }
  if(nv){
    float bv = bias ? bias[n] : 0.f;
    #pragma unroll
    for(int r=0;r<4;r++){
      int m = m0 + (l>>4)*4 + r;
      float v = acc[r] + bv;
      if(flags & 1) v = fmaxf(v, 0.f);
      if(flags & 2) ((float*)C)[(size_t)m*ldc + n] = v;
      else ((uint16_t*)C)[(size_t)m*ldc + n] = f2b(v);
    }
  }
}

// ---------------- batched per-head GEMM: C[m, z*coffs+n] = A[m, z*aoffs+k] . B[(z*brows+n), k] ----------------
__global__ __launch_bounds__(256) void k_bgemm(
    const uint16_t* __restrict__ A, int lda, int aoffs,
    const uint16_t* __restrict__ B, int ldb, int brows,
    uint16_t* __restrict__ C, int ldc, int coffs,
    int K)
{
  int t = threadIdx.x, w = t>>6, l = t&63;
  int z = blockIdx.z;
  int n = (blockIdx.x*4 + w)*16 + (l&15);
  int m0 = blockIdx.y*16;
  const uint16_t* Ab = A + (size_t)z*aoffs;
  const uint16_t* Bb = B + (size_t)z*brows*ldb;
  facc acc = facc{0.f,0.f,0.f,0.f};
  for(int k=0;k<K;k+=32){
    bfrag af = *(const bfrag*)(Ab + (size_t)(m0+(l&15))*lda + k + (l>>4)*8);
    bfrag bf_ = *(const bfrag*)(Bb + (size_t)n*ldb + k + (l>>4)*8);
    acc = MFMA(af, bf_, acc);
  }
  #pragma unroll
  for(int r=0;r<4;r++){
    int m = m0 + (l>>4)*4 + r;
    C[(size_t)m*ldc + z*coffs + n] = f2b(acc[r]);
  }
}

// ---------------- attention core: energy = U.y2, softmax (analytic ring), z = sum p*y2 ----------------
__global__ __launch_bounds__(512) void k_attn2(
    const uint16_t* __restrict__ U16, const uint16_t* __restrict__ y2,
    uint16_t* __restrict__ zout)
{
  __shared__ __align__(16) char LA[49*1024 + 8*1024];
  uint16_t* uls = (uint16_t*)(LA + 49*1024);
  int t = threadIdx.x, w = t>>6, l = t&63;
  int b = blockIdx.x >> 1, half = blockIdx.x & 1;
  int h = half*8 + w;

  for(int i=t; i<3136; i+=512){
    int g = i>>6, c16 = i&63;
    *(uint4*)(LA + g*1024 + ((c16*16) ^ ((g&31)<<4))) =
        *(const uint4*)(y2 + ((size_t)(b*49+g)*512 + c16*8));
  }
  *(uint4*)((char*)uls + w*1024 + l*16) =
      *(const uint4*)(U16 + (size_t)b*8192 + h*512 + l*8);
  __syncthreads();

  float dot = 0.f;
  if(l < 49){
    const char* yrow = LA + l*1024;
    const char* ur = (const char*)uls + w*1024;
    for(int c16=0;c16<64;c16++){
      uint4 uv = *(const uint4*)(ur + c16*16);
      uint4 yv = *(const uint4*)(yrow + ((c16*16) ^ ((l&31)<<4)));
      const uint16_t* up = (const uint16_t*)&uv;
      const uint16_t* yp = (const uint16_t*)&yv;
      #pragma unroll
      for(int j=0;j<8;j++) dot += b2f(up[j])*b2f(yp[j]);
    }
  }
  float e = (l<49) ? dot*(1.f/32.f) : -1e30f;
  float mx = e;
  for(int s=32;s>0;s>>=1) mx = fmaxf(mx, __shfl_xor(mx, s));
  mx = fmaxf(mx, 0.f);                      // 32 ring slots have energy 0
  float p = (l<49) ? __expf(e-mx) : 0.f;
  float den = p;
  for(int s=32;s>0;s>>=1) den += __shfl_xor(den, s);
  den += 32.f*__expf(-mx);

  float z[8];
  #pragma unroll
  for(int j=0;j<8;j++) z[j]=0.f;
  for(int g=0; g<49; g++){
    float pg = __shfl(p, g);
    uint4 yv = *(const uint4*)(LA + g*1024 + ((l*16) ^ ((g&31)<<4)));
    const uint16_t* yp = (const uint16_t*)&yv;
    #pragma unroll
    for(int j=0;j<8;j++) z[j] += pg*b2f(yp[j]);
  }
  float inv = 1.f/den;
  uint16_t zr[8];
  #pragma unroll
  for(int j=0;j<8;j++) zr[j] = f2b(z[j]*inv);
  *(uint4*)(zout + ((size_t)(b*16+h)*512) + l*8) = *(uint4*)zr;
}

// ---------------- trajectory: d2[b][25][16] @ tmat -> out [b][25][19][2] ----------------
__global__ void k_traj(const float* __restrict__ d2, const float* __restrict__ tm,
                       float* __restrict__ out)
{
  int i = blockIdx.x*256 + threadIdx.x;
  if(i >= 3200) return;
  const float* dp = d2 + (size_t)i*16;
  float cx[8], cy[8];
  #pragma unroll
  for(int j=0;j<8;j++){ cx[j]=dp[j]; cy[j]=dp[8+j]; }
  float* op = out + (size_t)i*38;
  for(int tt=0;tt<19;tt++){
    float x=0.f, y=0.f;
    #pragma unroll
    for(int j=0;j<8;j++){ float tv = tm[j*19+tt]; x += cx[j]*tv; y += cy[j]*tv; }
    op[tt*2+0]=x; op[tt*2+1]=y;
  }
}

// ======================= host =======================
extern "C" void kernel_launch(void* const* d_in, const int* in_sizes, int n_in,
                              void* d_out, int out_size, void* d_ws, size_t ws_size,
                              hipStream_t stream)
{
  const float* cnn      = (const float*)d_in[0];
  const float* ego_seq  = (const float*)d_in[1];
  const float* ag_seq   = (const float*)d_in[2];
  const int*   ego_len  = (const int*)d_in[3];
  const int*   ag_len   = (const int*)d_in[4];
  const int*   grid_pos = (const int*)d_in[5];
  const float* sW  = (const float*)d_in[6];
  const float* sb  = (const float*)d_in[7];
  const float* Wih = (const float*)d_in[8];
  const float* Whh = (const float*)d_in[9];
  const float* bih = (const float*)d_in[10];
  const float* bhh = (const float*)d_in[11];
  const float* encW = (const float*)d_in[12];
  const float* encB = (const float*)d_in[13];
  const float* conv1W = (const float*)d_in[14];
  const float* bn1g = (const float*)d_in[15];
  const float* bn1b = (const float*)d_in[16];
  const float* conv2W = (const float*)d_in[17];
  const float* bn2g = (const float*)d_in[18];
  const float* bn2b = (const float*)d_in[19];
  const float* qWf  = (const float*)d_in[20];
  const float* kWf  = (const float*)d_in[21];
  const float* vWf  = (const float*)d_in[22];
  const float* aoW  = (const float*)d_in[23];
  const float* aoB  = (const float*)d_in[24];
  const float* clsWf = (const float*)d_in[25];
  const float* clsB  = (const float*)d_in[26];
  const float* d1Wf  = (const float*)d_in[27];
  const float* d1B   = (const float*)d_in[28];
  const float* d2Wf  = (const float*)d_in[29];
  const float* d2B   = (const float*)d_in[30];

  char* ws = (char*)d_ws;
  const size_t XP_OFF   = 0;                 // 71 MB (dead after conv1)
  const size_t PS_OFF   = 0;                 // 19.3 MB bf16 partials (alias)
  const size_t U_OFF    = 0;                 // 2 MB (alias; after PS dead)
  const size_t ZB_OFF   = 2097152;           // 2 MB
  const size_t Y2_OFF   = 41943040;          // 6.4 MB
  const size_t Y1P_OFF  = 71303168;          // 33.5 MB
  const size_t WP1_OFF  = 104857600;
  const size_t WP2_OFF  = 114884608;
  const size_t WKT_OFF  = 119603200;         // 1 MB
  const size_t WVB_OFF  = 120651776;         // 1 MB
  const size_t QW_OFF   = 121700352;
  const size_t AOW_OFF  = 122880000;
  const size_t CLSW_OFF = 123928576;
  const size_t D1W_OFF  = 123982976;
  const size_t D2W_OFF  = 124540032;
  const size_t GRID_OFF = 124744832;
  const size_t EGOT_OFF = 131167360;
  const size_t FEAT_OFF = 131314816;
  const size_t QB_OFF   = 131593344;
  const size_t OBUF_OFF = 132117632;
  const size_t D1_OFF   = 132379776;
  const size_t D2_OFF   = 132445312;
  const size_t WC_OFF   = 132650112;
  const size_t BE_OFF   = 132699264;
  const size_t ENCW_OFF = 132700288;
  const size_t TMAT_OFF = 132708480;
  const size_t ST1_OFF  = 132709120;
  const size_t ST2_OFF  = 132713216;

  uint16_t* XP   = (uint16_t*)(ws + XP_OFF);
  uint16_t* PSB  = (uint16_t*)(ws + PS_OFF);
  uint16_t* U16  = (uint16_t*)(ws + U_OFF);
  uint16_t* ZB16 = (uint16_t*)(ws + ZB_OFF);
  uint16_t* Y2   = (uint16_t*)(ws + Y2_OFF);
  uint16_t* Y1P  = (uint16_t*)(ws + Y1P_OFF);
  uint16_t* WP1  = (uint16_t*)(ws + WP1_OFF);
  uint16_t* WP2  = (uint16_t*)(ws + WP2_OFF);
  uint16_t* WKT  = (uint16_t*)(ws + WKT_OFF);
  uint16_t* WVB  = (uint16_t*)(ws + WVB_OFF);
  uint16_t* QW   = (uint16_t*)(ws + QW_OFF);
  uint16_t* AOW  = (uint16_t*)(ws + AOW_OFF);
  uint16_t* CLSW = (uint16_t*)(ws + CLSW_OFF);
  uint16_t* D1W  = (uint16_t*)(ws + D1W_OFF);
  uint16_t* D2W  = (uint16_t*)(ws + D2W_OFF);
  float*    GRIDB= (float*)(ws + GRID_OFF);
  uint16_t* EGOT = (uint16_t*)(ws + EGOT_OFF);
  uint16_t* FEAT = (uint16_t*)(ws + FEAT_OFF);
  uint16_t* QB16 = (uint16_t*)(ws + QB_OFF);
  uint16_t* OBUF = (uint16_t*)(ws + OBUF_OFF);
  uint16_t* D1B  = (uint16_t*)(ws + D1_OFF);
  float*    D2B  = (float*)(ws + D2_OFF);
  uint16_t* WC   = (uint16_t*)(ws + WC_OFF);
  float*    BE   = (float*)(ws + BE_OFF);
  uint16_t* ENCWB= (uint16_t*)(ws + ENCW_OFF);
  float*    TMAT = (float*)(ws + TMAT_OFF);
  float*    ST1  = (float*)(ws + ST1_OFF);
  float*    ST2  = (float*)(ws + ST2_OFF);
  float*    outF = (float*)d_out;

  (void)hipMemsetAsync(ws + ST1_OFF,  0, 8192, stream);

  // border zeros + GRIDB zero (one launch)
  k_zborder<<<256,256,0,stream>>>(XP, Y1P, GRIDB);

  // constants / weight packs
  k_lstm_prep<<<1,256,0,stream>>>(Wih,Whh,bih,bhh,sW,sb,encW, WC,BE,ENCWB, TMAT);
  k_packw<<<dim3(512,17),64,0,stream>>>(conv1W, WP1, 512, 1088);
  k_packw2<<<dim3(512,8),64,0,stream>>>(conv2W, WP2);
  k_packwk<<<dim3(16,16),256,0,stream>>>(kWf, WKT);
  {
    F2BJobs jb;
    jb.s[0]=vWf;  jb.d[0]=WVB;   jb.n[0]=1024*512;
    jb.s[1]=qWf;  jb.d[1]=QW;    jb.n[1]=1024*576;
    jb.s[2]=aoW;  jb.d[2]=AOW;   jb.n[2]=512*1024;
    jb.s[3]=clsWf;jb.d[3]=CLSW;  jb.n[3]=25*1088;
    jb.s[4]=d1Wf; jb.d[4]=D1W;   jb.n[4]=256*1088;
    jb.s[5]=d2Wf; jb.d[5]=D2W;   jb.n[5]=400*256;
    k_f2b_multi<<<dim3(48,6),256,0,stream>>>(jb);
  }

  // encoders + scatter
  k_lstm<<<132,256,0,stream>>>(ego_seq, ag_seq, ego_len, ag_len, grid_pos,
                               WC, BE, ENCWB, encB, GRIDB, EGOT, FEAT);
  // conv input pack
  k_packx<<<dim3(128,34),256,0,stream>>>(cnn, GRIDB, XP);
  // conv1 (8-phase 256², +stats) -> BN1 -> relu (in place, padded)
  k_conv1_8p<<<196,512,0,stream>>>(XP, WP1, Y1P, ST1);
  k_bnapply<1><<<3136,256,0,stream>>>(Y1P, ST1, bn1g, bn1b, 25088, 1.f/25088.f, nullptr, nullptr);
  // conv2: dy-split bf16 partials -> sum+stats -> BN2 apply (+ center -> egoT/feat)
  k_conv2dy<<<dim3(196,3),256,0,stream>>>(Y1P, WP2, PSB);
  k_bn2sum<<<392,256,0,stream>>>(PSB, Y2, ST2);
  k_bnapply<0><<<784,256,0,stream>>>(Y2, ST2, bn2g, bn2b, 6272, 1.f/6272.f, EGOT, FEAT);
  // q = egoT @ qW^T (bf16)
  k_sgemm<<<dim3(16,8),256,0,stream>>>(EGOT, 576, QW, 576, nullptr, QB16, 1024, 1024, 576, 0);
  // U = q @ Wk (per head), attn core, o = z @ Wv^T (per head)
  k_bgemm<<<dim3(8,8,16),256,0,stream>>>(QB16, 1024, 64, WKT, 64, 512, U16, 8192, 512, 64);
  k_attn2<<<256,512,0,stream>>>(U16, Y2, ZB16);
  k_bgemm<<<dim3(1,8,16),256,0,stream>>>(ZB16, 8192, 512, WVB, 512, 64, OBUF, 1024, 64, 512);
  // attn_out -> feat[:,0:512]
  k_sgemm<<<dim3(8,8),256,0,stream>>>(OBUF, 1024, AOW, 1024, aoB, FEAT, 1088, 512, 1024, 0);
  // conf -> d_out[121600:]
  k_sgemm<<<dim3(1,8),256,0,stream>>>(FEAT, 1088, CLSW, 1088, clsB, outF + 121600, 25, 25, 1088, 2);
  // dec1 (relu) -> dec2 -> traj
  k_sgemm<<<dim3(4,8),256,0,stream>>>(FEAT, 1088, D1W, 1088, d1B, D1B, 256, 256, 1088, 1);
  k_sgemm<<<dim3(7,8),256,0,stream>>>(D1B, 256, D2W, 256, d2B, D2B, 400, 400, 256, 2);
  k_traj<<<13,256,0,stream>>>(D2B, TMAT, outF);

  (void)in_sizes; (void)n_in; (void)out_size; (void)ws_size;
}

// Round 11
// 588.620 us; speedup vs baseline: 1.3844x; 1.0131x over previous
//
#include <hip/hip_runtime.h>
#include <stdint.h>
#include <stddef.h>

#define DEVINL static __device__ __forceinline__

typedef __attribute__((ext_vector_type(8))) short  bfrag;   // 8x bf16 (bits)
typedef __attribute__((ext_vector_type(4))) float  facc;    // MFMA accumulator

DEVINL uint16_t f2b(float f){
  uint32_t u = __float_as_uint(f);
  return (uint16_t)((u + 0x7fffu + ((u >> 16) & 1u)) >> 16);   // RNE
}
DEVINL float b2f(uint16_t b){ return __uint_as_float(((uint32_t)b) << 16); }

DEVINL facc MFMA(bfrag a, bfrag b, facc c){
  return __builtin_amdgcn_mfma_f32_16x16x32_bf16(a, b, c, 0, 0, 0);
}

// async global->LDS, 16B per lane; LDS dest = wave-uniform base + lane*16
DEVINL void gload16(const void* g, void* l){
  __builtin_amdgcn_global_load_lds(
      (const __attribute__((address_space(1))) uint32_t*)g,
      (__attribute__((address_space(3))) uint32_t*)l, 16, 0, 0);
}

DEVINL float fast_tanh(float x){           // tanh = 2*sigmoid(2x)-1
  return 2.f/(1.f+__expf(-2.f*x)) - 1.f;
}

// ---------------- multi-buffer f32 -> bf16 convert (one launch) ----------------
struct F2BJobs {
  const float* s[6];
  uint16_t*    d[6];
  int          n[6];
};
__global__ void k_f2b_multi(F2BJobs jobs){
  int j = blockIdx.y;
  const float* s = jobs.s[j];
  uint16_t* d = jobs.d[j];
  int n = jobs.n[j];
  int i = blockIdx.x*256 + threadIdx.x;
  int st = gridDim.x*256;
  for(; i<n; i+=st) d[i] = f2b(s[i]);
}

// ---------------- zero borders + GRIDB + BN stats (one launch) ----------------
__global__ void k_zborder(uint16_t* __restrict__ X, uint16_t* __restrict__ Y,
                          float* __restrict__ gridb, float* __restrict__ stats){
  int b = blockIdx.x & 127, t = threadIdx.x;
  uint16_t* base = (blockIdx.x < 128) ? X : Y;
  int C = (blockIdx.x < 128) ? 1088 : 512;
  for(int p=0;p<60;p++){
    int y, x;
    if(p<16){ y=0; x=p; }
    else if(p<32){ y=15; x=p-16; }
    else { int q=p-32; y=1+(q>>1); x=(q&1)?15:0; }
    uint32_t* dst = (uint32_t*)(base + ((size_t)(b*16+y)*16 + x)*C);
    for(int i=t;i<C/2;i+=256) dst[i] = 0;
  }
  float* g = gridb + (size_t)blockIdx.x*6272;
  for(int i=t;i<6272;i+=256) g[i] = 0.f;
  if(blockIdx.x == 0){
    for(int i=t;i<2048;i+=256) stats[i] = 0.f;   // ST1 (1024) + ST2 (1024)
  }
}

// ---------------- LSTM weight prep + Legendre tmat ----------------
__global__ void k_lstm_prep(const float* __restrict__ Wih, const float* __restrict__ Whh,
                            const float* __restrict__ bih, const float* __restrict__ bhh,
                            const float* __restrict__ sW, const float* __restrict__ sb,
                            const float* __restrict__ encW,
                            uint16_t* __restrict__ Wc, float* __restrict__ be,
                            uint16_t* __restrict__ encWb, float* __restrict__ tm){
  int n = threadIdx.x;
  if(n < 19){
    float tv = (float)(n - 6) / 12.0f;
    float Pm = 1.0f, Pc = tv;
    tm[0*19+n] = Pm * sqrtf(0.5f);
    tm[1*19+n] = Pc * sqrtf(1.5f);
    for(int q=1; q<7; q++){
      float Pn = ((float)(2*q+1)*tv*Pc - (float)q*Pm) / (float)(q+1);
      Pm = Pc; Pc = Pn;
      tm[(q+1)*19+n] = Pc * sqrtf((float)(2*(q+1)+1) * 0.5f);
    }
  }
  for(int k=0;k<64;k++) Wc[n*96+k] = f2b(Whh[n*64+k]);
  for(int k5=0;k5<5;k5++){
    float s = 0.f;
    for(int j=0;j<64;j++) s += Wih[n*64+j]*sW[j*5+k5];
    Wc[n*96+64+k5] = f2b(s);
  }
  for(int k=69;k<96;k++) Wc[n*96+k] = 0;
  float s = 0.f;
  for(int j=0;j<64;j++) s += Wih[n*64+j]*sb[j];
  be[n] = s + bih[n] + bhh[n];
  if(n < 64){
    for(int k=0;k<64;k++) encWb[n*64+k] = f2b(encW[n*64+k]);
  }
}

// ---------------- LSTM: 32 sequences / block, MFMA gates ----------------
__global__ __launch_bounds__(256) void k_lstm(
    const float* __restrict__ ego_seq, const float* __restrict__ ag_seq,
    const int* __restrict__ ego_len, const int* __restrict__ ag_len,
    const int* __restrict__ grid_pos,
    const uint16_t* __restrict__ Wc, const float* __restrict__ be,
    const uint16_t* __restrict__ encWb, const float* __restrict__ encB,
    float* __restrict__ agrid, uint16_t* __restrict__ egoT, uint16_t* __restrict__ feat)
{
  __shared__ __align__(16) uint16_t A[32*96];   // [seq][k] : k<64 h, 64..68 x_t, 69..95 zero
  __shared__ float Xf[32*160];                  // raw seq f32 [32][32][5]
  __shared__ int   idxs[32];

  int t = threadIdx.x, w = t>>6, l = t&63;
  int blk = blockIdx.x;
  bool isEgo = blk < 4;
  int seq0 = isEgo ? blk*32 : (blk-4)*32;
  const float* seqp = (isEgo ? ego_seq : ag_seq) + (size_t)seq0*160;

  for(int i=t;i<32*160;i+=256) Xf[i] = seqp[i];
  if(t < 32){
    int L = isEgo ? ego_len[seq0+t] : ag_len[seq0+t];
    if(L < 1) L = 1;
    idxs[t] = L-1;
  }
  for(int i=t;i<32*96;i+=256) A[i] = 0;

  bfrag bf[4][3];
  float be4[4];
  for(int ct=0;ct<4;ct++){
    int n = (ct*4+w)*16 + (l&15);
    for(int ks=0;ks<3;ks++)
      bf[ct][ks] = *(const bfrag*)(Wc + n*96 + ks*32 + (l>>4)*8);
    be4[ct] = be[n];
  }
  float cst[8], hl[8];
  for(int i=0;i<8;i++){ cst[i]=0.f; hl[i]=0.f; }
  __syncthreads();
  int myidx[8];
  for(int rt=0;rt<2;rt++) for(int r=0;r<4;r++){
    int s = rt*16 + (l>>4)*4 + r;
    myidx[rt*4+r] = idxs[s];
  }

  for(int st=0; st<32; st++){
    if(t < 160){ int s=t/5, kk=t%5; A[s*96+64+kk] = f2b(Xf[s*160 + st*5 + kk]); }
    __syncthreads();
    facc acc[2][4];
    for(int rt=0;rt<2;rt++) for(int ct=0;ct<4;ct++) acc[rt][ct] = facc{0.f,0.f,0.f,0.f};
    #pragma unroll
    for(int ks=0;ks<3;ks++){
      bfrag aA[2];
      #pragma unroll
      for(int rt=0;rt<2;rt++)
        aA[rt] = *(const bfrag*)(A + (rt*16+(l&15))*96 + ks*32 + (l>>4)*8);
      #pragma unroll
      for(int rt=0;rt<2;rt++)
        #pragma unroll
        for(int ct=0;ct<4;ct++)
          acc[rt][ct] = MFMA(aA[rt], bf[ct][ks], acc[rt][ct]);
    }
    __syncthreads();   // all A reads done before h overwrite
    #pragma unroll
    for(int rt=0;rt<2;rt++) for(int r=0;r<4;r++){
      int cell = rt*4+r;
      int s = rt*16 + (l>>4)*4 + r;
      float gi = acc[rt][0][r] + be4[0];
      float gf = acc[rt][1][r] + be4[1];
      float gg = acc[rt][2][r] + be4[2];
      float go = acc[rt][3][r] + be4[3];
      float si = 1.f/(1.f+__expf(-gi));
      float sf = 1.f/(1.f+__expf(-gf));
      float so = 1.f/(1.f+__expf(-go));
      float tg = fast_tanh(gg);
      float c2 = sf*cst[cell] + si*tg;
      cst[cell] = c2;
      float hn = so*fast_tanh(c2);
      A[s*96 + w*16 + (l&15)] = f2b(hn);
      if(st == myidx[cell]) hl[cell] = hn;
    }
  }
  __syncthreads();
  for(int rt=0;rt<2;rt++) for(int r=0;r<4;r++){
    int s = rt*16 + (l>>4)*4 + r;
    A[s*96 + w*16 + (l&15)] = f2b(hl[rt*4+r]);
  }
  __syncthreads();
  bfrag eb[2];
  for(int ks=0;ks<2;ks++)
    eb[ks] = *(const bfrag*)(encWb + (w*16+(l&15))*64 + ks*32 + (l>>4)*8);
  facc ea[2]; ea[0] = facc{0.f,0.f,0.f,0.f}; ea[1] = facc{0.f,0.f,0.f,0.f};
  for(int ks=0;ks<2;ks++){
    for(int rt=0;rt<2;rt++){
      bfrag aA = *(const bfrag*)(A + (rt*16+(l&15))*96 + ks*32 + (l>>4)*8);
      ea[rt] = MFMA(aA, eb[ks], ea[rt]);
    }
  }
  int n = w*16 + (l&15);
  float bn_ = encB[n];
  for(int rt=0;rt<2;rt++) for(int r=0;r<4;r++){
    int s = rt*16 + (l>>4)*4 + r;
    float v = ea[rt][r] + bn_;
    int gs = seq0 + s;
    if(isEgo){
      egoT[(size_t)gs*576 + 512 + n] = f2b(v);
      feat[(size_t)gs*1088 + 1024 + n] = f2b(v);
    } else {
      int py = grid_pos[gs*2+0], px = grid_pos[gs*2+1];
      atomicAdd(&agrid[((size_t)(gs>>5)*196 + py*14 + px)*64 + n], v);
    }
  }
}

// ---------------- pack conv1 input: NCHW f32 (+grid NHWC f32) -> padded NHWC bf16 ----------------
__global__ void k_packx(const float* __restrict__ cnn, const float* __restrict__ agrid,
                        uint16_t* __restrict__ Xp)
{
  __shared__ float tile[32*200];
  int b = blockIdx.x, ch = blockIdx.y, t = threadIdx.x;
  if(ch < 32){
    int c0 = ch*32;
    for(int i=t;i<32*196;i+=256){
      int ci = i/196, s = i%196;
      tile[ci*200+s] = cnn[((size_t)b*1024 + c0+ci)*196 + s];
    }
    __syncthreads();
    for(int i=t;i<16*196;i+=256){
      int s = i>>4, c2 = i&15;
      int y = s/14, x = s%14;
      uint32_t pu = (uint32_t)f2b(tile[(2*c2)*200+s]) |
                    ((uint32_t)f2b(tile[(2*c2+1)*200+s])<<16);
      *(uint32_t*)(Xp + (((size_t)b*16 + y+1)*16 + x+1)*1088 + c0 + 2*c2) = pu;
    }
  } else {
    int j0 = (ch-32)*32;
    for(int i=t;i<16*196;i+=256){
      int s = i>>4, j2 = i&15;
      int y = s/14, x = s%14;
      const float* gsrc = agrid + ((size_t)b*196 + s)*64 + j0 + 2*j2;
      uint32_t pu = (uint32_t)f2b(gsrc[0]) | ((uint32_t)f2b(gsrc[1])<<16);
      *(uint32_t*)(Xp + (((size_t)b*16 + y+1)*16 + x+1)*1088 + 1024 + j0 + 2*j2) = pu;
    }
  }
}

// ---------------- pack conv1 weights OIHW f32 -> [dydx][O][C] bf16 ----------------
__global__ void k_packw(const float* __restrict__ W, uint16_t* __restrict__ Wp, int O, int C)
{
  int o = blockIdx.x;
  int c = blockIdx.y*64 + threadIdx.x;
  const float* src = W + ((size_t)o*C + c)*9;
  float v[9];
  #pragma unroll
  for(int d=0;d<9;d++) v[d] = src[d];
  #pragma unroll
  for(int d=0;d<9;d++)
    Wp[((size_t)d*O + o)*C + c] = f2b(v[d]);
}

// ---------------- pack conv2 weights OIHW -> [dy][O][dx*512+c] bf16 (flat K=1536 per dy) ----------------
__global__ void k_packw2(const float* __restrict__ W, uint16_t* __restrict__ Wp)
{
  int o = blockIdx.x;
  int c = blockIdx.y*64 + threadIdx.x;
  const float* src = W + ((size_t)o*512 + c)*9;
  float v[9];
  #pragma unroll
  for(int d=0;d<9;d++) v[d] = src[d];
  #pragma unroll
  for(int dy=0;dy<3;dy++)
    #pragma unroll
    for(int dx=0;dx<3;dx++)
      Wp[((size_t)(dy*512 + o))*1536 + dx*512 + c] = f2b(v[dy*3+dx]);
}

// ---------------- pack Wk transposed per head: WKT[h][c][d] = kW[(h*64+d)*512+c] ----------------
__global__ void k_packwk(const float* __restrict__ kW, uint16_t* __restrict__ WKT)
{
  int h = blockIdx.x;            // 16
  int c0 = blockIdx.y*32;        // 16 blocks
  int t = threadIdx.x;
  int d = t & 63;
  for(int ci = t>>6; ci<32; ci+=4){
    int c = c0 + ci;
    WKT[((size_t)h*512 + c)*64 + d] = f2b(kW[((size_t)(h*64+d))*512 + c]);
  }
}

// ================= conv1: 256x256 8-phase pipelined implicit GEMM =================
// (frozen from R9: 275us, MfmaUtil 39; dual persistent B regs; vmcnt ledger verified)
__global__ __launch_bounds__(512) void k_conv1_8p(
    const uint16_t* __restrict__ Ain, const uint16_t* __restrict__ Wb,
    uint16_t* __restrict__ Out, float* __restrict__ stats)
{
  constexpr int CB = 1088;
  constexpr int NSTEP = 153;          // 17 cc x 9 taps
  __shared__ __align__(16) char LDSb[131072];

  int t = threadIdx.x, w = t>>6, l = t&63;
  int wm = w>>2, wn = w&3;

  int xcd = blockIdx.x & 7, pos = blockIdx.x >> 3;
  int wgid = (xcd < 4 ? xcd*25 : 100 + (xcd-4)*24) + pos;
  int m0 = (wgid % 98) * 256;
  int n0 = (wgid / 98) * 256;

  const uint16_t* aP[2][2];
  const uint16_t* bP[2][2];
  #pragma unroll
  for(int P=0;P<2;P++)
    #pragma unroll
    for(int j=0;j<2;j++){
      int partrow = j*64 + (t>>3);
      int swz = ((t&7) ^ (partrow&7))*8;            // elements
      int gr = P*64 + partrow + ((partrow>=64)?64:0);
      int m = m0 + gr; int b = m/196, s = m%196, y = s/14, x = s%14;
      aP[P][j] = Ain + ((b*16+y)*16+x)*CB + swz;
      int nb = n0 + (partrow>>5)*64 + P*32 + (partrow&31);
      bP[P][j] = Wb + (size_t)nb*CB + swz;
    }

  facc acc[8][4];
  #pragma unroll
  for(int i=0;i<8;i++)
    #pragma unroll
    for(int j=0;j<4;j++) acc[i][j] = facc{0.f,0.f,0.f,0.f};

  bfrag aF[4][2], bF0[2][2], bF1[2][2];   // persistent operand fragments
  int dd = 0;

  #define STG(buf, PART) do{                                                   \
    if((PART)==0 || (PART)==3){ const int P_ = ((PART)==3);                    \
      _Pragma("unroll")                                                        \
      for(int j_=0;j_<2;j_++)                                                  \
        gload16(aP[P_][j_], LDSb + (buf)*65536 + P_*16384 + j_*8192 + w*1024); \
    } else { const int P_ = ((PART)==2);                                       \
      _Pragma("unroll")                                                        \
      for(int j_=0;j_<2;j_++)                                                  \
        gload16(bP[P_][j_], LDSb + (buf)*65536 + 32768 + P_*16384 + j_*8192 + w*1024); \
    }                                                                          \
  }while(0)

  #define ADVK() do{                                                          \
    if(dd==8){                                                                \
      _Pragma("unroll")                                                       \
      for(int P_=0;P_<2;P_++) for(int j_=0;j_<2;j_++){                        \
        aP[P_][j_] += 64 - 34*CB; bP[P_][j_] += 64 - 8*512*CB; }              \
      dd = 0;                                                                 \
    } else {                                                                  \
      int sA_ = (dd==2||dd==5) ? 14*CB : CB;                                  \
      _Pragma("unroll")                                                       \
      for(int P_=0;P_<2;P_++) for(int j_=0;j_<2;j_++){                        \
        aP[P_][j_] += sA_; bP[P_][j_] += 512*CB; }                            \
      dd++;                                                                   \
    }                                                                         \
  }while(0)

  #define VM4 asm volatile("s_waitcnt vmcnt(4)" ::: "memory")
  #define VM2 asm volatile("s_waitcnt vmcnt(2)" ::: "memory")
  #define VM0 asm volatile("s_waitcnt vmcnt(0)" ::: "memory")

  #define LDA(mh) do{                                                         \
    const uint16_t* Ab_ = (const uint16_t*)(LDSb + p*65536 + (mh)*16384);     \
    _Pragma("unroll")                                                         \
    for(int i_=0;i_<4;i_++)                                                   \
      _Pragma("unroll")                                                       \
      for(int ks_=0;ks_<2;ks_++)                                              \
        aF[i_][ks_] = *(const bfrag*)(Ab_ + (wm*64 + i_*16 + (l&15))*64       \
                        + ((ks_*32 + (l>>4)*8) ^ ((l&7)<<3)));                \
  }while(0)

  #define LDB(dst, nh) do{                                                   \
    const uint16_t* Bb_ = (const uint16_t*)(LDSb + p*65536 + 32768 + (nh)*16384); \
    _Pragma("unroll")                                                         \
    for(int j_=0;j_<2;j_++)                                                   \
      _Pragma("unroll")                                                       \
      for(int ks_=0;ks_<2;ks_++)                                              \
        dst[j_][ks_] = *(const bfrag*)(Bb_ + (wn*32 + j_*16 + (l&15))*64      \
                        + ((ks_*32 + (l>>4)*8) ^ ((l&7)<<3)));                \
  }while(0)

  #define MM(mh, nh, bsrc) do{                                               \
    __builtin_amdgcn_s_setprio(1);                                           \
    _Pragma("unroll")                                                        \
    for(int ks_=0;ks_<2;ks_++)                                               \
      _Pragma("unroll")                                                      \
      for(int i_=0;i_<4;i_++)                                                \
        _Pragma("unroll")                                                    \
        for(int j_=0;j_<2;j_++)                                              \
          acc[(mh)*4+i_][(nh)*2+j_] =                                        \
            MFMA(aF[i_][ks_], bsrc[j_][ks_], acc[(mh)*4+i_][(nh)*2+j_]);     \
    __builtin_amdgcn_s_setprio(0);                                           \
  }while(0)

  #define BARS do{ __builtin_amdgcn_sched_barrier(0); __builtin_amdgcn_s_barrier(); }while(0)
  #define EBAR __builtin_amdgcn_s_barrier()

  // prologue: stage K-tile 0 (A0,B0,B1,A1) into buf0
  STG(0,0); STG(0,1); STG(0,2); STG(0,3);
  ADVK();
  VM4;
  EBAR;

  for(int kt=0; kt<NSTEP-1; kt++){
    int p = kt&1;
    LDA(0); LDB(bF0,0); STG(p^1,0); BARS; MM(0,0,bF0); VM4; EBAR;
    LDB(bF1,1);         STG(p^1,1); BARS; MM(0,1,bF1); VM4; EBAR;
    LDA(1);             STG(p^1,2); BARS; MM(1,1,bF1);      EBAR;
                        STG(p^1,3); BARS; MM(1,0,bF0); VM4; EBAR;
    if(kt < NSTEP-2) ADVK();
  }
  { // peeled last K-tile (buf 0), no staging, drain
    int p = 0;
    LDA(0); LDB(bF0,0); BARS; MM(0,0,bF0); VM2; EBAR;
    LDB(bF1,1);         BARS; MM(0,1,bF1); VM0; EBAR;
    LDA(1);             BARS; MM(1,1,bF1);      EBAR;
                        BARS; MM(1,0,bF0);      EBAR;
  }

  #undef LDA
  #undef LDB
  #undef MM
  #undef BARS
  #undef EBAR
  #undef STG
  #undef ADVK

  __syncthreads();
  int* oo = (int*)LDSb;
  if(t < 256){
    int m = m0 + t; int b = m/196, s = m%196, y = s/14, x = s%14;
    oo[t] = ((b*16 + y+1)*16 + (x+1))*512;
  }
  __syncthreads();
  #pragma unroll
  for(int i=0;i<8;i++)
    #pragma unroll
    for(int j=0;j<4;j++){
      int n = n0 + wn*64 + j*16 + (l&15);
      #pragma unroll
      for(int r=0;r<4;r++){
        int mr = wm*128 + i*16 + (l>>4)*4 + r;
        Out[(size_t)oo[mr] + n] = f2b(acc[i][j][r]);
      }
    }
  __syncthreads();
  float* sred = (float*)LDSb;
  int rg = wm*4 + (l>>4);
  #pragma unroll
  for(int j=0;j<4;j++){
    float s=0.f, q=0.f;
    #pragma unroll
    for(int i=0;i<8;i++)
      #pragma unroll
      for(int r=0;r<4;r++){ float v = acc[i][j][r]; s += v; q += v*v; }
    int nl = wn*64 + j*16 + (l&15);
    sred[(nl*8 + rg)*2+0] = s;
    sred[(nl*8 + rg)*2+1] = q;
  }
  __syncthreads();
  if(t < 256){
    float s=0.f, q=0.f;
    #pragma unroll
    for(int rgi=0;rgi<8;rgi++){ s += sred[(t*8+rgi)*2]; q += sred[(t*8+rgi)*2+1]; }
    atomicAdd(&stats[n0+t], s);
    atomicAdd(&stats[512+n0+t], q);
  }
}

// ================= conv2: dy-split flat GEMM, 2-phase double-buffered (T3-min) =================
// Stage tile t+1 before computing tile t; counted vmcnt(8) (8 loads/thread/tile);
// raw s_barrier + sched_barrier(0) pins. K-order per element unchanged (canary).
__global__ __launch_bounds__(256) void k_conv2dy(
    const uint16_t* __restrict__ Ain, const uint16_t* __restrict__ Wb,
    uint16_t* __restrict__ PS)
{
  __shared__ __align__(16) uint16_t As[2*128*64];
  __shared__ __align__(16) uint16_t Bs[2*128*64];

  int t = threadIdx.x, w = t>>6, l = t&63;
  int dy = blockIdx.y;

  int xcd = blockIdx.x & 7, pos = blockIdx.x >> 3;
  int wgid = (xcd < 4 ? xcd*25 : 100 + (xcd-4)*24) + pos;
  int n0 = (wgid / 49) * 128;
  int m0 = (wgid % 49) * 128;

  const uint16_t* aP[4];
  const uint16_t* bP[4];
  #pragma unroll
  for(int p=0;p<4;p++){
    int r = w*32 + p*8 + (l>>3);
    int m = m0 + r;
    int b = m/49, s = m%49, y = s/7, x = s%7;
    aP[p] = Ain + ((b*16 + 2*y + dy)*16 + 2*x)*512 + (l&7)*8;
    bP[p] = Wb + ((size_t)(dy*512 + n0 + r))*1536 + (l&7)*8;
  }

  facc acc[4][4];
  #pragma unroll
  for(int i=0;i<4;i++)
    #pragma unroll
    for(int j=0;j<4;j++) acc[i][j] = facc{0.f,0.f,0.f,0.f};
  int wm = w>>1, wn = w&1;

  #define C2STG(buf) do{                                                    \
    char* ad_ = (char*)As + (buf)*16384 + w*4096;                           \
    char* bd_ = (char*)Bs + (buf)*16384 + w*4096;                           \
    _Pragma("unroll")                                                       \
    for(int p=0;p<4;p++){ gload16(aP[p], ad_ + p*1024); aP[p] += 64; }      \
    _Pragma("unroll")                                                       \
    for(int p=0;p<4;p++){ gload16(bP[p], bd_ + p*1024); bP[p] += 64; }      \
  }while(0)

  #define C2CMP(buf) do{                                                    \
    const uint16_t* Ab_ = As + (buf)*8192;                                  \
    const uint16_t* Bb_ = Bs + (buf)*8192;                                  \
    _Pragma("unroll")                                                       \
    for(int ks=0;ks<2;ks++){                                                \
      bfrag a_[4], b_[4];                                                   \
      _Pragma("unroll")                                                     \
      for(int i=0;i<4;i++)                                                  \
        a_[i] = *(const bfrag*)(Ab_ + (wm*64 + i*16 + (l&15))*64 + ks*32 + (l>>4)*8); \
      _Pragma("unroll")                                                     \
      for(int j=0;j<4;j++)                                                  \
        b_[j] = *(const bfrag*)(Bb_ + (wn*64 + j*16 + (l&15))*64 + ks*32 + (l>>4)*8); \
      _Pragma("unroll")                                                     \
      for(int i=0;i<4;i++)                                                  \
        _Pragma("unroll")                                                   \
        for(int j=0;j<4;j++)                                                \
          acc[i][j] = MFMA(a_[i], b_[j], acc[i][j]);                        \
    }                                                                       \
  }while(0)

  C2STG(0);
  asm volatile("s_waitcnt vmcnt(0)" ::: "memory");
  __builtin_amdgcn_s_barrier();
  for(int stp=0; stp<23; stp++){
    C2STG((stp+1)&1);
    asm volatile("s_waitcnt vmcnt(8)" ::: "memory");
    __builtin_amdgcn_sched_barrier(0);
    __builtin_amdgcn_s_barrier();
    C2CMP(stp&1);
    __builtin_amdgcn_sched_barrier(0);
    __builtin_amdgcn_s_barrier();
  }
  asm volatile("s_waitcnt vmcnt(0)" ::: "memory");
  __builtin_amdgcn_s_barrier();
  C2CMP(1);

  #undef C2STG
  #undef C2CMP

  uint16_t* out = PS + (size_t)dy*3211264;
  #pragma unroll
  for(int i=0;i<4;i++)
    #pragma unroll
    for(int j=0;j<4;j++){
      int n = n0 + wn*64 + j*16 + (l&15);
      #pragma unroll
      for(int r=0;r<4;r++){
        int mr = m0 + wm*64 + i*16 + (l>>4)*4 + r;
        out[(size_t)mr*512 + n] = f2b(acc[i][j][r]);
      }
    }
}

// ---------------- sum conv2 dy-partials (bf16) -> Y2 bf16 + BN2 stats ----------------
__global__ void k_bn2sum(const uint16_t* __restrict__ PS, uint16_t* __restrict__ Y2,
                         float* __restrict__ stats)
{
  int t = threadIdx.x;            // channel pair 2t, 2t+1
  int m0 = blockIdx.x*16;         // grid 392
  float s0=0,s1=0,q0=0,q1=0;
  for(int i=0;i<16;i++){
    size_t off = (size_t)(m0+i)*512 + 2*t;
    uint32_t u0 = *(const uint32_t*)(PS + off);
    uint32_t u1 = *(const uint32_t*)(PS + 3211264 + off);
    uint32_t u2 = *(const uint32_t*)(PS + 6422528 + off);
    float a = b2f((uint16_t)u0)+b2f((uint16_t)u1)+b2f((uint16_t)u2);
    float c = b2f((uint16_t)(u0>>16))+b2f((uint16_t)(u1>>16))+b2f((uint16_t)(u2>>16));
    s0+=a; q0+=a*a; s1+=c; q1+=c*c;
    *(uint32_t*)(Y2 + off) = (uint32_t)f2b(a) | ((uint32_t)f2b(c)<<16);
  }
  atomicAdd(&stats[2*t],   s0);
  atomicAdd(&stats[2*t+1], s1);
  atomicAdd(&stats[512+2*t],   q0);
  atomicAdd(&stats[512+2*t+1], q1);
}

// ---------------- BN apply + ReLU in-place; conv2 variant extracts center into egoT/feat ----------------
template<int PAD>
__global__ void k_bnapply(uint16_t* __restrict__ Y, const float* __restrict__ stats,
                          const float* __restrict__ gg, const float* __restrict__ bb,
                          int M, float invM,
                          uint16_t* __restrict__ egoT, uint16_t* __restrict__ feat)
{
  int t = threadIdx.x;
  int m0 = blockIdx.x*8;
  float mu0 = stats[2*t]*invM,       mu1 = stats[2*t+1]*invM;
  float v0 = stats[512+2*t]*invM - mu0*mu0, v1 = stats[512+2*t+1]*invM - mu1*mu1;
  float sc0 = gg[2*t]  *rsqrtf(v0+1e-5f), sc1 = gg[2*t+1]*rsqrtf(v1+1e-5f);
  float sh0 = bb[2*t]   - mu0*sc0,        sh1 = bb[2*t+1] - mu1*sc1;
  for(int i=0;i<8;i++){
    int m = m0+i; if(m>=M) break;
    size_t off;
    if(PAD){ int b=m/196, s=m%196, y=s/14, x=s%14; off = (((size_t)b*16+y+1)*16 + x+1)*512; }
    else off = (size_t)m*512;
    uint32_t u = *(const uint32_t*)(Y + off + 2*t);
    float a = fmaxf(b2f((uint16_t)u)*sc0 + sh0, 0.f);
    float c = fmaxf(b2f((uint16_t)(u>>16))*sc1 + sh1, 0.f);
    uint32_t pu = (uint32_t)f2b(a) | ((uint32_t)f2b(c)<<16);
    *(uint32_t*)(Y + off + 2*t) = pu;
    if(!PAD && (m%49)==24){
      int b = m/49;
      *(uint32_t*)(egoT + (size_t)b*576 + 2*t) = pu;
      *(uint32_t*)(feat + (size_t)b*1088 + 512 + 2*t) = pu;
    }
  }
}

// ---------------- small-M GEMM (M=128), no LDS ----------------
// flags: 1 = relu, 2 = f32 output (else bf16)
__global__ __launch_bounds__(256) void k_sgemm(
    const uint16_t* __restrict__ A, int lda,
    const uint16_t* __restrict__ B, int ldb,
    const float* __restrict__ bias,
    void* __restrict__ C, int ldc,
    int N, int K, int flags)
{
  int t = threadIdx.x, w = t>>6, l = t&63;
  int nt = blockIdx.x*4 + w;
  int n  = nt*16 + (l&15);
  int m0 = blockIdx.y*16;
  bool nv = n < N;
  facc acc = facc{0.f,0.f,0.f,0.f};
  for(int k=0;k<K;k+=32){
    bfrag af = *(const bfrag*)(A + (size_t)(m0+(l&15))*lda + k + (l>>4)*8);
    bfrag bf_ = {0,0,0,0,0,0,0,0};
    if(nv) bf_ = *(const bfrag*)(B + (size_t)n*ldb + k + (l>>4)*8);
    acc = MFMA(af, bf_, acc);
  }
  if(nv){
    float bv = bias ? bias[n] : 0.f;
    #pragma unroll
    for(int r=0;r<4;r++){
      int m = m0 + (l>>4)*4 + r;
      float v = acc[r] + bv;
      if(flags & 1) v = fmaxf(v, 0.f);
      if(flags & 2) ((float*)C)[(size_t)m*ldc + n] = v;
      else ((uint16_t*)C)[(size_t)m*ldc + n] = f2b(v);
    }
  }
}

// ---------------- fused tail: blockIdx.x<4 -> dec1 (relu,bf16), ==4 -> cls (f32) ----------------
__global__ __launch_bounds__(256) void k_tail1(
    const uint16_t* __restrict__ FEAT,
    const uint16_t* __restrict__ D1W, const float* __restrict__ d1B,
    const uint16_t* __restrict__ CLSW, const float* __restrict__ clsB,
    uint16_t* __restrict__ D1out, float* __restrict__ confOut)
{
  int t = threadIdx.x, w = t>>6, l = t&63;
  int m0 = blockIdx.y*16;
  bool isCls = (blockIdx.x == 4);
  int n = (isCls ? w : (blockIdx.x*4 + w))*16 + (l&15);
  int N = isCls ? 25 : 256;
  const uint16_t* B = isCls ? CLSW : D1W;
  bool nv = n < N;
  facc acc = facc{0.f,0.f,0.f,0.f};
  for(int k=0;k<1088;k+=32){
    bfrag af = *(const bfrag*)(FEAT + (size_t)(m0+(l&15))*1088 + k + (l>>4)*8);
    bfrag bf_ = {0,0,0,0,0,0,0,0};
    if(nv) bf_ = *(const bfrag*)(B + (size_t)n*1088 + k + (l>>4)*8);
    acc = MFMA(af, bf_, acc);
  }
  if(nv){
    #pragma unroll
    for(int r=0;r<4;r++){
      int m = m0 + (l>>4)*4 + r;
      if(isCls){
        confOut[(size_t)m*25 + n] = acc[r] + clsB[n];
      } else {
        D1out[(size_t)m*256 + n] = f2b(fmaxf(acc[r] + d1B[n], 0.f));
      }
    }
  }
}

// ---------------- batched per-head GEMM ----------------
__global__ __launch_bounds__(256) void k_bgemm(
    const uint16_t* __restrict__ A, int lda, int aoffs,
    const uint16_t* __restrict__ B, int ldb, int brows,
    uint16_t* __restrict__ C, int ldc, int coffs,
    int K)
{
  int t = threadIdx.x, w = t>>6, l = t&63;
  int z = blockIdx.z;
  int n = (blockIdx.x*4 + w)*16 + (l&15);
  int m0 = blockIdx.y*16;
  const uint16_t* Ab = A + (size_t)z*aoffs;
  const uint16_t* Bb = B + (size_t)z*brows*ldb;
  facc acc = facc{0.f,0.f,0.f,0.f};
  for(int k=0;k<K;k+=32){
    bfrag af = *(const bfrag*)(Ab + (size_t)(m0+(l&15))*lda + k + (l>>4)*8);
    bfrag bf_ = *(const bfrag*)(Bb + (size_t)n*ldb + k + (l>>4)*8);
    acc = MFMA(af, bf_, acc);
  }
  #pragma unroll
  for(int r=0;r<4;r++){
    int m = m0 + (l>>4)*4 + r;
    C[(size_t)m*ldc + z*coffs + n] = f2b(acc[r]);
  }
}

// ---------------- attention core: energy = U.y2, softmax (analytic ring), z = sum p*y2 ----------------
__global__ __launch_bounds__(512) void k_attn2(
    const uint16_t* __restrict__ U16, const uint16_t* __restrict__ y2,
    uint16_t* __restrict__ zout)
{
  __shared__ __align__(16) char LA[49*1024 + 8*1024];
  uint16_t* uls = (uint16_t*)(LA + 49*1024);
  int t = threadIdx.x, w = t>>6, l = t&63;
  int b = blockIdx.x >> 1, half = blockIdx.x & 1;
  int h = half*8 + w;

  for(int i=t; i<3136; i+=512){
    int g = i>>6, c16 = i&63;
    *(uint4*)(LA + g*1024 + ((c16*16) ^ ((g&31)<<4))) =
        *(const uint4*)(y2 + ((size_t)(b*49+g)*512 + c16*8));
  }
  *(uint4*)((char*)uls + w*1024 + l*16) =
      *(const uint4*)(U16 + (size_t)b*8192 + h*512 + l*8);
  __syncthreads();

  float dot = 0.f;
  if(l < 49){
    const char* yrow = LA + l*1024;
    const char* ur = (const char*)uls + w*1024;
    for(int c16=0;c16<64;c16++){
      uint4 uv = *(const uint4*)(ur + c16*16);
      uint4 yv = *(const uint4*)(yrow + ((c16*16) ^ ((l&31)<<4)));
      const uint16_t* up = (const uint16_t*)&uv;
      const uint16_t* yp = (const uint16_t*)&yv;
      #pragma unroll
      for(int j=0;j<8;j++) dot += b2f(up[j])*b2f(yp[j]);
    }
  }
  float e = (l<49) ? dot*(1.f/32.f) : -1e30f;
  float mx = e;
  for(int s=32;s>0;s>>=1) mx = fmaxf(mx, __shfl_xor(mx, s));
  mx = fmaxf(mx, 0.f);                      // 32 ring slots have energy 0
  float p = (l<49) ? __expf(e-mx) : 0.f;
  float den = p;
  for(int s=32;s>0;s>>=1) den += __shfl_xor(den, s);
  den += 32.f*__expf(-mx);

  float z[8];
  #pragma unroll
  for(int j=0;j<8;j++) z[j]=0.f;
  for(int g=0; g<49; g++){
    float pg = __shfl(p, g);
    uint4 yv = *(const uint4*)(LA + g*1024 + ((l*16) ^ ((g&31)<<4)));
    const uint16_t* yp = (const uint16_t*)&yv;
    #pragma unroll
    for(int j=0;j<8;j++) z[j] += pg*b2f(yp[j]);
  }
  float inv = 1.f/den;
  uint16_t zr[8];
  #pragma unroll
  for(int j=0;j<8;j++) zr[j] = f2b(z[j]*inv);
  *(uint4*)(zout + ((size_t)(b*16+h)*512) + l*8) = *(uint4*)zr;
}

// ---------------- trajectory: d2[b][25][16] @ tmat -> out [b][25][19][2] ----------------
__global__ void k_traj(const float* __restrict__ d2, const float* __restrict__ tm,
                       float* __restrict__ out)
{
  int i = blockIdx.x*256 + threadIdx.x;
  if(i >= 3200) return;
  const float* dp = d2 + (size_t)i*16;
  float cx[8], cy[8];
  #pragma unroll
  for(int j=0;j<8;j++){ cx[j]=dp[j]; cy[j]=dp[8+j]; }
  float* op = out + (size_t)i*38;
  for(int tt=0;tt<19;tt++){
    float x=0.f, y=0.f;
    #pragma unroll
    for(int j=0;j<8;j++){ float tv = tm[j*19+tt]; x += cx[j]*tv; y += cy[j]*tv; }
    op[tt*2+0]=x; op[tt*2+1]=y;
  }
}

// ======================= host =======================
extern "C" void kernel_launch(void* const* d_in, const int* in_sizes, int n_in,
                              void* d_out, int out_size, void* d_ws, size_t ws_size,
                              hipStream_t stream)
{
  const float* cnn      = (const float*)d_in[0];
  const float* ego_seq  = (const float*)d_in[1];
  const float* ag_seq   = (const float*)d_in[2];
  const int*   ego_len  = (const int*)d_in[3];
  const int*   ag_len   = (const int*)d_in[4];
  const int*   grid_pos = (const int*)d_in[5];
  const float* sW  = (const float*)d_in[6];
  const float* sb  = (const float*)d_in[7];
  const float* Wih = (const float*)d_in[8];
  const float* Whh = (const float*)d_in[9];
  const float* bih = (const float*)d_in[10];
  const float* bhh = (const float*)d_in[11];
  const float* encW = (const float*)d_in[12];
  const float* encB = (const float*)d_in[13];
  const float* conv1W = (const float*)d_in[14];
  const float* bn1g = (const float*)d_in[15];
  const float* bn1b = (const float*)d_in[16];
  const float* conv2W = (const float*)d_in[17];
  const float* bn2g = (const float*)d_in[18];
  const float* bn2b = (const float*)d_in[19];
  const float* qWf  = (const float*)d_in[20];
  const float* kWf  = (const float*)d_in[21];
  const float* vWf  = (const float*)d_in[22];
  const float* aoW  = (const float*)d_in[23];
  const float* aoB  = (const float*)d_in[24];
  const float* clsWf = (const float*)d_in[25];
  const float* clsB  = (const float*)d_in[26];
  const float* d1Wf  = (const float*)d_in[27];
  const float* d1B   = (const float*)d_in[28];
  const float* d2Wf  = (const float*)d_in[29];
  const float* d2B   = (const float*)d_in[30];

  char* ws = (char*)d_ws;
  const size_t XP_OFF   = 0;                 // 71 MB (dead after conv1)
  const size_t PS_OFF   = 0;                 // 19.3 MB bf16 partials (alias)
  const size_t U_OFF    = 0;                 // 2 MB (alias; after PS dead)
  const size_t ZB_OFF   = 2097152;           // 2 MB
  const size_t Y2_OFF   = 41943040;          // 6.4 MB
  const size_t Y1P_OFF  = 71303168;          // 33.5 MB
  const size_t WP1_OFF  = 104857600;
  const size_t WP2_OFF  = 114884608;
  const size_t WKT_OFF  = 119603200;         // 1 MB
  const size_t WVB_OFF  = 120651776;         // 1 MB
  const size_t QW_OFF   = 121700352;
  const size_t AOW_OFF  = 122880000;
  const size_t CLSW_OFF = 123928576;
  const size_t D1W_OFF  = 123982976;
  const size_t D2W_OFF  = 124540032;
  const size_t GRID_OFF = 124744832;
  const size_t EGOT_OFF = 131167360;
  const size_t FEAT_OFF = 131314816;
  const size_t QB_OFF   = 131593344;
  const size_t OBUF_OFF = 132117632;
  const size_t D1_OFF   = 132379776;
  const size_t D2_OFF   = 132445312;
  const size_t WC_OFF   = 132650112;
  const size_t BE_OFF   = 132699264;
  const size_t ENCW_OFF = 132700288;
  const size_t TMAT_OFF = 132708480;
  const size_t ST1_OFF  = 132709120;
  const size_t ST2_OFF  = 132713216;

  uint16_t* XP   = (uint16_t*)(ws + XP_OFF);
  uint16_t* PSB  = (uint16_t*)(ws + PS_OFF);
  uint16_t* U16  = (uint16_t*)(ws + U_OFF);
  uint16_t* ZB16 = (uint16_t*)(ws + ZB_OFF);
  uint16_t* Y2   = (uint16_t*)(ws + Y2_OFF);
  uint16_t* Y1P  = (uint16_t*)(ws + Y1P_OFF);
  uint16_t* WP1  = (uint16_t*)(ws + WP1_OFF);
  uint16_t* WP2  = (uint16_t*)(ws + WP2_OFF);
  uint16_t* WKT  = (uint16_t*)(ws + WKT_OFF);
  uint16_t* WVB  = (uint16_t*)(ws + WVB_OFF);
  uint16_t* QW   = (uint16_t*)(ws + QW_OFF);
  uint16_t* AOW  = (uint16_t*)(ws + AOW_OFF);
  uint16_t* CLSW = (uint16_t*)(ws + CLSW_OFF);
  uint16_t* D1W  = (uint16_t*)(ws + D1W_OFF);
  uint16_t* D2W  = (uint16_t*)(ws + D2W_OFF);
  float*    GRIDB= (float*)(ws + GRID_OFF);
  uint16_t* EGOT = (uint16_t*)(ws + EGOT_OFF);
  uint16_t* FEAT = (uint16_t*)(ws + FEAT_OFF);
  uint16_t* QB16 = (uint16_t*)(ws + QB_OFF);
  uint16_t* OBUF = (uint16_t*)(ws + OBUF_OFF);
  uint16_t* D1B  = (uint16_t*)(ws + D1_OFF);
  float*    D2B  = (float*)(ws + D2_OFF);
  uint16_t* WC   = (uint16_t*)(ws + WC_OFF);
  float*    BE   = (float*)(ws + BE_OFF);
  uint16_t* ENCWB= (uint16_t*)(ws + ENCW_OFF);
  float*    TMAT = (float*)(ws + TMAT_OFF);
  float*    ST1  = (float*)(ws + ST1_OFF);
  float*    ST2  = (float*)(ws + ST2_OFF);
  float*    outF = (float*)d_out;

  // border zeros + GRIDB + BN-stats zero (one launch, no memsets)
  k_zborder<<<256,256,0,stream>>>(XP, Y1P, GRIDB, ST1);

  // constants / weight packs
  k_lstm_prep<<<1,256,0,stream>>>(Wih,Whh,bih,bhh,sW,sb,encW, WC,BE,ENCWB, TMAT);
  k_packw<<<dim3(512,17),64,0,stream>>>(conv1W, WP1, 512, 1088);
  k_packw2<<<dim3(512,8),64,0,stream>>>(conv2W, WP2);
  k_packwk<<<dim3(16,16),256,0,stream>>>(kWf, WKT);
  {
    F2BJobs jb;
    jb.s[0]=vWf;  jb.d[0]=WVB;   jb.n[0]=1024*512;
    jb.s[1]=qWf;  jb.d[1]=QW;    jb.n[1]=1024*576;
    jb.s[2]=aoW;  jb.d[2]=AOW;   jb.n[2]=512*1024;
    jb.s[3]=clsWf;jb.d[3]=CLSW;  jb.n[3]=25*1088;
    jb.s[4]=d1Wf; jb.d[4]=D1W;   jb.n[4]=256*1088;
    jb.s[5]=d2Wf; jb.d[5]=D2W;   jb.n[5]=400*256;
    k_f2b_multi<<<dim3(48,6),256,0,stream>>>(jb);
  }

  // encoders + scatter
  k_lstm<<<132,256,0,stream>>>(ego_seq, ag_seq, ego_len, ag_len, grid_pos,
                               WC, BE, ENCWB, encB, GRIDB, EGOT, FEAT);
  // conv input pack
  k_packx<<<dim3(128,34),256,0,stream>>>(cnn, GRIDB, XP);
  // conv1 (8-phase 256², +stats) -> BN1 -> relu (in place, padded)
  k_conv1_8p<<<196,512,0,stream>>>(XP, WP1, Y1P, ST1);
  k_bnapply<1><<<3136,256,0,stream>>>(Y1P, ST1, bn1g, bn1b, 25088, 1.f/25088.f, nullptr, nullptr);
  // conv2: dy-split bf16 partials (2-phase dbuf) -> sum+stats -> BN2 apply
  k_conv2dy<<<dim3(196,3),256,0,stream>>>(Y1P, WP2, PSB);
  k_bn2sum<<<392,256,0,stream>>>(PSB, Y2, ST2);
  k_bnapply<0><<<784,256,0,stream>>>(Y2, ST2, bn2g, bn2b, 6272, 1.f/6272.f, EGOT, FEAT);
  // q = egoT @ qW^T (bf16)
  k_sgemm<<<dim3(16,8),256,0,stream>>>(EGOT, 576, QW, 576, nullptr, QB16, 1024, 1024, 576, 0);
  // U = q @ Wk (per head), attn core, o = z @ Wv^T (per head)
  k_bgemm<<<dim3(8,8,16),256,0,stream>>>(QB16, 1024, 64, WKT, 64, 512, U16, 8192, 512, 64);
  k_attn2<<<256,512,0,stream>>>(U16, Y2, ZB16);
  k_bgemm<<<dim3(1,8,16),256,0,stream>>>(ZB16, 8192, 512, WVB, 512, 64, OBUF, 1024, 64, 512);
  // attn_out -> feat[:,0:512]
  k_sgemm<<<dim3(8,8),256,0,stream>>>(OBUF, 1024, AOW, 1024, aoB, FEAT, 1088, 512, 1024, 0);
  // fused cls + dec1
  k_tail1<<<dim3(5,8),256,0,stream>>>(FEAT, D1W, d1B, CLSW, clsB, D1B, outF + 121600);
  // dec2 -> traj
  k_sgemm<<<dim3(7,8),256,0,stream>>>(D1B, 256, D2W, 256, d2B, D2B, 400, 400, 256, 2);
  k_traj<<<13,256,0,stream>>>(D2B, TMAT, outF);

  (void)in_sizes; (void)n_in; (void)out_size; (void)ws_size;
}

// Round 12
// 553.009 us; speedup vs baseline: 1.4735x; 1.0644x over previous
//
#include <hip/hip_runtime.h>
#include <stdint.h>
#include <stddef.h>

#define DEVINL static __device__ __forceinline__

typedef __attribute__((ext_vector_type(8))) short  bfrag;   // 8x bf16 (bits)
typedef __attribute__((ext_vector_type(4))) float  facc;    // MFMA accumulator

DEVINL uint16_t f2b(float f){
  uint32_t u = __float_as_uint(f);
  return (uint16_t)((u + 0x7fffu + ((u >> 16) & 1u)) >> 16);   // RNE
}
DEVINL float b2f(uint16_t b){ return __uint_as_float(((uint32_t)b) << 16); }

DEVINL facc MFMA(bfrag a, bfrag b, facc c){
  return __builtin_amdgcn_mfma_f32_16x16x32_bf16(a, b, c, 0, 0, 0);
}

// async global->LDS, 16B per lane; LDS dest = wave-uniform base + lane*16
DEVINL void gload16(const void* g, void* l){
  __builtin_amdgcn_global_load_lds(
      (const __attribute__((address_space(1))) uint32_t*)g,
      (__attribute__((address_space(3))) uint32_t*)l, 16, 0, 0);
}

DEVINL float fast_tanh(float x){           // tanh = 2*sigmoid(2x)-1
  return 2.f/(1.f+__expf(-2.f*x)) - 1.f;
}

// ================= mega-prep: ONE launch for all input-independent work =================
// blocks [0,4096)      : packx cnn channels (b = blk>>5, ch = blk&31)
// blocks [4096,4352)   : border zero XP/Y1P + GRIDB zero + (blk==4096) BN-stats zero
// block  4352          : lstm weight prep + Legendre tmat
// blocks [4353,4865)   : conv1 weight pack (o = blk-4353)
// blocks [4865,5377)   : conv2 weight pack (o = blk-4865)
// blocks [5377,5393)   : Wk transpose pack (h = blk-5377)
// blocks [5393,5644)   : f2b weight conversions (6 jobs, 8192 elems/block)
struct PrepArgs {
  const float* cnn;        uint16_t* Xp;
  uint16_t* Y1P;           float* gridb;   float* stats;
  const float *Wih, *Whh, *bih, *bhh, *sW, *sb, *encW;
  uint16_t* Wc;  float* be;  uint16_t* encWb;  float* tm;
  const float* conv1W;     uint16_t* WP1;
  const float* conv2W;     uint16_t* WP2;
  const float* kWf;        uint16_t* WKT;
  const float* fs[6];      uint16_t* fd[6];   int fn[6];  int fb0[6];
};

__global__ __launch_bounds__(256) void k_prep(PrepArgs a){
  int blk = blockIdx.x, t = threadIdx.x;
  if(blk < 4096){
    // ---- packx: cnn NCHW f32 -> padded NHWC bf16 (paired u32 stores) ----
    __shared__ float tile[32*200];
    int b = blk>>5, ch = blk&31;
    int c0 = ch*32;
    for(int i=t;i<32*196;i+=256){
      int ci = i/196, s = i%196;
      tile[ci*200+s] = a.cnn[((size_t)b*1024 + c0+ci)*196 + s];
    }
    __syncthreads();
    for(int i=t;i<16*196;i+=256){
      int s = i>>4, c2 = i&15;
      int y = s/14, x = s%14;
      uint32_t pu = (uint32_t)f2b(tile[(2*c2)*200+s]) |
                    ((uint32_t)f2b(tile[(2*c2+1)*200+s])<<16);
      *(uint32_t*)(a.Xp + (((size_t)b*16 + y+1)*16 + x+1)*1088 + c0 + 2*c2) = pu;
    }
  } else if(blk < 4352){
    int idx = blk - 4096;
    int b = idx & 127;
    uint16_t* base = (idx < 128) ? a.Xp : a.Y1P;
    int C = (idx < 128) ? 1088 : 512;
    for(int p=0;p<60;p++){
      int y, x;
      if(p<16){ y=0; x=p; }
      else if(p<32){ y=15; x=p-16; }
      else { int q=p-32; y=1+(q>>1); x=(q&1)?15:0; }
      uint32_t* dst = (uint32_t*)(base + ((size_t)(b*16+y)*16 + x)*C);
      for(int i=t;i<C/2;i+=256) dst[i] = 0;
    }
    float* g = a.gridb + (size_t)idx*6272;
    for(int i=t;i<6272;i+=256) g[i] = 0.f;
    if(idx == 0){
      for(int i=t;i<2048;i+=256) a.stats[i] = 0.f;
    }
  } else if(blk == 4352){
    int n = t;
    if(n < 19){
      float tv = (float)(n - 6) / 12.0f;
      float Pm = 1.0f, Pc = tv;
      a.tm[0*19+n] = Pm * sqrtf(0.5f);
      a.tm[1*19+n] = Pc * sqrtf(1.5f);
      for(int q=1; q<7; q++){
        float Pn = ((float)(2*q+1)*tv*Pc - (float)q*Pm) / (float)(q+1);
        Pm = Pc; Pc = Pn;
        a.tm[(q+1)*19+n] = Pc * sqrtf((float)(2*(q+1)+1) * 0.5f);
      }
    }
    for(int k=0;k<64;k++) a.Wc[n*96+k] = f2b(a.Whh[n*64+k]);
    for(int k5=0;k5<5;k5++){
      float s = 0.f;
      for(int j=0;j<64;j++) s += a.Wih[n*64+j]*a.sW[j*5+k5];
      a.Wc[n*96+64+k5] = f2b(s);
    }
    for(int k=69;k<96;k++) a.Wc[n*96+k] = 0;
    float s = 0.f;
    for(int j=0;j<64;j++) s += a.Wih[n*64+j]*a.sb[j];
    a.be[n] = s + a.bih[n] + a.bhh[n];
    if(n < 64){
      for(int k=0;k<64;k++) a.encWb[n*64+k] = f2b(a.encW[n*64+k]);
    }
  } else if(blk < 4865){
    int o = blk - 4353;
    for(int c=t; c<1088; c+=256){
      const float* src = a.conv1W + ((size_t)o*1088 + c)*9;
      float v[9];
      #pragma unroll
      for(int d=0;d<9;d++) v[d] = src[d];
      #pragma unroll
      for(int d=0;d<9;d++)
        a.WP1[((size_t)d*512 + o)*1088 + c] = f2b(v[d]);
    }
  } else if(blk < 5377){
    int o = blk - 4865;
    for(int c=t; c<512; c+=256){
      const float* src = a.conv2W + ((size_t)o*512 + c)*9;
      float v[9];
      #pragma unroll
      for(int d=0;d<9;d++) v[d] = src[d];
      #pragma unroll
      for(int dy=0;dy<3;dy++)
        #pragma unroll
        for(int dx=0;dx<3;dx++)
          a.WP2[((size_t)(dy*512 + o))*1536 + dx*512 + c] = f2b(v[dy*3+dx]);
    }
  } else if(blk < 5393){
    int h = blk - 5377;
    for(int i=t; i<32768; i+=256){
      int c = i>>6, d = i&63;
      a.WKT[((size_t)h*512 + c)*64 + d] = f2b(a.kWf[((size_t)(h*64+d))*512 + c]);
    }
  } else {
    int fblk = blk - 5393;
    int j = 0;
    while(j < 5 && fblk >= a.fb0[j+1]) j++;
    int base = (fblk - a.fb0[j])*8192;
    const float* s = a.fs[j];
    uint16_t* d = a.fd[j];
    int n = a.fn[j];
    int hi = base + 8192; if(hi > n) hi = n;
    for(int i=base+t; i<hi; i+=256) d[i] = f2b(s[i]);
  }
}

// ---------------- pack grid channels (1024..1087) of Xp (depends on LSTM) ----------------
__global__ void k_packx_grid(const float* __restrict__ agrid, uint16_t* __restrict__ Xp)
{
  int b = blockIdx.x >> 1, half = blockIdx.x & 1;
  int j0 = half*32, t = threadIdx.x;
  for(int i=t;i<16*196;i+=256){
    int s = i>>4, j2 = i&15;
    int y = s/14, x = s%14;
    const float* gsrc = agrid + ((size_t)b*196 + s)*64 + j0 + 2*j2;
    uint32_t pu = (uint32_t)f2b(gsrc[0]) | ((uint32_t)f2b(gsrc[1])<<16);
    *(uint32_t*)(Xp + (((size_t)b*16 + y+1)*16 + x+1)*1088 + 1024 + j0 + 2*j2) = pu;
  }
}

// ---------------- LSTM: 32 sequences / block, MFMA gates ----------------
__global__ __launch_bounds__(256) void k_lstm(
    const float* __restrict__ ego_seq, const float* __restrict__ ag_seq,
    const int* __restrict__ ego_len, const int* __restrict__ ag_len,
    const int* __restrict__ grid_pos,
    const uint16_t* __restrict__ Wc, const float* __restrict__ be,
    const uint16_t* __restrict__ encWb, const float* __restrict__ encB,
    float* __restrict__ agrid, uint16_t* __restrict__ egoT, uint16_t* __restrict__ feat)
{
  __shared__ __align__(16) uint16_t A[32*96];   // [seq][k] : k<64 h, 64..68 x_t, 69..95 zero
  __shared__ float Xf[32*160];                  // raw seq f32 [32][32][5]
  __shared__ int   idxs[32];

  int t = threadIdx.x, w = t>>6, l = t&63;
  int blk = blockIdx.x;
  bool isEgo = blk < 4;
  int seq0 = isEgo ? blk*32 : (blk-4)*32;
  const float* seqp = (isEgo ? ego_seq : ag_seq) + (size_t)seq0*160;

  for(int i=t;i<32*160;i+=256) Xf[i] = seqp[i];
  if(t < 32){
    int L = isEgo ? ego_len[seq0+t] : ag_len[seq0+t];
    if(L < 1) L = 1;
    idxs[t] = L-1;
  }
  for(int i=t;i<32*96;i+=256) A[i] = 0;

  bfrag bf[4][3];
  float be4[4];
  for(int ct=0;ct<4;ct++){
    int n = (ct*4+w)*16 + (l&15);
    for(int ks=0;ks<3;ks++)
      bf[ct][ks] = *(const bfrag*)(Wc + n*96 + ks*32 + (l>>4)*8);
    be4[ct] = be[n];
  }
  float cst[8], hl[8];
  for(int i=0;i<8;i++){ cst[i]=0.f; hl[i]=0.f; }
  __syncthreads();
  int myidx[8];
  for(int rt=0;rt<2;rt++) for(int r=0;r<4;r++){
    int s = rt*16 + (l>>4)*4 + r;
    myidx[rt*4+r] = idxs[s];
  }

  for(int st=0; st<32; st++){
    if(t < 160){ int s=t/5, kk=t%5; A[s*96+64+kk] = f2b(Xf[s*160 + st*5 + kk]); }
    __syncthreads();
    facc acc[2][4];
    for(int rt=0;rt<2;rt++) for(int ct=0;ct<4;ct++) acc[rt][ct] = facc{0.f,0.f,0.f,0.f};
    #pragma unroll
    for(int ks=0;ks<3;ks++){
      bfrag aA[2];
      #pragma unroll
      for(int rt=0;rt<2;rt++)
        aA[rt] = *(const bfrag*)(A + (rt*16+(l&15))*96 + ks*32 + (l>>4)*8);
      #pragma unroll
      for(int rt=0;rt<2;rt++)
        #pragma unroll
        for(int ct=0;ct<4;ct++)
          acc[rt][ct] = MFMA(aA[rt], bf[ct][ks], acc[rt][ct]);
    }
    __syncthreads();   // all A reads done before h overwrite
    #pragma unroll
    for(int rt=0;rt<2;rt++) for(int r=0;r<4;r++){
      int cell = rt*4+r;
      int s = rt*16 + (l>>4)*4 + r;
      float gi = acc[rt][0][r] + be4[0];
      float gf = acc[rt][1][r] + be4[1];
      float gg = acc[rt][2][r] + be4[2];
      float go = acc[rt][3][r] + be4[3];
      float si = 1.f/(1.f+__expf(-gi));
      float sf = 1.f/(1.f+__expf(-gf));
      float so = 1.f/(1.f+__expf(-go));
      float tg = fast_tanh(gg);
      float c2 = sf*cst[cell] + si*tg;
      cst[cell] = c2;
      float hn = so*fast_tanh(c2);
      A[s*96 + w*16 + (l&15)] = f2b(hn);
      if(st == myidx[cell]) hl[cell] = hn;
    }
  }
  __syncthreads();
  for(int rt=0;rt<2;rt++) for(int r=0;r<4;r++){
    int s = rt*16 + (l>>4)*4 + r;
    A[s*96 + w*16 + (l&15)] = f2b(hl[rt*4+r]);
  }
  __syncthreads();
  bfrag eb[2];
  for(int ks=0;ks<2;ks++)
    eb[ks] = *(const bfrag*)(encWb + (w*16+(l&15))*64 + ks*32 + (l>>4)*8);
  facc ea[2]; ea[0] = facc{0.f,0.f,0.f,0.f}; ea[1] = facc{0.f,0.f,0.f,0.f};
  for(int ks=0;ks<2;ks++){
    for(int rt=0;rt<2;rt++){
      bfrag aA = *(const bfrag*)(A + (rt*16+(l&15))*96 + ks*32 + (l>>4)*8);
      ea[rt] = MFMA(aA, eb[ks], ea[rt]);
    }
  }
  int n = w*16 + (l&15);
  float bn_ = encB[n];
  for(int rt=0;rt<2;rt++) for(int r=0;r<4;r++){
    int s = rt*16 + (l>>4)*4 + r;
    float v = ea[rt][r] + bn_;
    int gs = seq0 + s;
    if(isEgo){
      egoT[(size_t)gs*576 + 512 + n] = f2b(v);
      feat[(size_t)gs*1088 + 1024 + n] = f2b(v);
    } else {
      int py = grid_pos[gs*2+0], px = grid_pos[gs*2+1];
      atomicAdd(&agrid[((size_t)(gs>>5)*196 + py*14 + px)*64 + n], v);
    }
  }
}

// ================= conv1: 256x256 8-phase pipelined implicit GEMM =================
// (frozen: 276us, MfmaUtil 39; dual persistent B regs; vmcnt ledger verified)
__global__ __launch_bounds__(512) void k_conv1_8p(
    const uint16_t* __restrict__ Ain, const uint16_t* __restrict__ Wb,
    uint16_t* __restrict__ Out, float* __restrict__ stats)
{
  constexpr int CB = 1088;
  constexpr int NSTEP = 153;          // 17 cc x 9 taps
  __shared__ __align__(16) char LDSb[131072];

  int t = threadIdx.x, w = t>>6, l = t&63;
  int wm = w>>2, wn = w&3;

  int xcd = blockIdx.x & 7, pos = blockIdx.x >> 3;
  int wgid = (xcd < 4 ? xcd*25 : 100 + (xcd-4)*24) + pos;
  int m0 = (wgid % 98) * 256;
  int n0 = (wgid / 98) * 256;

  const uint16_t* aP[2][2];
  const uint16_t* bP[2][2];
  #pragma unroll
  for(int P=0;P<2;P++)
    #pragma unroll
    for(int j=0;j<2;j++){
      int partrow = j*64 + (t>>3);
      int swz = ((t&7) ^ (partrow&7))*8;            // elements
      int gr = P*64 + partrow + ((partrow>=64)?64:0);
      int m = m0 + gr; int b = m/196, s = m%196, y = s/14, x = s%14;
      aP[P][j] = Ain + ((b*16+y)*16+x)*CB + swz;
      int nb = n0 + (partrow>>5)*64 + P*32 + (partrow&31);
      bP[P][j] = Wb + (size_t)nb*CB + swz;
    }

  facc acc[8][4];
  #pragma unroll
  for(int i=0;i<8;i++)
    #pragma unroll
    for(int j=0;j<4;j++) acc[i][j] = facc{0.f,0.f,0.f,0.f};

  bfrag aF[4][2], bF0[2][2], bF1[2][2];   // persistent operand fragments
  int dd = 0;

  #define STG(buf, PART) do{                                                   \
    if((PART)==0 || (PART)==3){ const int P_ = ((PART)==3);                    \
      _Pragma("unroll")                                                        \
      for(int j_=0;j_<2;j_++)                                                  \
        gload16(aP[P_][j_], LDSb + (buf)*65536 + P_*16384 + j_*8192 + w*1024); \
    } else { const int P_ = ((PART)==2);                                       \
      _Pragma("unroll")                                                        \
      for(int j_=0;j_<2;j_++)                                                  \
        gload16(bP[P_][j_], LDSb + (buf)*65536 + 32768 + P_*16384 + j_*8192 + w*1024); \
    }                                                                          \
  }while(0)

  #define ADVK() do{                                                          \
    if(dd==8){                                                                \
      _Pragma("unroll")                                                       \
      for(int P_=0;P_<2;P_++) for(int j_=0;j_<2;j_++){                        \
        aP[P_][j_] += 64 - 34*CB; bP[P_][j_] += 64 - 8*512*CB; }              \
      dd = 0;                                                                 \
    } else {                                                                  \
      int sA_ = (dd==2||dd==5) ? 14*CB : CB;                                  \
      _Pragma("unroll")                                                       \
      for(int P_=0;P_<2;P_++) for(int j_=0;j_<2;j_++){                        \
        aP[P_][j_] += sA_; bP[P_][j_] += 512*CB; }                            \
      dd++;                                                                   \
    }                                                                         \
  }while(0)

  #define VM4 asm volatile("s_waitcnt vmcnt(4)" ::: "memory")
  #define VM2 asm volatile("s_waitcnt vmcnt(2)" ::: "memory")
  #define VM0 asm volatile("s_waitcnt vmcnt(0)" ::: "memory")

  #define LDA(mh) do{                                                         \
    const uint16_t* Ab_ = (const uint16_t*)(LDSb + p*65536 + (mh)*16384);     \
    _Pragma("unroll")                                                         \
    for(int i_=0;i_<4;i_++)                                                   \
      _Pragma("unroll")                                                       \
      for(int ks_=0;ks_<2;ks_++)                                              \
        aF[i_][ks_] = *(const bfrag*)(Ab_ + (wm*64 + i_*16 + (l&15))*64       \
                        + ((ks_*32 + (l>>4)*8) ^ ((l&7)<<3)));                \
  }while(0)

  #define LDB(dst, nh) do{                                                   \
    const uint16_t* Bb_ = (const uint16_t*)(LDSb + p*65536 + 32768 + (nh)*16384); \
    _Pragma("unroll")                                                         \
    for(int j_=0;j_<2;j_++)                                                   \
      _Pragma("unroll")                                                       \
      for(int ks_=0;ks_<2;ks_++)                                              \
        dst[j_][ks_] = *(const bfrag*)(Bb_ + (wn*32 + j_*16 + (l&15))*64      \
                        + ((ks_*32 + (l>>4)*8) ^ ((l&7)<<3)));                \
  }while(0)

  #define MM(mh, nh, bsrc) do{                                               \
    __builtin_amdgcn_s_setprio(1);                                           \
    _Pragma("unroll")                                                        \
    for(int ks_=0;ks_<2;ks_++)                                               \
      _Pragma("unroll")                                                      \
      for(int i_=0;i_<4;i_++)                                                \
        _Pragma("unroll")                                                    \
        for(int j_=0;j_<2;j_++)                                              \
          acc[(mh)*4+i_][(nh)*2+j_] =                                        \
            MFMA(aF[i_][ks_], bsrc[j_][ks_], acc[(mh)*4+i_][(nh)*2+j_]);     \
    __builtin_amdgcn_s_setprio(0);                                           \
  }while(0)

  #define BARS do{ __builtin_amdgcn_sched_barrier(0); __builtin_amdgcn_s_barrier(); }while(0)
  #define EBAR __builtin_amdgcn_s_barrier()

  // prologue: stage K-tile 0 (A0,B0,B1,A1) into buf0
  STG(0,0); STG(0,1); STG(0,2); STG(0,3);
  ADVK();
  VM4;
  EBAR;

  for(int kt=0; kt<NSTEP-1; kt++){
    int p = kt&1;
    LDA(0); LDB(bF0,0); STG(p^1,0); BARS; MM(0,0,bF0); VM4; EBAR;
    LDB(bF1,1);         STG(p^1,1); BARS; MM(0,1,bF1); VM4; EBAR;
    LDA(1);             STG(p^1,2); BARS; MM(1,1,bF1);      EBAR;
                        STG(p^1,3); BARS; MM(1,0,bF0); VM4; EBAR;
    if(kt < NSTEP-2) ADVK();
  }
  { // peeled last K-tile (buf 0), no staging, drain
    int p = 0;
    LDA(0); LDB(bF0,0); BARS; MM(0,0,bF0); VM2; EBAR;
    LDB(bF1,1);         BARS; MM(0,1,bF1); VM0; EBAR;
    LDA(1);             BARS; MM(1,1,bF1);      EBAR;
                        BARS; MM(1,0,bF0);      EBAR;
  }

  #undef LDA
  #undef LDB
  #undef MM
  #undef BARS
  #undef EBAR
  #undef STG
  #undef ADVK

  __syncthreads();
  int* oo = (int*)LDSb;
  if(t < 256){
    int m = m0 + t; int b = m/196, s = m%196, y = s/14, x = s%14;
    oo[t] = ((b*16 + y+1)*16 + (x+1))*512;
  }
  __syncthreads();
  #pragma unroll
  for(int i=0;i<8;i++)
    #pragma unroll
    for(int j=0;j<4;j++){
      int n = n0 + wn*64 + j*16 + (l&15);
      #pragma unroll
      for(int r=0;r<4;r++){
        int mr = wm*128 + i*16 + (l>>4)*4 + r;
        Out[(size_t)oo[mr] + n] = f2b(acc[i][j][r]);
      }
    }
  __syncthreads();
  float* sred = (float*)LDSb;
  int rg = wm*4 + (l>>4);
  #pragma unroll
  for(int j=0;j<4;j++){
    float s=0.f, q=0.f;
    #pragma unroll
    for(int i=0;i<8;i++)
      #pragma unroll
      for(int r=0;r<4;r++){ float v = acc[i][j][r]; s += v; q += v*v; }
    int nl = wn*64 + j*16 + (l&15);
    sred[(nl*8 + rg)*2+0] = s;
    sred[(nl*8 + rg)*2+1] = q;
  }
  __syncthreads();
  if(t < 256){
    float s=0.f, q=0.f;
    #pragma unroll
    for(int rgi=0;rgi<8;rgi++){ s += sred[(t*8+rgi)*2]; q += sred[(t*8+rgi)*2+1]; }
    atomicAdd(&stats[n0+t], s);
    atomicAdd(&stats[512+n0+t], q);
  }
}

// ================= conv2: dy-split flat GEMM, 2-phase double-buffered =================
__global__ __launch_bounds__(256) void k_conv2dy(
    const uint16_t* __restrict__ Ain, const uint16_t* __restrict__ Wb,
    uint16_t* __restrict__ PS)
{
  __shared__ __align__(16) uint16_t As[2*128*64];
  __shared__ __align__(16) uint16_t Bs[2*128*64];

  int t = threadIdx.x, w = t>>6, l = t&63;
  int dy = blockIdx.y;

  int xcd = blockIdx.x & 7, pos = blockIdx.x >> 3;
  int wgid = (xcd < 4 ? xcd*25 : 100 + (xcd-4)*24) + pos;
  int n0 = (wgid / 49) * 128;
  int m0 = (wgid % 49) * 128;

  const uint16_t* aP[4];
  const uint16_t* bP[4];
  #pragma unroll
  for(int p=0;p<4;p++){
    int r = w*32 + p*8 + (l>>3);
    int m = m0 + r;
    int b = m/49, s = m%49, y = s/7, x = s%7;
    aP[p] = Ain + ((b*16 + 2*y + dy)*16 + 2*x)*512 + (l&7)*8;
    bP[p] = Wb + ((size_t)(dy*512 + n0 + r))*1536 + (l&7)*8;
  }

  facc acc[4][4];
  #pragma unroll
  for(int i=0;i<4;i++)
    #pragma unroll
    for(int j=0;j<4;j++) acc[i][j] = facc{0.f,0.f,0.f,0.f};
  int wm = w>>1, wn = w&1;

  #define C2STG(buf) do{                                                    \
    char* ad_ = (char*)As + (buf)*16384 + w*4096;                           \
    char* bd_ = (char*)Bs + (buf)*16384 + w*4096;                           \
    _Pragma("unroll")                                                       \
    for(int p=0;p<4;p++){ gload16(aP[p], ad_ + p*1024); aP[p] += 64; }      \
    _Pragma("unroll")                                                       \
    for(int p=0;p<4;p++){ gload16(bP[p], bd_ + p*1024); bP[p] += 64; }      \
  }while(0)

  #define C2CMP(buf) do{                                                    \
    const uint16_t* Ab_ = As + (buf)*8192;                                  \
    const uint16_t* Bb_ = Bs + (buf)*8192;                                  \
    _Pragma("unroll")                                                       \
    for(int ks=0;ks<2;ks++){                                                \
      bfrag a_[4], b_[4];                                                   \
      _Pragma("unroll")                                                     \
      for(int i=0;i<4;i++)                                                  \
        a_[i] = *(const bfrag*)(Ab_ + (wm*64 + i*16 + (l&15))*64 + ks*32 + (l>>4)*8); \
      _Pragma("unroll")                                                     \
      for(int j=0;j<4;j++)                                                  \
        b_[j] = *(const bfrag*)(Bb_ + (wn*64 + j*16 + (l&15))*64 + ks*32 + (l>>4)*8); \
      _Pragma("unroll")                                                     \
      for(int i=0;i<4;i++)                                                  \
        _Pragma("unroll")                                                   \
        for(int j=0;j<4;j++)                                                \
          acc[i][j] = MFMA(a_[i], b_[j], acc[i][j]);                        \
    }                                                                       \
  }while(0)

  C2STG(0);
  asm volatile("s_waitcnt vmcnt(0)" ::: "memory");
  __builtin_amdgcn_s_barrier();
  for(int stp=0; stp<23; stp++){
    C2STG((stp+1)&1);
    asm volatile("s_waitcnt vmcnt(8)" ::: "memory");
    __builtin_amdgcn_sched_barrier(0);
    __builtin_amdgcn_s_barrier();
    C2CMP(stp&1);
    __builtin_amdgcn_sched_barrier(0);
    __builtin_amdgcn_s_barrier();
  }
  asm volatile("s_waitcnt vmcnt(0)" ::: "memory");
  __builtin_amdgcn_s_barrier();
  C2CMP(1);

  #undef C2STG
  #undef C2CMP

  uint16_t* out = PS + (size_t)dy*3211264;
  #pragma unroll
  for(int i=0;i<4;i++)
    #pragma unroll
    for(int j=0;j<4;j++){
      int n = n0 + wn*64 + j*16 + (l&15);
      #pragma unroll
      for(int r=0;r<4;r++){
        int mr = m0 + wm*64 + i*16 + (l>>4)*4 + r;
        out[(size_t)mr*512 + n] = f2b(acc[i][j][r]);
      }
    }
}

// ---------------- sum conv2 dy-partials (bf16) -> Y2 bf16 + BN2 stats ----------------
__global__ void k_bn2sum(const uint16_t* __restrict__ PS, uint16_t* __restrict__ Y2,
                         float* __restrict__ stats)
{
  int t = threadIdx.x;            // channel pair 2t, 2t+1
  int m0 = blockIdx.x*16;         // grid 392
  float s0=0,s1=0,q0=0,q1=0;
  for(int i=0;i<16;i++){
    size_t off = (size_t)(m0+i)*512 + 2*t;
    uint32_t u0 = *(const uint32_t*)(PS + off);
    uint32_t u1 = *(const uint32_t*)(PS + 3211264 + off);
    uint32_t u2 = *(const uint32_t*)(PS + 6422528 + off);
    float a = b2f((uint16_t)u0)+b2f((uint16_t)u1)+b2f((uint16_t)u2);
    float c = b2f((uint16_t)(u0>>16))+b2f((uint16_t)(u1>>16))+b2f((uint16_t)(u2>>16));
    s0+=a; q0+=a*a; s1+=c; q1+=c*c;
    *(uint32_t*)(Y2 + off) = (uint32_t)f2b(a) | ((uint32_t)f2b(c)<<16);
  }
  atomicAdd(&stats[2*t],   s0);
  atomicAdd(&stats[2*t+1], s1);
  atomicAdd(&stats[512+2*t],   q0);
  atomicAdd(&stats[512+2*t+1], q1);
}

// ---------------- BN apply + ReLU in-place; conv2 variant extracts center into egoT/feat ----------------
template<int PAD>
__global__ void k_bnapply(uint16_t* __restrict__ Y, const float* __restrict__ stats,
                          const float* __restrict__ gg, const float* __restrict__ bb,
                          int M, float invM,
                          uint16_t* __restrict__ egoT, uint16_t* __restrict__ feat)
{
  int t = threadIdx.x;
  int m0 = blockIdx.x*8;
  float mu0 = stats[2*t]*invM,       mu1 = stats[2*t+1]*invM;
  float v0 = stats[512+2*t]*invM - mu0*mu0, v1 = stats[512+2*t+1]*invM - mu1*mu1;
  float sc0 = gg[2*t]  *rsqrtf(v0+1e-5f), sc1 = gg[2*t+1]*rsqrtf(v1+1e-5f);
  float sh0 = bb[2*t]   - mu0*sc0,        sh1 = bb[2*t+1] - mu1*sc1;
  for(int i=0;i<8;i++){
    int m = m0+i; if(m>=M) break;
    size_t off;
    if(PAD){ int b=m/196, s=m%196, y=s/14, x=s%14; off = (((size_t)b*16+y+1)*16 + x+1)*512; }
    else off = (size_t)m*512;
    uint32_t u = *(const uint32_t*)(Y + off + 2*t);
    float a = fmaxf(b2f((uint16_t)u)*sc0 + sh0, 0.f);
    float c = fmaxf(b2f((uint16_t)(u>>16))*sc1 + sh1, 0.f);
    uint32_t pu = (uint32_t)f2b(a) | ((uint32_t)f2b(c)<<16);
    *(uint32_t*)(Y + off + 2*t) = pu;
    if(!PAD && (m%49)==24){
      int b = m/49;
      *(uint32_t*)(egoT + (size_t)b*576 + 2*t) = pu;
      *(uint32_t*)(feat + (size_t)b*1088 + 512 + 2*t) = pu;
    }
  }
}

// ---------------- small-M GEMM (M=128), no LDS ----------------
// flags: 1 = relu, 2 = f32 output (else bf16)
__global__ __launch_bounds__(256) void k_sgemm(
    const uint16_t* __restrict__ A, int lda,
    const uint16_t* __restrict__ B, int ldb,
    const float* __restrict__ bias,
    void* __restrict__ C, int ldc,
    int N, int K, int flags)
{
  int t = threadIdx.x, w = t>>6, l = t&63;
  int nt = blockIdx.x*4 + w;
  int n  = nt*16 + (l&15);
  int m0 = blockIdx.y*16;
  bool nv = n < N;
  facc acc = facc{0.f,0.f,0.f,0.f};
  for(int k=0;k<K;k+=32){
    bfrag af = *(const bfrag*)(A + (size_t)(m0+(l&15))*lda + k + (l>>4)*8);
    bfrag bf_ = {0,0,0,0,0,0,0,0};
    if(nv) bf_ = *(const bfrag*)(B + (size_t)n*ldb + k + (l>>4)*8);
    acc = MFMA(af, bf_, acc);
  }
  if(nv){
    float bv = bias ? bias[n] : 0.f;
    #pragma unroll
    for(int r=0;r<4;r++){
      int m = m0 + (l>>4)*4 + r;
      float v = acc[r] + bv;
      if(flags & 1) v = fmaxf(v, 0.f);
      if(flags & 2) ((float*)C)[(size_t)m*ldc + n] = v;
      else ((uint16_t*)C)[(size_t)m*ldc + n] = f2b(v);
    }
  }
}

// ---------------- fused tail: blockIdx.x<4 -> dec1 (relu,bf16), ==4 -> cls (f32) ----------------
__global__ __launch_bounds__(256) void k_tail1(
    const uint16_t* __restrict__ FEAT,
    const uint16_t* __restrict__ D1W, const float* __restrict__ d1B,
    const uint16_t* __restrict__ CLSW, const float* __restrict__ clsB,
    uint16_t* __restrict__ D1out, float* __restrict__ confOut)
{
  int t = threadIdx.x, w = t>>6, l = t&63;
  int m0 = blockIdx.y*16;
  bool isCls = (blockIdx.x == 4);
  int n = (isCls ? w : (blockIdx.x*4 + w))*16 + (l&15);
  int N = isCls ? 25 : 256;
  const uint16_t* B = isCls ? CLSW : D1W;
  bool nv = n < N;
  facc acc = facc{0.f,0.f,0.f,0.f};
  for(int k=0;k<1088;k+=32){
    bfrag af = *(const bfrag*)(FEAT + (size_t)(m0+(l&15))*1088 + k + (l>>4)*8);
    bfrag bf_ = {0,0,0,0,0,0,0,0};
    if(nv) bf_ = *(const bfrag*)(B + (size_t)n*1088 + k + (l>>4)*8);
    acc = MFMA(af, bf_, acc);
  }
  if(nv){
    #pragma unroll
    for(int r=0;r<4;r++){
      int m = m0 + (l>>4)*4 + r;
      if(isCls){
        confOut[(size_t)m*25 + n] = acc[r] + clsB[n];
      } else {
        D1out[(size_t)m*256 + n] = f2b(fmaxf(acc[r] + d1B[n], 0.f));
      }
    }
  }
}

// ---------------- batched per-head GEMM ----------------
__global__ __launch_bounds__(256) void k_bgemm(
    const uint16_t* __restrict__ A, int lda, int aoffs,
    const uint16_t* __restrict__ B, int ldb, int brows,
    uint16_t* __restrict__ C, int ldc, int coffs,
    int K)
{
  int t = threadIdx.x, w = t>>6, l = t&63;
  int z = blockIdx.z;
  int n = (blockIdx.x*4 + w)*16 + (l&15);
  int m0 = blockIdx.y*16;
  const uint16_t* Ab = A + (size_t)z*aoffs;
  const uint16_t* Bb = B + (size_t)z*brows*ldb;
  facc acc = facc{0.f,0.f,0.f,0.f};
  for(int k=0;k<K;k+=32){
    bfrag af = *(const bfrag*)(Ab + (size_t)(m0+(l&15))*lda + k + (l>>4)*8);
    bfrag bf_ = *(const bfrag*)(Bb + (size_t)n*ldb + k + (l>>4)*8);
    acc = MFMA(af, bf_, acc);
  }
  #pragma unroll
  for(int r=0;r<4;r++){
    int m = m0 + (l>>4)*4 + r;
    C[(size_t)m*ldc + z*coffs + n] = f2b(acc[r]);
  }
}

// ---------------- attention core: energy = U.y2, softmax (analytic ring), z = sum p*y2 ----------------
__global__ __launch_bounds__(512) void k_attn2(
    const uint16_t* __restrict__ U16, const uint16_t* __restrict__ y2,
    uint16_t* __restrict__ zout)
{
  __shared__ __align__(16) char LA[49*1024 + 8*1024];
  uint16_t* uls = (uint16_t*)(LA + 49*1024);
  int t = threadIdx.x, w = t>>6, l = t&63;
  int b = blockIdx.x >> 1, half = blockIdx.x & 1;
  int h = half*8 + w;

  for(int i=t; i<3136; i+=512){
    int g = i>>6, c16 = i&63;
    *(uint4*)(LA + g*1024 + ((c16*16) ^ ((g&31)<<4))) =
        *(const uint4*)(y2 + ((size_t)(b*49+g)*512 + c16*8));
  }
  *(uint4*)((char*)uls + w*1024 + l*16) =
      *(const uint4*)(U16 + (size_t)b*8192 + h*512 + l*8);
  __syncthreads();

  float dot = 0.f;
  if(l < 49){
    const char* yrow = LA + l*1024;
    const char* ur = (const char*)uls + w*1024;
    for(int c16=0;c16<64;c16++){
      uint4 uv = *(const uint4*)(ur + c16*16);
      uint4 yv = *(const uint4*)(yrow + ((c16*16) ^ ((l&31)<<4)));
      const uint16_t* up = (const uint16_t*)&uv;
      const uint16_t* yp = (const uint16_t*)&yv;
      #pragma unroll
      for(int j=0;j<8;j++) dot += b2f(up[j])*b2f(yp[j]);
    }
  }
  float e = (l<49) ? dot*(1.f/32.f) : -1e30f;
  float mx = e;
  for(int s=32;s>0;s>>=1) mx = fmaxf(mx, __shfl_xor(mx, s));
  mx = fmaxf(mx, 0.f);                      // 32 ring slots have energy 0
  float p = (l<49) ? __expf(e-mx) : 0.f;
  float den = p;
  for(int s=32;s>0;s>>=1) den += __shfl_xor(den, s);
  den += 32.f*__expf(-mx);

  float z[8];
  #pragma unroll
  for(int j=0;j<8;j++) z[j]=0.f;
  for(int g=0; g<49; g++){
    float pg = __shfl(p, g);
    uint4 yv = *(const uint4*)(LA + g*1024 + ((l*16) ^ ((g&31)<<4)));
    const uint16_t* yp = (const uint16_t*)&yv;
    #pragma unroll
    for(int j=0;j<8;j++) z[j] += pg*b2f(yp[j]);
  }
  float inv = 1.f/den;
  uint16_t zr[8];
  #pragma unroll
  for(int j=0;j<8;j++) zr[j] = f2b(z[j]*inv);
  *(uint4*)(zout + ((size_t)(b*16+h)*512) + l*8) = *(uint4*)zr;
}

// ---------------- trajectory: d2[b][25][16] @ tmat -> out [b][25][19][2] ----------------
__global__ void k_traj(const float* __restrict__ d2, const float* __restrict__ tm,
                       float* __restrict__ out)
{
  int i = blockIdx.x*256 + threadIdx.x;
  if(i >= 3200) return;
  const float* dp = d2 + (size_t)i*16;
  float cx[8], cy[8];
  #pragma unroll
  for(int j=0;j<8;j++){ cx[j]=dp[j]; cy[j]=dp[8+j]; }
  float* op = out + (size_t)i*38;
  for(int tt=0;tt<19;tt++){
    float x=0.f, y=0.f;
    #pragma unroll
    for(int j=0;j<8;j++){ float tv = tm[j*19+tt]; x += cx[j]*tv; y += cy[j]*tv; }
    op[tt*2+0]=x; op[tt*2+1]=y;
  }
}

// ======================= host =======================
extern "C" void kernel_launch(void* const* d_in, const int* in_sizes, int n_in,
                              void* d_out, int out_size, void* d_ws, size_t ws_size,
                              hipStream_t stream)
{
  const float* cnn      = (const float*)d_in[0];
  const float* ego_seq  = (const float*)d_in[1];
  const float* ag_seq   = (const float*)d_in[2];
  const int*   ego_len  = (const int*)d_in[3];
  const int*   ag_len   = (const int*)d_in[4];
  const int*   grid_pos = (const int*)d_in[5];
  const float* sW  = (const float*)d_in[6];
  const float* sb  = (const float*)d_in[7];
  const float* Wih = (const float*)d_in[8];
  const float* Whh = (const float*)d_in[9];
  const float* bih = (const float*)d_in[10];
  const float* bhh = (const float*)d_in[11];
  const float* encW = (const float*)d_in[12];
  const float* encB = (const float*)d_in[13];
  const float* conv1W = (const float*)d_in[14];
  const float* bn1g = (const float*)d_in[15];
  const float* bn1b = (const float*)d_in[16];
  const float* conv2W = (const float*)d_in[17];
  const float* bn2g = (const float*)d_in[18];
  const float* bn2b = (const float*)d_in[19];
  const float* qWf  = (const float*)d_in[20];
  const float* kWf  = (const float*)d_in[21];
  const float* vWf  = (const float*)d_in[22];
  const float* aoW  = (const float*)d_in[23];
  const float* aoB  = (const float*)d_in[24];
  const float* clsWf = (const float*)d_in[25];
  const float* clsB  = (const float*)d_in[26];
  const float* d1Wf  = (const float*)d_in[27];
  const float* d1B   = (const float*)d_in[28];
  const float* d2Wf  = (const float*)d_in[29];
  const float* d2B   = (const float*)d_in[30];

  char* ws = (char*)d_ws;
  const size_t XP_OFF   = 0;                 // 71 MB (dead after conv1)
  const size_t PS_OFF   = 0;                 // 19.3 MB bf16 partials (alias)
  const size_t U_OFF    = 0;                 // 2 MB (alias; after PS dead)
  const size_t ZB_OFF   = 2097152;           // 2 MB
  const size_t Y2_OFF   = 41943040;          // 6.4 MB
  const size_t Y1P_OFF  = 71303168;          // 33.5 MB
  const size_t WP1_OFF  = 104857600;
  const size_t WP2_OFF  = 114884608;
  const size_t WKT_OFF  = 119603200;         // 1 MB
  const size_t WVB_OFF  = 120651776;         // 1 MB
  const size_t QW_OFF   = 121700352;
  const size_t AOW_OFF  = 122880000;
  const size_t CLSW_OFF = 123928576;
  const size_t D1W_OFF  = 123982976;
  const size_t D2W_OFF  = 124540032;
  const size_t GRID_OFF = 124744832;
  const size_t EGOT_OFF = 131167360;
  const size_t FEAT_OFF = 131314816;
  const size_t QB_OFF   = 131593344;
  const size_t OBUF_OFF = 132117632;
  const size_t D1_OFF   = 132379776;
  const size_t D2_OFF   = 132445312;
  const size_t WC_OFF   = 132650112;
  const size_t BE_OFF   = 132699264;
  const size_t ENCW_OFF = 132700288;
  const size_t TMAT_OFF = 132708480;
  const size_t ST1_OFF  = 132709120;
  const size_t ST2_OFF  = 132713216;

  uint16_t* XP   = (uint16_t*)(ws + XP_OFF);
  uint16_t* PSB  = (uint16_t*)(ws + PS_OFF);
  uint16_t* U16  = (uint16_t*)(ws + U_OFF);
  uint16_t* ZB16 = (uint16_t*)(ws + ZB_OFF);
  uint16_t* Y2   = (uint16_t*)(ws + Y2_OFF);
  uint16_t* Y1P  = (uint16_t*)(ws + Y1P_OFF);
  uint16_t* WP1  = (uint16_t*)(ws + WP1_OFF);
  uint16_t* WP2  = (uint16_t*)(ws + WP2_OFF);
  uint16_t* WKT  = (uint16_t*)(ws + WKT_OFF);
  uint16_t* WVB  = (uint16_t*)(ws + WVB_OFF);
  uint16_t* QW   = (uint16_t*)(ws + QW_OFF);
  uint16_t* AOW  = (uint16_t*)(ws + AOW_OFF);
  uint16_t* CLSW = (uint16_t*)(ws + CLSW_OFF);
  uint16_t* D1W  = (uint16_t*)(ws + D1W_OFF);
  uint16_t* D2W  = (uint16_t*)(ws + D2W_OFF);
  float*    GRIDB= (float*)(ws + GRID_OFF);
  uint16_t* EGOT = (uint16_t*)(ws + EGOT_OFF);
  uint16_t* FEAT = (uint16_t*)(ws + FEAT_OFF);
  uint16_t* QB16 = (uint16_t*)(ws + QB_OFF);
  uint16_t* OBUF = (uint16_t*)(ws + OBUF_OFF);
  uint16_t* D1B  = (uint16_t*)(ws + D1_OFF);
  float*    D2B  = (float*)(ws + D2_OFF);
  uint16_t* WC   = (uint16_t*)(ws + WC_OFF);
  float*    BE   = (float*)(ws + BE_OFF);
  uint16_t* ENCWB= (uint16_t*)(ws + ENCW_OFF);
  float*    TMAT = (float*)(ws + TMAT_OFF);
  float*    ST1  = (float*)(ws + ST1_OFF);
  float*    ST2  = (float*)(ws + ST2_OFF);
  float*    outF = (float*)d_out;

  // ---- mega-prep: all input-independent work in ONE launch ----
  {
    PrepArgs a;
    a.cnn = cnn; a.Xp = XP; a.Y1P = Y1P; a.gridb = GRIDB; a.stats = ST1;
    a.Wih=Wih; a.Whh=Whh; a.bih=bih; a.bhh=bhh; a.sW=sW; a.sb=sb; a.encW=encW;
    a.Wc=WC; a.be=BE; a.encWb=ENCWB; a.tm=TMAT;
    a.conv1W=conv1W; a.WP1=WP1;
    a.conv2W=conv2W; a.WP2=WP2;
    a.kWf=kWf; a.WKT=WKT;
    a.fs[0]=vWf;  a.fd[0]=WVB;   a.fn[0]=1024*512;
    a.fs[1]=qWf;  a.fd[1]=QW;    a.fn[1]=1024*576;
    a.fs[2]=aoW;  a.fd[2]=AOW;   a.fn[2]=512*1024;
    a.fs[3]=clsWf;a.fd[3]=CLSW;  a.fn[3]=25*1088;
    a.fs[4]=d1Wf; a.fd[4]=D1W;   a.fn[4]=256*1088;
    a.fs[5]=d2Wf; a.fd[5]=D2W;   a.fn[5]=400*256;
    int nb = 0;
    for(int j=0;j<6;j++){ a.fb0[j] = nb; nb += (a.fn[j] + 8191)/8192; }
    k_prep<<<5393 + nb, 256, 0, stream>>>(a);
  }

  // encoders + scatter (needs WC/BE/ENCWB + zeroed GRIDB)
  k_lstm<<<132,256,0,stream>>>(ego_seq, ag_seq, ego_len, ag_len, grid_pos,
                               WC, BE, ENCWB, encB, GRIDB, EGOT, FEAT);
  // grid channels of Xp (needs GRIDB)
  k_packx_grid<<<256,256,0,stream>>>(GRIDB, XP);
  // conv1 (8-phase 256², +stats) -> BN1 -> relu (in place, padded)
  k_conv1_8p<<<196,512,0,stream>>>(XP, WP1, Y1P, ST1);
  k_bnapply<1><<<3136,256,0,stream>>>(Y1P, ST1, bn1g, bn1b, 25088, 1.f/25088.f, nullptr, nullptr);
  // conv2: dy-split bf16 partials (2-phase dbuf) -> sum+stats -> BN2 apply
  k_conv2dy<<<dim3(196,3),256,0,stream>>>(Y1P, WP2, PSB);
  k_bn2sum<<<392,256,0,stream>>>(PSB, Y2, ST2);
  k_bnapply<0><<<784,256,0,stream>>>(Y2, ST2, bn2g, bn2b, 6272, 1.f/6272.f, EGOT, FEAT);
  // q = egoT @ qW^T (bf16)
  k_sgemm<<<dim3(16,8),256,0,stream>>>(EGOT, 576, QW, 576, nullptr, QB16, 1024, 1024, 576, 0);
  // U = q @ Wk (per head), attn core, o = z @ Wv^T (per head)
  k_bgemm<<<dim3(8,8,16),256,0,stream>>>(QB16, 1024, 64, WKT, 64, 512, U16, 8192, 512, 64);
  k_attn2<<<256,512,0,stream>>>(U16, Y2, ZB16);
  k_bgemm<<<dim3(1,8,16),256,0,stream>>>(ZB16, 8192, 512, WVB, 512, 64, OBUF, 1024, 64, 512);
  // attn_out -> feat[:,0:512]
  k_sgemm<<<dim3(8,8),256,0,stream>>>(OBUF, 1024, AOW, 1024, aoB, FEAT, 1088, 512, 1024, 0);
  // fused cls + dec1
  k_tail1<<<dim3(5,8),256,0,stream>>>(FEAT, D1W, d1B, CLSW, clsB, D1B, outF + 121600);
  // dec2 -> traj
  k_sgemm<<<dim3(7,8),256,0,stream>>>(D1B, 256, D2W, 256, d2B, D2B, 400, 400, 256, 2);
  k_traj<<<13,256,0,stream>>>(D2B, TMAT, outF);

  (void)in_sizes; (void)n_in; (void)out_size; (void)ws_size;
}

// Round 13
// 551.093 us; speedup vs baseline: 1.4787x; 1.0035x over previous
//
#include <hip/hip_runtime.h>
#include <stdint.h>
#include <stddef.h>

#define DEVINL static __device__ __forceinline__

typedef __attribute__((ext_vector_type(8))) short  bfrag;   // 8x bf16 (bits)
typedef __attribute__((ext_vector_type(4))) float  facc;    // MFMA accumulator

DEVINL uint16_t f2b(float f){
  uint32_t u = __float_as_uint(f);
  return (uint16_t)((u + 0x7fffu + ((u >> 16) & 1u)) >> 16);   // RNE
}
DEVINL float b2f(uint16_t b){ return __uint_as_float(((uint32_t)b) << 16); }

DEVINL facc MFMA(bfrag a, bfrag b, facc c){
  return __builtin_amdgcn_mfma_f32_16x16x32_bf16(a, b, c, 0, 0, 0);
}

// async global->LDS, 16B per lane; LDS dest = wave-uniform base + lane*16
DEVINL void gload16(const void* g, void* l){
  __builtin_amdgcn_global_load_lds(
      (const __attribute__((address_space(1))) uint32_t*)g,
      (__attribute__((address_space(3))) uint32_t*)l, 16, 0, 0);
}

DEVINL float fast_tanh(float x){           // tanh = 2*sigmoid(2x)-1
  return 2.f/(1.f+__expf(-2.f*x)) - 1.f;
}

// ================= mega-prep: ONE launch for all input-independent work =================
struct PrepArgs {
  const float* cnn;        uint16_t* Xp;
  uint16_t* Y1P;           float* gridb;   float* stats;
  const float *Wih, *Whh, *bih, *bhh, *sW, *sb, *encW;
  uint16_t* Wc;  float* be;  uint16_t* encWb;  float* tm;
  const float* conv1W;     uint16_t* WP1;
  const float* conv2W;     uint16_t* WP2;
  const float* kWf;        uint16_t* WKT;
  const float* fs[6];      uint16_t* fd[6];   int fn[6];  int fb0[6];
};

__global__ __launch_bounds__(256) void k_prep(PrepArgs a){
  int blk = blockIdx.x, t = threadIdx.x;
  if(blk < 4096){
    __shared__ float tile[32*200];
    int b = blk>>5, ch = blk&31;
    int c0 = ch*32;
    for(int i=t;i<32*196;i+=256){
      int ci = i/196, s = i%196;
      tile[ci*200+s] = a.cnn[((size_t)b*1024 + c0+ci)*196 + s];
    }
    __syncthreads();
    for(int i=t;i<16*196;i+=256){
      int s = i>>4, c2 = i&15;
      int y = s/14, x = s%14;
      uint32_t pu = (uint32_t)f2b(tile[(2*c2)*200+s]) |
                    ((uint32_t)f2b(tile[(2*c2+1)*200+s])<<16);
      *(uint32_t*)(a.Xp + (((size_t)b*16 + y+1)*16 + x+1)*1088 + c0 + 2*c2) = pu;
    }
  } else if(blk < 4352){
    int idx = blk - 4096;
    int b = idx & 127;
    uint16_t* base = (idx < 128) ? a.Xp : a.Y1P;
    int C = (idx < 128) ? 1088 : 512;
    for(int p=0;p<60;p++){
      int y, x;
      if(p<16){ y=0; x=p; }
      else if(p<32){ y=15; x=p-16; }
      else { int q=p-32; y=1+(q>>1); x=(q&1)?15:0; }
      uint32_t* dst = (uint32_t*)(base + ((size_t)(b*16+y)*16 + x)*C);
      for(int i=t;i<C/2;i+=256) dst[i] = 0;
    }
    float* g = a.gridb + (size_t)idx*6272;
    for(int i=t;i<6272;i+=256) g[i] = 0.f;
    if(idx == 0){
      for(int i=t;i<2048;i+=256) a.stats[i] = 0.f;
    }
  } else if(blk == 4352){
    int n = t;
    if(n < 19){
      float tv = (float)(n - 6) / 12.0f;
      float Pm = 1.0f, Pc = tv;
      a.tm[0*19+n] = Pm * sqrtf(0.5f);
      a.tm[1*19+n] = Pc * sqrtf(1.5f);
      for(int q=1; q<7; q++){
        float Pn = ((float)(2*q+1)*tv*Pc - (float)q*Pm) / (float)(q+1);
        Pm = Pc; Pc = Pn;
        a.tm[(q+1)*19+n] = Pc * sqrtf((float)(2*(q+1)+1) * 0.5f);
      }
    }
    for(int k=0;k<64;k++) a.Wc[n*96+k] = f2b(a.Whh[n*64+k]);
    for(int k5=0;k5<5;k5++){
      float s = 0.f;
      for(int j=0;j<64;j++) s += a.Wih[n*64+j]*a.sW[j*5+k5];
      a.Wc[n*96+64+k5] = f2b(s);
    }
    for(int k=69;k<96;k++) a.Wc[n*96+k] = 0;
    float s = 0.f;
    for(int j=0;j<64;j++) s += a.Wih[n*64+j]*a.sb[j];
    a.be[n] = s + a.bih[n] + a.bhh[n];
    if(n < 64){
      for(int k=0;k<64;k++) a.encWb[n*64+k] = f2b(a.encW[n*64+k]);
    }
  } else if(blk < 4865){
    int o = blk - 4353;
    for(int c=t; c<1088; c+=256){
      const float* src = a.conv1W + ((size_t)o*1088 + c)*9;
      float v[9];
      #pragma unroll
      for(int d=0;d<9;d++) v[d] = src[d];
      #pragma unroll
      for(int d=0;d<9;d++)
        a.WP1[((size_t)d*512 + o)*1088 + c] = f2b(v[d]);
    }
  } else if(blk < 5377){
    int o = blk - 4865;
    for(int c=t; c<512; c+=256){
      const float* src = a.conv2W + ((size_t)o*512 + c)*9;
      float v[9];
      #pragma unroll
      for(int d=0;d<9;d++) v[d] = src[d];
      #pragma unroll
      for(int dy=0;dy<3;dy++)
        #pragma unroll
        for(int dx=0;dx<3;dx++)
          a.WP2[((size_t)(dy*512 + o))*1536 + dx*512 + c] = f2b(v[dy*3+dx]);
    }
  } else if(blk < 5393){
    int h = blk - 5377;
    for(int i=t; i<32768; i+=256){
      int c = i>>6, d = i&63;
      a.WKT[((size_t)h*512 + c)*64 + d] = f2b(a.kWf[((size_t)(h*64+d))*512 + c]);
    }
  } else {
    int fblk = blk - 5393;
    int j = 0;
    while(j < 5 && fblk >= a.fb0[j+1]) j++;
    int base = (fblk - a.fb0[j])*8192;
    const float* s = a.fs[j];
    uint16_t* d = a.fd[j];
    int n = a.fn[j];
    int hi = base + 8192; if(hi > n) hi = n;
    for(int i=base+t; i<hi; i+=256) d[i] = f2b(s[i]);
  }
}

// ---------------- pack grid channels (1024..1087) of Xp (depends on LSTM) ----------------
__global__ void k_packx_grid(const float* __restrict__ agrid, uint16_t* __restrict__ Xp)
{
  int b = blockIdx.x >> 1, half = blockIdx.x & 1;
  int j0 = half*32, t = threadIdx.x;
  for(int i=t;i<16*196;i+=256){
    int s = i>>4, j2 = i&15;
    int y = s/14, x = s%14;
    const float* gsrc = agrid + ((size_t)b*196 + s)*64 + j0 + 2*j2;
    uint32_t pu = (uint32_t)f2b(gsrc[0]) | ((uint32_t)f2b(gsrc[1])<<16);
    *(uint32_t*)(Xp + (((size_t)b*16 + y+1)*16 + x+1)*1088 + 1024 + j0 + 2*j2) = pu;
  }
}

// ---------------- LSTM: 32 sequences / block, MFMA gates ----------------
__global__ __launch_bounds__(256) void k_lstm(
    const float* __restrict__ ego_seq, const float* __restrict__ ag_seq,
    const int* __restrict__ ego_len, const int* __restrict__ ag_len,
    const int* __restrict__ grid_pos,
    const uint16_t* __restrict__ Wc, const float* __restrict__ be,
    const uint16_t* __restrict__ encWb, const float* __restrict__ encB,
    float* __restrict__ agrid, uint16_t* __restrict__ egoT, uint16_t* __restrict__ feat)
{
  __shared__ __align__(16) uint16_t A[32*96];
  __shared__ float Xf[32*160];
  __shared__ int   idxs[32];

  int t = threadIdx.x, w = t>>6, l = t&63;
  int blk = blockIdx.x;
  bool isEgo = blk < 4;
  int seq0 = isEgo ? blk*32 : (blk-4)*32;
  const float* seqp = (isEgo ? ego_seq : ag_seq) + (size_t)seq0*160;

  for(int i=t;i<32*160;i+=256) Xf[i] = seqp[i];
  if(t < 32){
    int L = isEgo ? ego_len[seq0+t] : ag_len[seq0+t];
    if(L < 1) L = 1;
    idxs[t] = L-1;
  }
  for(int i=t;i<32*96;i+=256) A[i] = 0;

  bfrag bf[4][3];
  float be4[4];
  for(int ct=0;ct<4;ct++){
    int n = (ct*4+w)*16 + (l&15);
    for(int ks=0;ks<3;ks++)
      bf[ct][ks] = *(const bfrag*)(Wc + n*96 + ks*32 + (l>>4)*8);
    be4[ct] = be[n];
  }
  float cst[8], hl[8];
  for(int i=0;i<8;i++){ cst[i]=0.f; hl[i]=0.f; }
  __syncthreads();
  int myidx[8];
  for(int rt=0;rt<2;rt++) for(int r=0;r<4;r++){
    int s = rt*16 + (l>>4)*4 + r;
    myidx[rt*4+r] = idxs[s];
  }

  for(int st=0; st<32; st++){
    if(t < 160){ int s=t/5, kk=t%5; A[s*96+64+kk] = f2b(Xf[s*160 + st*5 + kk]); }
    __syncthreads();
    facc acc[2][4];
    for(int rt=0;rt<2;rt++) for(int ct=0;ct<4;ct++) acc[rt][ct] = facc{0.f,0.f,0.f,0.f};
    #pragma unroll
    for(int ks=0;ks<3;ks++){
      bfrag aA[2];
      #pragma unroll
      for(int rt=0;rt<2;rt++)
        aA[rt] = *(const bfrag*)(A + (rt*16+(l&15))*96 + ks*32 + (l>>4)*8);
      #pragma unroll
      for(int rt=0;rt<2;rt++)
        #pragma unroll
        for(int ct=0;ct<4;ct++)
          acc[rt][ct] = MFMA(aA[rt], bf[ct][ks], acc[rt][ct]);
    }
    __syncthreads();
    #pragma unroll
    for(int rt=0;rt<2;rt++) for(int r=0;r<4;r++){
      int cell = rt*4+r;
      int s = rt*16 + (l>>4)*4 + r;
      float gi = acc[rt][0][r] + be4[0];
      float gf = acc[rt][1][r] + be4[1];
      float gg = acc[rt][2][r] + be4[2];
      float go = acc[rt][3][r] + be4[3];
      float si = 1.f/(1.f+__expf(-gi));
      float sf = 1.f/(1.f+__expf(-gf));
      float so = 1.f/(1.f+__expf(-go));
      float tg = fast_tanh(gg);
      float c2 = sf*cst[cell] + si*tg;
      cst[cell] = c2;
      float hn = so*fast_tanh(c2);
      A[s*96 + w*16 + (l&15)] = f2b(hn);
      if(st == myidx[cell]) hl[cell] = hn;
    }
  }
  __syncthreads();
  for(int rt=0;rt<2;rt++) for(int r=0;r<4;r++){
    int s = rt*16 + (l>>4)*4 + r;
    A[s*96 + w*16 + (l&15)] = f2b(hl[rt*4+r]);
  }
  __syncthreads();
  bfrag eb[2];
  for(int ks=0;ks<2;ks++)
    eb[ks] = *(const bfrag*)(encWb + (w*16+(l&15))*64 + ks*32 + (l>>4)*8);
  facc ea[2]; ea[0] = facc{0.f,0.f,0.f,0.f}; ea[1] = facc{0.f,0.f,0.f,0.f};
  for(int ks=0;ks<2;ks++){
    for(int rt=0;rt<2;rt++){
      bfrag aA = *(const bfrag*)(A + (rt*16+(l&15))*96 + ks*32 + (l>>4)*8);
      ea[rt] = MFMA(aA, eb[ks], ea[rt]);
    }
  }
  int n = w*16 + (l&15);
  float bn_ = encB[n];
  for(int rt=0;rt<2;rt++) for(int r=0;r<4;r++){
    int s = rt*16 + (l>>4)*4 + r;
    float v = ea[rt][r] + bn_;
    int gs = seq0 + s;
    if(isEgo){
      egoT[(size_t)gs*576 + 512 + n] = f2b(v);
      feat[(size_t)gs*1088 + 1024 + n] = f2b(v);
    } else {
      int py = grid_pos[gs*2+0], px = grid_pos[gs*2+1];
      atomicAdd(&agrid[((size_t)(gs>>5)*196 + py*14 + px)*64 + n], v);
    }
  }
}

// ================= conv1: 256x256 8-phase pipelined implicit GEMM =================
// (frozen: 273us, MfmaUtil 39.5; dual persistent B regs; vmcnt ledger verified)
__global__ __launch_bounds__(512) void k_conv1_8p(
    const uint16_t* __restrict__ Ain, const uint16_t* __restrict__ Wb,
    uint16_t* __restrict__ Out, float* __restrict__ stats)
{
  constexpr int CB = 1088;
  constexpr int NSTEP = 153;
  __shared__ __align__(16) char LDSb[131072];

  int t = threadIdx.x, w = t>>6, l = t&63;
  int wm = w>>2, wn = w&3;

  int xcd = blockIdx.x & 7, pos = blockIdx.x >> 3;
  int wgid = (xcd < 4 ? xcd*25 : 100 + (xcd-4)*24) + pos;
  int m0 = (wgid % 98) * 256;
  int n0 = (wgid / 98) * 256;

  const uint16_t* aP[2][2];
  const uint16_t* bP[2][2];
  #pragma unroll
  for(int P=0;P<2;P++)
    #pragma unroll
    for(int j=0;j<2;j++){
      int partrow = j*64 + (t>>3);
      int swz = ((t&7) ^ (partrow&7))*8;
      int gr = P*64 + partrow + ((partrow>=64)?64:0);
      int m = m0 + gr; int b = m/196, s = m%196, y = s/14, x = s%14;
      aP[P][j] = Ain + ((b*16+y)*16+x)*CB + swz;
      int nb = n0 + (partrow>>5)*64 + P*32 + (partrow&31);
      bP[P][j] = Wb + (size_t)nb*CB + swz;
    }

  facc acc[8][4];
  #pragma unroll
  for(int i=0;i<8;i++)
    #pragma unroll
    for(int j=0;j<4;j++) acc[i][j] = facc{0.f,0.f,0.f,0.f};

  bfrag aF[4][2], bF0[2][2], bF1[2][2];
  int dd = 0;

  #define STG(buf, PART) do{                                                   \
    if((PART)==0 || (PART)==3){ const int P_ = ((PART)==3);                    \
      _Pragma("unroll")                                                        \
      for(int j_=0;j_<2;j_++)                                                  \
        gload16(aP[P_][j_], LDSb + (buf)*65536 + P_*16384 + j_*8192 + w*1024); \
    } else { const int P_ = ((PART)==2);                                       \
      _Pragma("unroll")                                                        \
      for(int j_=0;j_<2;j_++)                                                  \
        gload16(bP[P_][j_], LDSb + (buf)*65536 + 32768 + P_*16384 + j_*8192 + w*1024); \
    }                                                                          \
  }while(0)

  #define ADVK() do{                                                          \
    if(dd==8){                                                                \
      _Pragma("unroll")                                                       \
      for(int P_=0;P_<2;P_++) for(int j_=0;j_<2;j_++){                        \
        aP[P_][j_] += 64 - 34*CB; bP[P_][j_] += 64 - 8*512*CB; }              \
      dd = 0;                                                                 \
    } else {                                                                  \
      int sA_ = (dd==2||dd==5) ? 14*CB : CB;                                  \
      _Pragma("unroll")                                                       \
      for(int P_=0;P_<2;P_++) for(int j_=0;j_<2;j_++){                        \
        aP[P_][j_] += sA_; bP[P_][j_] += 512*CB; }                            \
      dd++;                                                                   \
    }                                                                         \
  }while(0)

  #define VM4 asm volatile("s_waitcnt vmcnt(4)" ::: "memory")
  #define VM2 asm volatile("s_waitcnt vmcnt(2)" ::: "memory")
  #define VM0 asm volatile("s_waitcnt vmcnt(0)" ::: "memory")

  #define LDA(mh) do{                                                         \
    const uint16_t* Ab_ = (const uint16_t*)(LDSb + p*65536 + (mh)*16384);     \
    _Pragma("unroll")                                                         \
    for(int i_=0;i_<4;i_++)                                                   \
      _Pragma("unroll")                                                       \
      for(int ks_=0;ks_<2;ks_++)                                              \
        aF[i_][ks_] = *(const bfrag*)(Ab_ + (wm*64 + i_*16 + (l&15))*64       \
                        + ((ks_*32 + (l>>4)*8) ^ ((l&7)<<3)));                \
  }while(0)

  #define LDB(dst, nh) do{                                                   \
    const uint16_t* Bb_ = (const uint16_t*)(LDSb + p*65536 + 32768 + (nh)*16384); \
    _Pragma("unroll")                                                         \
    for(int j_=0;j_<2;j_++)                                                   \
      _Pragma("unroll")                                                       \
      for(int ks_=0;ks_<2;ks_++)                                              \
        dst[j_][ks_] = *(const bfrag*)(Bb_ + (wn*32 + j_*16 + (l&15))*64      \
                        + ((ks_*32 + (l>>4)*8) ^ ((l&7)<<3)));                \
  }while(0)

  #define MM(mh, nh, bsrc) do{                                               \
    __builtin_amdgcn_s_setprio(1);                                           \
    _Pragma("unroll")                                                        \
    for(int ks_=0;ks_<2;ks_++)                                               \
      _Pragma("unroll")                                                      \
      for(int i_=0;i_<4;i_++)                                                \
        _Pragma("unroll")                                                    \
        for(int j_=0;j_<2;j_++)                                              \
          acc[(mh)*4+i_][(nh)*2+j_] =                                        \
            MFMA(aF[i_][ks_], bsrc[j_][ks_], acc[(mh)*4+i_][(nh)*2+j_]);     \
    __builtin_amdgcn_s_setprio(0);                                           \
  }while(0)

  #define BARS do{ __builtin_amdgcn_sched_barrier(0); __builtin_amdgcn_s_barrier(); }while(0)
  #define EBAR __builtin_amdgcn_s_barrier()

  STG(0,0); STG(0,1); STG(0,2); STG(0,3);
  ADVK();
  VM4;
  EBAR;

  for(int kt=0; kt<NSTEP-1; kt++){
    int p = kt&1;
    LDA(0); LDB(bF0,0); STG(p^1,0); BARS; MM(0,0,bF0); VM4; EBAR;
    LDB(bF1,1);         STG(p^1,1); BARS; MM(0,1,bF1); VM4; EBAR;
    LDA(1);             STG(p^1,2); BARS; MM(1,1,bF1);      EBAR;
                        STG(p^1,3); BARS; MM(1,0,bF0); VM4; EBAR;
    if(kt < NSTEP-2) ADVK();
  }
  {
    int p = 0;
    LDA(0); LDB(bF0,0); BARS; MM(0,0,bF0); VM2; EBAR;
    LDB(bF1,1);         BARS; MM(0,1,bF1); VM0; EBAR;
    LDA(1);             BARS; MM(1,1,bF1);      EBAR;
                        BARS; MM(1,0,bF0);      EBAR;
  }

  #undef LDA
  #undef LDB
  #undef MM
  #undef BARS
  #undef EBAR
  #undef STG
  #undef ADVK

  __syncthreads();
  int* oo = (int*)LDSb;
  if(t < 256){
    int m = m0 + t; int b = m/196, s = m%196, y = s/14, x = s%14;
    oo[t] = ((b*16 + y+1)*16 + (x+1))*512;
  }
  __syncthreads();
  #pragma unroll
  for(int i=0;i<8;i++)
    #pragma unroll
    for(int j=0;j<4;j++){
      int n = n0 + wn*64 + j*16 + (l&15);
      #pragma unroll
      for(int r=0;r<4;r++){
        int mr = wm*128 + i*16 + (l>>4)*4 + r;
        Out[(size_t)oo[mr] + n] = f2b(acc[i][j][r]);
      }
    }
  __syncthreads();
  float* sred = (float*)LDSb;
  int rg = wm*4 + (l>>4);
  #pragma unroll
  for(int j=0;j<4;j++){
    float s=0.f, q=0.f;
    #pragma unroll
    for(int i=0;i<8;i++)
      #pragma unroll
      for(int r=0;r<4;r++){ float v = acc[i][j][r]; s += v; q += v*v; }
    int nl = wn*64 + j*16 + (l&15);
    sred[(nl*8 + rg)*2+0] = s;
    sred[(nl*8 + rg)*2+1] = q;
  }
  __syncthreads();
  if(t < 256){
    float s=0.f, q=0.f;
    #pragma unroll
    for(int rgi=0;rgi<8;rgi++){ s += sred[(t*8+rgi)*2]; q += sred[(t*8+rgi)*2+1]; }
    atomicAdd(&stats[n0+t], s);
    atomicAdd(&stats[512+n0+t], q);
  }
}

// ================= conv2: dy-split flat GEMM, BN1+ReLU folded into A-load =================
// A path: reg-stage (global->reg during compute, f32 BN1 transform, f2b, ds_write).
// Rounding chain f2b(relu(sc*b2f(y1)+sh)) is BIT-IDENTICAL to the old bnapply<1> pass.
// B path: gload16 direct (unchanged). One __syncthreads per K-step (dbuf).
__global__ __launch_bounds__(256) void k_conv2dy(
    const uint16_t* __restrict__ Ain, const uint16_t* __restrict__ Wb,
    uint16_t* __restrict__ PS,
    const float* __restrict__ stats, const float* __restrict__ gg,
    const float* __restrict__ bb)
{
  __shared__ __align__(16) uint16_t As[2*128*64];
  __shared__ __align__(16) uint16_t Bs[2*128*64];
  __shared__ float scs[512], shs[512];

  int t = threadIdx.x, w = t>>6, l = t&63;
  int dy = blockIdx.y;

  for(int c=t;c<512;c+=256){
    float mu = stats[c]*(1.f/25088.f);
    float var = stats[512+c]*(1.f/25088.f) - mu*mu;
    float sc = gg[c]*rsqrtf(var+1e-5f);
    scs[c] = sc; shs[c] = bb[c] - mu*sc;
  }

  int xcd = blockIdx.x & 7, pos = blockIdx.x >> 3;
  int wgid = (xcd < 4 ? xcd*25 : 100 + (xcd-4)*24) + pos;
  int n0 = (wgid / 49) * 128;
  int m0 = (wgid % 49) * 128;

  const uint16_t* aP[4];
  const uint16_t* bP[4];
  #pragma unroll
  for(int p=0;p<4;p++){
    int r = w*32 + p*8 + (l>>3);
    int m = m0 + r;
    int b = m/49, s = m%49, y = s/7, x = s%7;
    aP[p] = Ain + ((b*16 + 2*y + dy)*16 + 2*x)*512 + (l&7)*8;
    bP[p] = Wb + ((size_t)(dy*512 + n0 + r))*1536 + (l&7)*8;
  }

  facc acc[4][4];
  #pragma unroll
  for(int i=0;i<4;i++)
    #pragma unroll
    for(int j=0;j<4;j++) acc[i][j] = facc{0.f,0.f,0.f,0.f};
  int wm = w>>1, wn = w&1;

  uint4 av[4];

  #define C2LOADA() do{                                                     \
    _Pragma("unroll")                                                       \
    for(int p=0;p<4;p++){ av[p] = *(const uint4*)aP[p]; aP[p] += 64; }      \
  }while(0)

  #define C2BSTG(buf) do{                                                  \
    char* bd_ = (char*)Bs + (buf)*16384 + w*4096;                          \
    _Pragma("unroll")                                                      \
    for(int p=0;p<4;p++){ gload16(bP[p], bd_ + p*1024); bP[p] += 64; }     \
  }while(0)

  #define C2AWRITE(buf, kt) do{                                            \
    int c0_ = (((kt)*64) & 511) + (l&7)*8;                                  \
    _Pragma("unroll")                                                      \
    for(int p=0;p<4;p++){                                                  \
      const uint16_t* vv = (const uint16_t*)&av[p];                        \
      uint16_t ov[8];                                                      \
      _Pragma("unroll")                                                    \
      for(int j=0;j<8;j++){                                                \
        int c_ = c0_ + j;                                                  \
        ov[j] = f2b(fmaxf(b2f(vv[j])*scs[c_] + shs[c_], 0.f));             \
      }                                                                    \
      *(uint4*)((char*)As + (buf)*16384 + w*4096 + p*1024 + l*16) = *(uint4*)ov; \
    }                                                                      \
  }while(0)

  #define C2CMP(buf) do{                                                    \
    const uint16_t* Ab_ = As + (buf)*8192;                                  \
    const uint16_t* Bb_ = Bs + (buf)*8192;                                  \
    _Pragma("unroll")                                                       \
    for(int ks=0;ks<2;ks++){                                                \
      bfrag a_[4], b_[4];                                                   \
      _Pragma("unroll")                                                     \
      for(int i=0;i<4;i++)                                                  \
        a_[i] = *(const bfrag*)(Ab_ + (wm*64 + i*16 + (l&15))*64 + ks*32 + (l>>4)*8); \
      _Pragma("unroll")                                                     \
      for(int j=0;j<4;j++)                                                  \
        b_[j] = *(const bfrag*)(Bb_ + (wn*64 + j*16 + (l&15))*64 + ks*32 + (l>>4)*8); \
      _Pragma("unroll")                                                     \
      for(int i=0;i<4;i++)                                                  \
        _Pragma("unroll")                                                   \
        for(int j=0;j<4;j++)                                                \
          acc[i][j] = MFMA(a_[i], b_[j], acc[i][j]);                        \
    }                                                                       \
  }while(0)

  // prologue: tile 0
  C2LOADA();
  C2BSTG(0);
  C2AWRITE(0, 0);
  __syncthreads();
  for(int stp=0; stp<24; stp++){
    if(stp < 23){ C2LOADA(); C2BSTG((stp+1)&1); }
    C2CMP(stp&1);
    if(stp < 23) C2AWRITE((stp+1)&1, stp+1);
    __syncthreads();
  }

  #undef C2LOADA
  #undef C2BSTG
  #undef C2AWRITE
  #undef C2CMP

  uint16_t* out = PS + (size_t)dy*3211264;
  #pragma unroll
  for(int i=0;i<4;i++)
    #pragma unroll
    for(int j=0;j<4;j++){
      int n = n0 + wn*64 + j*16 + (l&15);
      #pragma unroll
      for(int r=0;r<4;r++){
        int mr = m0 + wm*64 + i*16 + (l>>4)*4 + r;
        out[(size_t)mr*512 + n] = f2b(acc[i][j][r]);
      }
    }
}

// ---------------- sum conv2 dy-partials (bf16) -> Y2 bf16 (pre-BN) + BN2 stats ----------------
__global__ void k_bn2sum(const uint16_t* __restrict__ PS, uint16_t* __restrict__ Y2,
                         float* __restrict__ stats)
{
  int t = threadIdx.x;
  int m0 = blockIdx.x*16;         // grid 392
  float s0=0,s1=0,q0=0,q1=0;
  for(int i=0;i<16;i++){
    size_t off = (size_t)(m0+i)*512 + 2*t;
    uint32_t u0 = *(const uint32_t*)(PS + off);
    uint32_t u1 = *(const uint32_t*)(PS + 3211264 + off);
    uint32_t u2 = *(const uint32_t*)(PS + 6422528 + off);
    float a = b2f((uint16_t)u0)+b2f((uint16_t)u1)+b2f((uint16_t)u2);
    float c = b2f((uint16_t)(u0>>16))+b2f((uint16_t)(u1>>16))+b2f((uint16_t)(u2>>16));
    s0+=a; q0+=a*a; s1+=c; q1+=c*c;
    *(uint32_t*)(Y2 + off) = (uint32_t)f2b(a) | ((uint32_t)f2b(c)<<16);
  }
  atomicAdd(&stats[2*t],   s0);
  atomicAdd(&stats[2*t+1], s1);
  atomicAdd(&stats[512+2*t],   q0);
  atomicAdd(&stats[512+2*t+1], q1);
}

// ---------------- center pixel: BN2+ReLU of Y2[b][24][:] -> egoT, FEAT ----------------
__global__ void k_center(const uint16_t* __restrict__ Y2, const float* __restrict__ stats,
                         const float* __restrict__ gg, const float* __restrict__ bb,
                         uint16_t* __restrict__ egoT, uint16_t* __restrict__ feat)
{
  int b = blockIdx.x, t = threadIdx.x;
  int c = 2*t;
  float mu0 = stats[c]*(1.f/6272.f),     mu1 = stats[c+1]*(1.f/6272.f);
  float v0 = stats[512+c]*(1.f/6272.f) - mu0*mu0;
  float v1 = stats[512+c+1]*(1.f/6272.f) - mu1*mu1;
  float sc0 = gg[c]*rsqrtf(v0+1e-5f),    sc1 = gg[c+1]*rsqrtf(v1+1e-5f);
  float sh0 = bb[c] - mu0*sc0,           sh1 = bb[c+1] - mu1*sc1;
  size_t off = (size_t)(b*49+24)*512 + c;
  uint32_t u = *(const uint32_t*)(Y2 + off);
  float a = fmaxf(b2f((uint16_t)u)*sc0 + sh0, 0.f);
  float d = fmaxf(b2f((uint16_t)(u>>16))*sc1 + sh1, 0.f);
  uint32_t pu = (uint32_t)f2b(a) | ((uint32_t)f2b(d)<<16);
  *(uint32_t*)(egoT + (size_t)b*576 + c) = pu;
  *(uint32_t*)(feat + (size_t)b*1088 + 512 + c) = pu;
}

// ---------------- small-M GEMM (M=128), no LDS ----------------
__global__ __launch_bounds__(256) void k_sgemm(
    const uint16_t* __restrict__ A, int lda,
    const uint16_t* __restrict__ B, int ldb,
    const float* __restrict__ bias,
    void* __restrict__ C, int ldc,
    int N, int K, int flags)
{
  int t = threadIdx.x, w = t>>6, l = t&63;
  int nt = blockIdx.x*4 + w;
  int n  = nt*16 + (l&15);
  int m0 = blockIdx.y*16;
  bool nv = n < N;
  facc acc = facc{0.f,0.f,0.f,0.f};
  for(int k=0;k<K;k+=32){
    bfrag af = *(const bfrag*)(A + (size_t)(m0+(l&15))*lda + k + (l>>4)*8);
    bfrag bf_ = {0,0,0,0,0,0,0,0};
    if(nv) bf_ = *(const bfrag*)(B + (size_t)n*ldb + k + (l>>4)*8);
    acc = MFMA(af, bf_, acc);
  }
  if(nv){
    float bv = bias ? bias[n] : 0.f;
    #pragma unroll
    for(int r=0;r<4;r++){
      int m = m0 + (l>>4)*4 + r;
      float v = acc[r] + bv;
      if(flags & 1) v = fmaxf(v, 0.f);
      if(flags & 2) ((float*)C)[(size_t)m*ldc + n] = v;
      else ((uint16_t*)C)[(size_t)m*ldc + n] = f2b(v);
    }
  }
}

// ---------------- fused tail: blockIdx.x<4 -> dec1 (relu,bf16), ==4 -> cls (f32) ----------------
__global__ __launch_bounds__(256) void k_tail1(
    const uint16_t* __restrict__ FEAT,
    const uint16_t* __restrict__ D1W, const float* __restrict__ d1B,
    const uint16_t* __restrict__ CLSW, const float* __restrict__ clsB,
    uint16_t* __restrict__ D1out, float* __restrict__ confOut)
{
  int t = threadIdx.x, w = t>>6, l = t&63;
  int m0 = blockIdx.y*16;
  bool isCls = (blockIdx.x == 4);
  int n = (isCls ? w : (blockIdx.x*4 + w))*16 + (l&15);
  int N = isCls ? 25 : 256;
  const uint16_t* B = isCls ? CLSW : D1W;
  bool nv = n < N;
  facc acc = facc{0.f,0.f,0.f,0.f};
  for(int k=0;k<1088;k+=32){
    bfrag af = *(const bfrag*)(FEAT + (size_t)(m0+(l&15))*1088 + k + (l>>4)*8);
    bfrag bf_ = {0,0,0,0,0,0,0,0};
    if(nv) bf_ = *(const bfrag*)(B + (size_t)n*1088 + k + (l>>4)*8);
    acc = MFMA(af, bf_, acc);
  }
  if(nv){
    #pragma unroll
    for(int r=0;r<4;r++){
      int m = m0 + (l>>4)*4 + r;
      if(isCls){
        confOut[(size_t)m*25 + n] = acc[r] + clsB[n];
      } else {
        D1out[(size_t)m*256 + n] = f2b(fmaxf(acc[r] + d1B[n], 0.f));
      }
    }
  }
}

// ---------------- fused dec2 + Legendre trajectory ----------------
// grid (7, 8): block covers n in [bx*64, bx*64+64) = 4 modes, m in [by*16,+16).
__global__ __launch_bounds__(256) void k_tail2(
    const uint16_t* __restrict__ D1B, const uint16_t* __restrict__ D2W,
    const float* __restrict__ d2B, const float* __restrict__ tm,
    float* __restrict__ outF)
{
  __shared__ float co[16*64];
  __shared__ float tms[152];
  int t = threadIdx.x, w = t>>6, l = t&63;
  if(t < 152) tms[t] = tm[t];
  int bx = blockIdx.x, m0 = blockIdx.y*16;
  int n = (bx*4 + w)*16 + (l&15);
  bool nv = n < 400;
  facc acc = facc{0.f,0.f,0.f,0.f};
  for(int k=0;k<256;k+=32){
    bfrag af = *(const bfrag*)(D1B + (size_t)(m0+(l&15))*256 + k + (l>>4)*8);
    bfrag bf_ = {0,0,0,0,0,0,0,0};
    if(nv) bf_ = *(const bfrag*)(D2W + (size_t)n*256 + k + (l>>4)*8);
    acc = MFMA(af, bf_, acc);
  }
  if(nv){
    #pragma unroll
    for(int r=0;r<4;r++){
      int mm = (l>>4)*4 + r;
      co[mm*64 + (w*16 + (l&15))] = acc[r] + d2B[n];
    }
  }
  __syncthreads();
  int nmodes = (bx < 6) ? 4 : 1;
  for(int idx=t; idx<16*nmodes*19; idx+=256){
    int mm = idx/(nmodes*19);
    int rem = idx%(nmodes*19);
    int md = rem/19, tt = rem%19;
    const float* cp = &co[mm*64 + md*16];
    float x=0.f, y=0.f;
    #pragma unroll
    for(int j=0;j<8;j++){ float tv = tms[j*19+tt]; x += cp[j]*tv; y += cp[8+j]*tv; }
    float* op = outF + ((size_t)(m0+mm)*25 + bx*4+md)*38;
    op[tt*2+0] = x; op[tt*2+1] = y;
  }
}

// ---------------- batched per-head GEMM ----------------
__global__ __launch_bounds__(256) void k_bgemm(
    const uint16_t* __restrict__ A, int lda, int aoffs,
    const uint16_t* __restrict__ B, int ldb, int brows,
    uint16_t* __restrict__ C, int ldc, int coffs,
    int K)
{
  int t = threadIdx.x, w = t>>6, l = t&63;
  int z = blockIdx.z;
  int n = (blockIdx.x*4 + w)*16 + (l&15);
  int m0 = blockIdx.y*16;
  const uint16_t* Ab = A + (size_t)z*aoffs;
  const uint16_t* Bb = B + (size_t)z*brows*ldb;
  facc acc = facc{0.f,0.f,0.f,0.f};
  for(int k=0;k<K;k+=32){
    bfrag af = *(const bfrag*)(Ab + (size_t)(m0+(l&15))*lda + k + (l>>4)*8);
    bfrag bf_ = *(const bfrag*)(Bb + (size_t)n*ldb + k + (l>>4)*8);
    acc = MFMA(af, bf_, acc);
  }
  #pragma unroll
  for(int r=0;r<4;r++){
    int m = m0 + (l>>4)*4 + r;
    C[(size_t)m*ldc + z*coffs + n] = f2b(acc[r]);
  }
}

// ---------------- attention core with inline BN2+ReLU on y2 load ----------------
__global__ __launch_bounds__(512) void k_attn2(
    const uint16_t* __restrict__ U16, const uint16_t* __restrict__ y2,
    const float* __restrict__ stats, const float* __restrict__ gg,
    const float* __restrict__ bb,
    uint16_t* __restrict__ zout)
{
  __shared__ __align__(16) char LA[49*1024 + 8*1024];
  __shared__ float scs[512], shs[512];
  uint16_t* uls = (uint16_t*)(LA + 49*1024);
  int t = threadIdx.x, w = t>>6, l = t&63;
  int b = blockIdx.x >> 1, half = blockIdx.x & 1;
  int h = half*8 + w;

  if(t < 512){
    float mu = stats[t]*(1.f/6272.f);
    float var = stats[512+t]*(1.f/6272.f) - mu*mu;
    float sc = gg[t]*rsqrtf(var+1e-5f);
    scs[t] = sc; shs[t] = bb[t] - mu*sc;
  }
  __syncthreads();

  for(int i=t; i<3136; i+=512){
    int g = i>>6, c16 = i&63;
    uint4 raw = *(const uint4*)(y2 + ((size_t)(b*49+g)*512 + c16*8));
    const uint16_t* rp = (const uint16_t*)&raw;
    uint16_t ov[8];
    #pragma unroll
    for(int j=0;j<8;j++){
      int c = c16*8 + j;
      ov[j] = f2b(fmaxf(b2f(rp[j])*scs[c] + shs[c], 0.f));
    }
    *(uint4*)(LA + g*1024 + ((c16*16) ^ ((g&31)<<4))) = *(uint4*)ov;
  }
  *(uint4*)((char*)uls + w*1024 + l*16) =
      *(const uint4*)(U16 + (size_t)b*8192 + h*512 + l*8);
  __syncthreads();

  float dot = 0.f;
  if(l < 49){
    const char* yrow = LA + l*1024;
    const char* ur = (const char*)uls + w*1024;
    for(int c16=0;c16<64;c16++){
      uint4 uv = *(const uint4*)(ur + c16*16);
      uint4 yv = *(const uint4*)(yrow + ((c16*16) ^ ((l&31)<<4)));
      const uint16_t* up = (const uint16_t*)&uv;
      const uint16_t* yp = (const uint16_t*)&yv;
      #pragma unroll
      for(int j=0;j<8;j++) dot += b2f(up[j])*b2f(yp[j]);
    }
  }
  float e = (l<49) ? dot*(1.f/32.f) : -1e30f;
  float mx = e;
  for(int s=32;s>0;s>>=1) mx = fmaxf(mx, __shfl_xor(mx, s));
  mx = fmaxf(mx, 0.f);
  float p = (l<49) ? __expf(e-mx) : 0.f;
  float den = p;
  for(int s=32;s>0;s>>=1) den += __shfl_xor(den, s);
  den += 32.f*__expf(-mx);

  float z[8];
  #pragma unroll
  for(int j=0;j<8;j++) z[j]=0.f;
  for(int g=0; g<49; g++){
    float pg = __shfl(p, g);
    uint4 yv = *(const uint4*)(LA + g*1024 + ((l*16) ^ ((g&31)<<4)));
    const uint16_t* yp = (const uint16_t*)&yv;
    #pragma unroll
    for(int j=0;j<8;j++) z[j] += pg*b2f(yp[j]);
  }
  float inv = 1.f/den;
  uint16_t zr[8];
  #pragma unroll
  for(int j=0;j<8;j++) zr[j] = f2b(z[j]*inv);
  *(uint4*)(zout + ((size_t)(b*16+h)*512) + l*8) = *(uint4*)zr;
}

// ======================= host =======================
extern "C" void kernel_launch(void* const* d_in, const int* in_sizes, int n_in,
                              void* d_out, int out_size, void* d_ws, size_t ws_size,
                              hipStream_t stream)
{
  const float* cnn      = (const float*)d_in[0];
  const float* ego_seq  = (const float*)d_in[1];
  const float* ag_seq   = (const float*)d_in[2];
  const int*   ego_len  = (const int*)d_in[3];
  const int*   ag_len   = (const int*)d_in[4];
  const int*   grid_pos = (const int*)d_in[5];
  const float* sW  = (const float*)d_in[6];
  const float* sb  = (const float*)d_in[7];
  const float* Wih = (const float*)d_in[8];
  const float* Whh = (const float*)d_in[9];
  const float* bih = (const float*)d_in[10];
  const float* bhh = (const float*)d_in[11];
  const float* encW = (const float*)d_in[12];
  const float* encB = (const float*)d_in[13];
  const float* conv1W = (const float*)d_in[14];
  const float* bn1g = (const float*)d_in[15];
  const float* bn1b = (const float*)d_in[16];
  const float* conv2W = (const float*)d_in[17];
  const float* bn2g = (const float*)d_in[18];
  const float* bn2b = (const float*)d_in[19];
  const float* qWf  = (const float*)d_in[20];
  const float* kWf  = (const float*)d_in[21];
  const float* vWf  = (const float*)d_in[22];
  const float* aoW  = (const float*)d_in[23];
  const float* aoB  = (const float*)d_in[24];
  const float* clsWf = (const float*)d_in[25];
  const float* clsB  = (const float*)d_in[26];
  const float* d1Wf  = (const float*)d_in[27];
  const float* d1B   = (const float*)d_in[28];
  const float* d2Wf  = (const float*)d_in[29];
  const float* d2B   = (const float*)d_in[30];

  char* ws = (char*)d_ws;
  const size_t XP_OFF   = 0;
  const size_t PS_OFF   = 0;
  const size_t U_OFF    = 0;
  const size_t ZB_OFF   = 2097152;
  const size_t Y2_OFF   = 41943040;
  const size_t Y1P_OFF  = 71303168;
  const size_t WP1_OFF  = 104857600;
  const size_t WP2_OFF  = 114884608;
  const size_t WKT_OFF  = 119603200;
  const size_t WVB_OFF  = 120651776;
  const size_t QW_OFF   = 121700352;
  const size_t AOW_OFF  = 122880000;
  const size_t CLSW_OFF = 123928576;
  const size_t D1W_OFF  = 123982976;
  const size_t D2W_OFF  = 124540032;
  const size_t GRID_OFF = 124744832;
  const size_t EGOT_OFF = 131167360;
  const size_t FEAT_OFF = 131314816;
  const size_t QB_OFF   = 131593344;
  const size_t OBUF_OFF = 132117632;
  const size_t D1_OFF   = 132379776;
  const size_t WC_OFF   = 132650112;
  const size_t BE_OFF   = 132699264;
  const size_t ENCW_OFF = 132700288;
  const size_t TMAT_OFF = 132708480;
  const size_t ST1_OFF  = 132709120;
  const size_t ST2_OFF  = 132713216;

  uint16_t* XP   = (uint16_t*)(ws + XP_OFF);
  uint16_t* PSB  = (uint16_t*)(ws + PS_OFF);
  uint16_t* U16  = (uint16_t*)(ws + U_OFF);
  uint16_t* ZB16 = (uint16_t*)(ws + ZB_OFF);
  uint16_t* Y2   = (uint16_t*)(ws + Y2_OFF);
  uint16_t* Y1P  = (uint16_t*)(ws + Y1P_OFF);
  uint16_t* WP1  = (uint16_t*)(ws + WP1_OFF);
  uint16_t* WP2  = (uint16_t*)(ws + WP2_OFF);
  uint16_t* WKT  = (uint16_t*)(ws + WKT_OFF);
  uint16_t* WVB  = (uint16_t*)(ws + WVB_OFF);
  uint16_t* QW   = (uint16_t*)(ws + QW_OFF);
  uint16_t* AOW  = (uint16_t*)(ws + AOW_OFF);
  uint16_t* CLSW = (uint16_t*)(ws + CLSW_OFF);
  uint16_t* D1W  = (uint16_t*)(ws + D1W_OFF);
  uint16_t* D2W  = (uint16_t*)(ws + D2W_OFF);
  float*    GRIDB= (float*)(ws + GRID_OFF);
  uint16_t* EGOT = (uint16_t*)(ws + EGOT_OFF);
  uint16_t* FEAT = (uint16_t*)(ws + FEAT_OFF);
  uint16_t* QB16 = (uint16_t*)(ws + QB_OFF);
  uint16_t* OBUF = (uint16_t*)(ws + OBUF_OFF);
  uint16_t* D1B  = (uint16_t*)(ws + D1_OFF);
  uint16_t* WC   = (uint16_t*)(ws + WC_OFF);
  float*    BE   = (float*)(ws + BE_OFF);
  uint16_t* ENCWB= (uint16_t*)(ws + ENCW_OFF);
  float*    TMAT = (float*)(ws + TMAT_OFF);
  float*    ST1  = (float*)(ws + ST1_OFF);
  float*    ST2  = (float*)(ws + ST2_OFF);
  float*    outF = (float*)d_out;

  // ---- mega-prep ----
  {
    PrepArgs a;
    a.cnn = cnn; a.Xp = XP; a.Y1P = Y1P; a.gridb = GRIDB; a.stats = ST1;
    a.Wih=Wih; a.Whh=Whh; a.bih=bih; a.bhh=bhh; a.sW=sW; a.sb=sb; a.encW=encW;
    a.Wc=WC; a.be=BE; a.encWb=ENCWB; a.tm=TMAT;
    a.conv1W=conv1W; a.WP1=WP1;
    a.conv2W=conv2W; a.WP2=WP2;
    a.kWf=kWf; a.WKT=WKT;
    a.fs[0]=vWf;  a.fd[0]=WVB;   a.fn[0]=1024*512;
    a.fs[1]=qWf;  a.fd[1]=QW;    a.fn[1]=1024*576;
    a.fs[2]=aoW;  a.fd[2]=AOW;   a.fn[2]=512*1024;
    a.fs[3]=clsWf;a.fd[3]=CLSW;  a.fn[3]=25*1088;
    a.fs[4]=d1Wf; a.fd[4]=D1W;   a.fn[4]=256*1088;
    a.fs[5]=d2Wf; a.fd[5]=D2W;   a.fn[5]=400*256;
    int nb = 0;
    for(int j=0;j<6;j++){ a.fb0[j] = nb; nb += (a.fn[j] + 8191)/8192; }
    k_prep<<<5393 + nb, 256, 0, stream>>>(a);
  }

  // encoders + scatter
  k_lstm<<<132,256,0,stream>>>(ego_seq, ag_seq, ego_len, ag_len, grid_pos,
                               WC, BE, ENCWB, encB, GRIDB, EGOT, FEAT);
  k_packx_grid<<<256,256,0,stream>>>(GRIDB, XP);
  // conv1 (raw output + stats; BN1 applied lazily by conv2dy)
  k_conv1_8p<<<196,512,0,stream>>>(XP, WP1, Y1P, ST1);
  // conv2 with inline BN1+ReLU on A-load -> bf16 partials -> sum+stats
  k_conv2dy<<<dim3(196,3),256,0,stream>>>(Y1P, WP2, PSB, ST1, bn1g, bn1b);
  k_bn2sum<<<392,256,0,stream>>>(PSB, Y2, ST2);
  // center pixel -> egoT / FEAT (BN2 inline)
  k_center<<<128,256,0,stream>>>(Y2, ST2, bn2g, bn2b, EGOT, FEAT);
  // q = egoT @ qW^T (bf16)
  k_sgemm<<<dim3(16,8),256,0,stream>>>(EGOT, 576, QW, 576, nullptr, QB16, 1024, 1024, 576, 0);
  // U = q @ Wk (per head), attn core (BN2 inline on y2), o = z @ Wv^T
  k_bgemm<<<dim3(8,8,16),256,0,stream>>>(QB16, 1024, 64, WKT, 64, 512, U16, 8192, 512, 64);
  k_attn2<<<256,512,0,stream>>>(U16, Y2, ST2, bn2g, bn2b, ZB16);
  k_bgemm<<<dim3(1,8,16),256,0,stream>>>(ZB16, 8192, 512, WVB, 512, 64, OBUF, 1024, 64, 512);
  // attn_out -> feat[:,0:512]
  k_sgemm<<<dim3(8,8),256,0,stream>>>(OBUF, 1024, AOW, 1024, aoB, FEAT, 1088, 512, 1024, 0);
  // fused cls + dec1
  k_tail1<<<dim3(5,8),256,0,stream>>>(FEAT, D1W, d1B, CLSW, clsB, D1B, outF + 121600);
  // fused dec2 + trajectory
  k_tail2<<<dim3(7,8),256,0,stream>>>(D1B, D2W, d2B, TMAT, outF);

  (void)in_sizes; (void)n_in; (void)out_size; (void)ws_size;
}